// Round 1
// baseline (1442.456 us; speedup 1.0000x reference)
//
#include <hip/hip_runtime.h>
#include <cstdint>
#include <cstddef>

namespace {
constexpr float kScale = 0.17677669529663689f; // 32^-0.5
constexpr float kEps = 1e-6f;
constexpr float kInvC = 1.0f / 128.0f;

__device__ __forceinline__ float gelu_exact(float v) {
  return 0.5f * v * (1.0f + erff(v * 0.70710678118654752f));
}
} // namespace

// ---------------------------------------------------------------------------
// K1: LN(norm1) + cyclic shift(-3,-3) + window partition
// out: wp[2048 windows][49 tokens][128]
// ---------------------------------------------------------------------------
__global__ __launch_bounds__(256) void k_ln1_part(
    const float* __restrict__ x, const float* __restrict__ g,
    const float* __restrict__ b, float* __restrict__ wp) {
  int wv = threadIdx.x >> 6, lane = threadIdx.x & 63;
  int tok = blockIdx.x * 4 + wv;               // 0..100351
  int win = tok / 49, n = tok - win * 49;
  int bb = win >> 6, wi = win & 63;
  int whi = wi >> 3, wwi = wi & 7;
  int r = n / 7, c = n - r * 7;
  int hs = whi * 7 + r + 3; if (hs >= 56) hs -= 56;
  int ws = wwi * 7 + c + 3; if (ws >= 56) ws -= 56;
  size_t src = ((size_t)bb * 3136 + hs * 56 + ws) * 128;
  float2 v = *(const float2*)(x + src + lane * 2);
  float s = v.x + v.y, sq = v.x * v.x + v.y * v.y;
#pragma unroll
  for (int off = 1; off < 64; off <<= 1) {
    s += __shfl_xor(s, off);
    sq += __shfl_xor(sq, off);
  }
  float mu = s * kInvC;
  float var = sq * kInvC - mu * mu;
  float rs = rsqrtf(var + kEps);
  float2 gg = *(const float2*)(g + lane * 2);
  float2 bv = *(const float2*)(b + lane * 2);
  float2 o;
  o.x = (v.x - mu) * rs * gg.x + bv.x;
  o.y = (v.y - mu) * rs * gg.y + bv.y;
  *(float2*)(wp + (size_t)tok * 128 + lane * 2) = o;
}

// ---------------------------------------------------------------------------
// K2: qkv = wp @ qkv_w + qkv_b    (M=100352, K=128, N=384)
// 64x64 tile, BK=64, 256 threads, 4x4 per thread, A kept transposed in LDS.
// ---------------------------------------------------------------------------
__global__ __launch_bounds__(256) void k_qkv(
    const float* __restrict__ A, const float* __restrict__ Bw,
    const float* __restrict__ bias, float* __restrict__ C) {
  __shared__ float At[64][68];  // [k][row], pad 68 -> conflict-free b128 reads
  __shared__ float Bs[64][64];
  int tid = threadIdx.x;
  int mBase = blockIdx.x * 64;
  int nBase = blockIdx.y * 64;
  int tx = tid & 15, ty = tid >> 4;
  float acc[4][4] = {};
  for (int ks = 0; ks < 128; ks += 64) {
#pragma unroll
    for (int l = 0; l < 4; ++l) {
      int idx = tid + l * 256;
      int row = idx >> 4, k4 = (idx & 15) << 2;
      float4 v = *(const float4*)(A + (size_t)(mBase + row) * 128 + ks + k4);
      At[k4 + 0][row] = v.x; At[k4 + 1][row] = v.y;
      At[k4 + 2][row] = v.z; At[k4 + 3][row] = v.w;
    }
#pragma unroll
    for (int l = 0; l < 4; ++l) {
      int idx = tid + l * 256;
      int row = idx >> 4, n4 = (idx & 15) << 2;
      *(float4*)&Bs[row][n4] =
          *(const float4*)(Bw + (size_t)(ks + row) * 384 + nBase + n4);
    }
    __syncthreads();
#pragma unroll 8
    for (int k = 0; k < 64; ++k) {
      float4 a = *(const float4*)&At[k][ty << 2];
      float4 bv = *(const float4*)&Bs[k][tx << 2];
      acc[0][0] += a.x * bv.x; acc[0][1] += a.x * bv.y; acc[0][2] += a.x * bv.z; acc[0][3] += a.x * bv.w;
      acc[1][0] += a.y * bv.x; acc[1][1] += a.y * bv.y; acc[1][2] += a.y * bv.z; acc[1][3] += a.y * bv.w;
      acc[2][0] += a.z * bv.x; acc[2][1] += a.z * bv.y; acc[2][2] += a.z * bv.z; acc[2][3] += a.z * bv.w;
      acc[3][0] += a.w * bv.x; acc[3][1] += a.w * bv.y; acc[3][2] += a.w * bv.z; acc[3][3] += a.w * bv.w;
    }
    __syncthreads();
  }
#pragma unroll
  for (int i = 0; i < 4; ++i) {
    size_t row = (size_t)(mBase + (ty << 2) + i) * 384 + nBase;
#pragma unroll
    for (int j = 0; j < 4; ++j)
      C[row + (tx << 2) + j] = acc[i][j] + bias[nBase + (tx << 2) + j];
  }
}

// ---------------------------------------------------------------------------
// K3: per-(window, head) attention: S = q k^T (q pre-scaled) + rel-pos bias
//     + shift mask; softmax; softmax again (faithful); O = S v.
// ---------------------------------------------------------------------------
__global__ __launch_bounds__(256) void k_attn(
    const float* __restrict__ qkv, const float* __restrict__ rpb,
    float* __restrict__ ob) {
  int win = blockIdx.x >> 2, head = blockIdx.x & 3;
  int wi = win & 63, whi = wi >> 3, wwi = wi & 7;
  __shared__ float qs[49][33], ks[49][33], vs[49][33];
  __shared__ float at[49][50];
  __shared__ int lab[49];
  int tid = threadIdx.x;
  const float* base = qkv + (size_t)win * 49 * 384 + head * 32;
  for (int idx = tid; idx < 1568; idx += 256) {
    int n = idx >> 5, d = idx & 31;
    const float* row = base + (size_t)n * 384;
    qs[n][d] = row[d] * kScale;
    ks[n][d] = row[128 + d];
    vs[n][d] = row[256 + d];
  }
  if (tid < 49) {
    int r = tid / 7, c = tid - (tid / 7) * 7;
    int hh = whi * 7 + r, ww = wwi * 7 + c;
    int rh = (hh < 49) ? 0 : ((hh < 53) ? 1 : 2);
    int rw = (ww < 49) ? 0 : ((ww < 53) ? 1 : 2);
    lab[tid] = rh * 3 + rw;
  }
  __syncthreads();
  for (int idx = tid; idx < 2401; idx += 256) {
    int i = idx / 49, j = idx - i * 49;
    float s = 0.f;
#pragma unroll
    for (int d = 0; d < 32; ++d) s += qs[i][d] * ks[j][d];
    int ri = i / 7, ci = i - ri * 7, rj = j / 7, cj = j - rj * 7;
    int ridx = (ri - rj + 6) * 13 + (ci - cj + 6);
    s += rpb[ridx * 4 + head];
    s += (lab[i] != lab[j]) ? -100.0f : 0.0f;
    at[i][j] = s;
  }
  __syncthreads();
  if (tid < 49) {
    for (int pass = 0; pass < 2; ++pass) {
      float m = -1e30f;
      for (int j = 0; j < 49; ++j) m = fmaxf(m, at[tid][j]);
      float sum = 0.f;
      for (int j = 0; j < 49; ++j) {
        float e = expf(at[tid][j] - m);
        at[tid][j] = e;
        sum += e;
      }
      float inv = 1.0f / sum;
      for (int j = 0; j < 49; ++j) at[tid][j] *= inv;
    }
  }
  __syncthreads();
  for (int idx = tid; idx < 1568; idx += 256) {
    int i = idx >> 5, d = idx & 31;
    float s = 0.f;
#pragma unroll
    for (int j = 0; j < 49; ++j) s += at[i][j] * vs[j][d];
    ob[((size_t)win * 49 + i) * 128 + head * 32 + d] = s;
  }
}

// ---------------------------------------------------------------------------
// K4: per-window proj GEMM (49x128x128) + bias + LN(proj_ln) + exact GELU,
//     reverse partition + reverse shift + residual add. Writes xres = d_out.
// ---------------------------------------------------------------------------
__global__ __launch_bounds__(256) void k_proj(
    const float* __restrict__ ob, const float* __restrict__ pw,
    const float* __restrict__ pb, const float* __restrict__ lg,
    const float* __restrict__ lb, const float* __restrict__ x,
    float* __restrict__ xres) {
  int win = blockIdx.x;
  int bb = win >> 6, wi = win & 63, whi = wi >> 3, wwi = wi & 7;
  __shared__ float os[49][128];   // 25 KB
  __shared__ float pws[64][128];  // 32 KB (k-chunk of proj_w)
  int tid = threadIdx.x;
  int wv = tid >> 6, lane = tid & 63;
  for (int idx = tid; idx < 1568; idx += 256) {
    int n = idx >> 5, k4 = (idx & 31) << 2;
    *(float4*)&os[n][k4] =
        *(const float4*)(ob + ((size_t)win * 49 + n) * 128 + k4);
  }
  float a0[13], a1[13];
#pragma unroll
  for (int t = 0; t < 13; ++t) { a0[t] = 0.f; a1[t] = 0.f; }
  for (int ks = 0; ks < 128; ks += 64) {
    __syncthreads();
    for (int idx = tid; idx < 2048; idx += 256) {
      int kk = idx >> 5, k4 = (idx & 31) << 2;
      *(float4*)&pws[kk][k4] =
          *(const float4*)(pw + (size_t)(ks + kk) * 128 + k4);
    }
    __syncthreads();
#pragma unroll
    for (int ti = 0; ti < 13; ++ti) {
      int t = wv * 13 + ti;
      if (t < 49) {
        float s0 = 0.f, s1 = 0.f;
        for (int k = 0; k < 64; ++k) {
          float ovv = os[t][ks + k];
          float2 w2v = *(const float2*)&pws[k][lane * 2];
          s0 += ovv * w2v.x;
          s1 += ovv * w2v.y;
        }
        a0[ti] += s0; a1[ti] += s1;
      }
    }
  }
  float2 pbv = *(const float2*)(pb + lane * 2);
  float2 lgv = *(const float2*)(lg + lane * 2);
  float2 lbv = *(const float2*)(lb + lane * 2);
#pragma unroll
  for (int ti = 0; ti < 13; ++ti) {
    int t = wv * 13 + ti;
    if (t < 49) {
      float y0 = a0[ti] + pbv.x, y1 = a1[ti] + pbv.y;
      float s = y0 + y1, sq = y0 * y0 + y1 * y1;
#pragma unroll
      for (int off = 1; off < 64; off <<= 1) {
        s += __shfl_xor(s, off);
        sq += __shfl_xor(sq, off);
      }
      float mu = s * kInvC, var = sq * kInvC - mu * mu;
      float rs = rsqrtf(var + kEps);
      y0 = (y0 - mu) * rs * lgv.x + lbv.x;
      y1 = (y1 - mu) * rs * lgv.y + lbv.y;
      y0 = gelu_exact(y0);
      y1 = gelu_exact(y1);
      int r = t / 7, c = t - (t / 7) * 7;
      int hs = whi * 7 + r + 3; if (hs >= 56) hs -= 56;
      int wsd = wwi * 7 + c + 3; if (wsd >= 56) wsd -= 56;
      size_t row = ((size_t)bb * 3136 + hs * 56 + wsd) * 128;
      float2 xv = *(const float2*)(x + row + lane * 2);
      float2 o2;
      o2.x = xv.x + y0;
      o2.y = xv.y + y1;
      *(float2*)(xres + row + lane * 2) = o2;
    }
  }
}

// ---------------------------------------------------------------------------
// K5: fused MLP per 16 tokens: LN(norm2) -> gelu(m@W1+b1) -> @W2+b2 -> +res.
// In-place on d_out (each element read only by the thread that rewrites it).
// ---------------------------------------------------------------------------
__global__ __launch_bounds__(256) void k_mlp(
    const float* __restrict__ w1, const float* __restrict__ b1,
    const float* __restrict__ w2, const float* __restrict__ b2,
    const float* __restrict__ g2, const float* __restrict__ lb2,
    float* __restrict__ xio) {
  int tb = blockIdx.x * 16;
  __shared__ float ms[16][128];    // 8 KB (LN output)
  __shared__ float hsd[16][516];   // 33 KB (hidden, pad 516 -> conflict-free)
  int tid = threadIdx.x;
  int wv = tid >> 6, lane = tid & 63;
#pragma unroll
  for (int i = 0; i < 4; ++i) {
    int t = wv * 4 + i;
    size_t row = (size_t)(tb + t) * 128;
    float2 v = *(const float2*)(xio + row + lane * 2);
    float s = v.x + v.y, sq = v.x * v.x + v.y * v.y;
#pragma unroll
    for (int off = 1; off < 64; off <<= 1) {
      s += __shfl_xor(s, off);
      sq += __shfl_xor(sq, off);
    }
    float mu = s * kInvC, var = sq * kInvC - mu * mu;
    float rs = rsqrtf(var + kEps);
    float2 gg = *(const float2*)(g2 + lane * 2);
    float2 bb = *(const float2*)(lb2 + lane * 2);
    ms[t][lane * 2] = (v.x - mu) * rs * gg.x + bb.x;
    ms[t][lane * 2 + 1] = (v.y - mu) * rs * gg.y + bb.y;
  }
  __syncthreads();
  {
    float acc0[16], acc1[16];
#pragma unroll
    for (int t = 0; t < 16; ++t) { acc0[t] = 0.f; acc1[t] = 0.f; }
    for (int k4 = 0; k4 < 32; ++k4) {
      float wa[4], wb[4];
#pragma unroll
      for (int kk = 0; kk < 4; ++kk) {
        wa[kk] = w1[(size_t)(k4 * 4 + kk) * 512 + tid];
        wb[kk] = w1[(size_t)(k4 * 4 + kk) * 512 + 256 + tid];
      }
#pragma unroll
      for (int t = 0; t < 16; ++t) {
        float4 m = *(const float4*)&ms[t][k4 << 2];
        acc0[t] += m.x * wa[0] + m.y * wa[1] + m.z * wa[2] + m.w * wa[3];
        acc1[t] += m.x * wb[0] + m.y * wb[1] + m.z * wb[2] + m.w * wb[3];
      }
    }
    float bb0 = b1[tid], bb1 = b1[256 + tid];
#pragma unroll
    for (int t = 0; t < 16; ++t) {
      hsd[t][tid] = gelu_exact(acc0[t] + bb0);
      hsd[t][256 + tid] = gelu_exact(acc1[t] + bb1);
    }
  }
  __syncthreads();
  {
    int t = tid >> 4, cb = (tid & 15) << 3;
    float acc[8];
#pragma unroll
    for (int q = 0; q < 8; ++q) acc[q] = b2[cb + q];
    for (int j4 = 0; j4 < 128; ++j4) {
      float4 h = *(const float4*)&hsd[t][j4 << 2];
      const float* wrow = w2 + (size_t)(j4 << 2) * 128 + cb;
      float hv[4] = {h.x, h.y, h.z, h.w};
#pragma unroll
      for (int jj = 0; jj < 4; ++jj) {
        float4 wA = *(const float4*)(wrow + jj * 128);
        float4 wB = *(const float4*)(wrow + jj * 128 + 4);
        acc[0] += hv[jj] * wA.x; acc[1] += hv[jj] * wA.y;
        acc[2] += hv[jj] * wA.z; acc[3] += hv[jj] * wA.w;
        acc[4] += hv[jj] * wB.x; acc[5] += hv[jj] * wB.y;
        acc[6] += hv[jj] * wB.z; acc[7] += hv[jj] * wB.w;
      }
    }
    size_t row = (size_t)(tb + t) * 128;
    float4 xa = *(const float4*)(xio + row + cb);
    float4 xb = *(const float4*)(xio + row + cb + 4);
    float4 oa, obv;
    oa.x = xa.x + acc[0]; oa.y = xa.y + acc[1];
    oa.z = xa.z + acc[2]; oa.w = xa.w + acc[3];
    obv.x = xb.x + acc[4]; obv.y = xb.y + acc[5];
    obv.z = xb.z + acc[6]; obv.w = xb.w + acc[7];
    *(float4*)(xio + row + cb) = oa;
    *(float4*)(xio + row + cb + 4) = obv;
  }
}

extern "C" void kernel_launch(void* const* d_in, const int* in_sizes, int n_in,
                              void* d_out, int out_size, void* d_ws,
                              size_t ws_size, hipStream_t stream) {
  (void)in_sizes; (void)n_in; (void)out_size; (void)ws_size;
  const float* x      = (const float*)d_in[0];
  const float* qkv_w  = (const float*)d_in[1];
  const float* qkv_b  = (const float*)d_in[2];
  const float* proj_w = (const float*)d_in[3];
  const float* proj_b = (const float*)d_in[4];
  const float* plg    = (const float*)d_in[5];
  const float* plb    = (const float*)d_in[6];
  const float* rpb    = (const float*)d_in[7];
  const float* n1g    = (const float*)d_in[8];
  const float* n1b    = (const float*)d_in[9];
  const float* n2g    = (const float*)d_in[10];
  const float* n2b    = (const float*)d_in[11];
  const float* w1     = (const float*)d_in[12];
  const float* b1     = (const float*)d_in[13];
  const float* w2     = (const float*)d_in[14];
  const float* b2     = (const float*)d_in[15];
  float* out = (float*)d_out;

  float* wp  = (float*)d_ws;                      // 100352*128
  float* qkv = wp + (size_t)100352 * 128;         // 100352*384
  float* ob  = qkv + (size_t)100352 * 384;        // 100352*128

  k_ln1_part<<<25088, 256, 0, stream>>>(x, n1g, n1b, wp);
  k_qkv<<<dim3(1568, 6), 256, 0, stream>>>(wp, qkv_w, qkv_b, qkv);
  k_attn<<<8192, 256, 0, stream>>>(qkv, rpb, ob);
  k_proj<<<2048, 256, 0, stream>>>(ob, proj_w, proj_b, plg, plb, x, out);
  k_mlp<<<6272, 256, 0, stream>>>(w1, b1, w2, b2, n2g, n2b, out);
}

// Round 2
// 575.322 us; speedup vs baseline: 2.5072x; 2.5072x over previous
//
#include <hip/hip_runtime.h>
#include <cstdint>
#include <cstddef>

typedef __attribute__((ext_vector_type(8))) short bf16x8;
typedef __attribute__((ext_vector_type(4))) float f32x4;

namespace {
constexpr float kScale = 0.17677669529663689f; // 32^-0.5
constexpr float kEps = 1e-6f;
constexpr float kInvC = 1.0f / 128.0f;

__device__ __forceinline__ float gelu_exact(float v) {
  return 0.5f * v * (1.0f + erff(v * 0.70710678118654752f));
}
__device__ __forceinline__ ushort f2bf(float f) {
  uint32_t u = __builtin_bit_cast(uint32_t, f);
  u += 0x7FFFu + ((u >> 16) & 1u);
  return (ushort)(u >> 16);
}
__device__ __forceinline__ float bf2f(ushort u) {
  return __builtin_bit_cast(float, (uint32_t)u << 16);
}
} // namespace

// ---------------------------------------------------------------------------
// K0: convert+transpose weights to bf16 [N][K] layout.
// qkvT[384][128], w1T[512][128], w2T[128][512]
// ---------------------------------------------------------------------------
__global__ __launch_bounds__(256) void k_prep(
    const float* __restrict__ qkv_w, const float* __restrict__ w1,
    const float* __restrict__ w2, ushort* __restrict__ qkvT,
    ushort* __restrict__ w1T, ushort* __restrict__ w2T) {
  int i = blockIdx.x * 256 + threadIdx.x;
  if (i < 384 * 128) {
    int n = i >> 7, k = i & 127;
    qkvT[i] = f2bf(qkv_w[k * 384 + n]);
  } else if (i < 384 * 128 + 512 * 128) {
    int j = i - 384 * 128;
    int n = j >> 7, k = j & 127;
    w1T[j] = f2bf(w1[k * 512 + n]);
  } else if (i < 384 * 128 + 512 * 128 + 128 * 512) {
    int j = i - 384 * 128 - 512 * 128;
    int n = j >> 9, k = j & 511;
    w2T[j] = f2bf(w2[k * 128 + n]);
  }
}

// ---------------------------------------------------------------------------
// K1: LN(norm1) + cyclic shift(-3,-3) + window partition -> bf16
// ---------------------------------------------------------------------------
__global__ __launch_bounds__(256) void k_ln1_part(
    const float* __restrict__ x, const float* __restrict__ g,
    const float* __restrict__ b, ushort* __restrict__ wp) {
  int wv = threadIdx.x >> 6, lane = threadIdx.x & 63;
  int tok = blockIdx.x * 4 + wv;               // 0..100351
  int win = tok / 49, n = tok - win * 49;
  int bb = win >> 6, wi = win & 63;
  int whi = wi >> 3, wwi = wi & 7;
  int r = n / 7, c = n - r * 7;
  int hs = whi * 7 + r + 3; if (hs >= 56) hs -= 56;
  int ws = wwi * 7 + c + 3; if (ws >= 56) ws -= 56;
  size_t src = ((size_t)bb * 3136 + hs * 56 + ws) * 128;
  float2 v = *(const float2*)(x + src + lane * 2);
  float s = v.x + v.y, sq = v.x * v.x + v.y * v.y;
#pragma unroll
  for (int off = 1; off < 64; off <<= 1) {
    s += __shfl_xor(s, off);
    sq += __shfl_xor(sq, off);
  }
  float mu = s * kInvC;
  float var = sq * kInvC - mu * mu;
  float rs = rsqrtf(var + kEps);
  float2 gg = *(const float2*)(g + lane * 2);
  float2 bv = *(const float2*)(b + lane * 2);
  float o0 = (v.x - mu) * rs * gg.x + bv.x;
  float o1 = (v.y - mu) * rs * gg.y + bv.y;
  uint p = (uint)f2bf(o0) | ((uint)f2bf(o1) << 16);
  ((uint*)wp)[(size_t)tok * 64 + lane] = p;
}

// ---------------------------------------------------------------------------
// K-LN2: LN(norm2) on xres (d_out) -> bf16 m
// ---------------------------------------------------------------------------
__global__ __launch_bounds__(256) void k_ln2(
    const float* __restrict__ x, const float* __restrict__ g,
    const float* __restrict__ b, ushort* __restrict__ m) {
  int wv = threadIdx.x >> 6, lane = threadIdx.x & 63;
  int tok = blockIdx.x * 4 + wv;
  float2 v = *(const float2*)(x + (size_t)tok * 128 + lane * 2);
  float s = v.x + v.y, sq = v.x * v.x + v.y * v.y;
#pragma unroll
  for (int off = 1; off < 64; off <<= 1) {
    s += __shfl_xor(s, off);
    sq += __shfl_xor(sq, off);
  }
  float mu = s * kInvC;
  float var = sq * kInvC - mu * mu;
  float rs = rsqrtf(var + kEps);
  float2 gg = *(const float2*)(g + lane * 2);
  float2 bv = *(const float2*)(b + lane * 2);
  float o0 = (v.x - mu) * rs * gg.x + bv.x;
  float o1 = (v.y - mu) * rs * gg.y + bv.y;
  uint p = (uint)f2bf(o0) | ((uint)f2bf(o1) << 16);
  ((uint*)m)[(size_t)tok * 64 + lane] = p;
}

// ---------------------------------------------------------------------------
// K-GEMM: C[M,N] = A[M,K](bf16) @ BT[N,K](bf16)^T, 128x128 tile, BK=64,
// 4 waves each 64x64 via 4x4 frags of mfma_f32_16x16x32_bf16.
// EPI 0: +bias -> bf16   EPI 1: gelu(+bias) -> bf16   EPI 2: +bias+res -> f32
// ---------------------------------------------------------------------------
template <int K, int EPI>
__global__ __launch_bounds__(256) void k_gemm(
    const ushort* __restrict__ A, const ushort* __restrict__ BT,
    const float* __restrict__ bias, const float* __restrict__ res,
    void* __restrict__ Cout) {
  __shared__ ushort As[128][72];  // [row][k], +8 pad -> 2-way (free) on b128
  __shared__ ushort Bs[128][72];  // [col][k]
  int tid = threadIdx.x;
  int mBase = blockIdx.x << 7;
  int nBase = blockIdx.y << 7;
  int lane = tid & 63, wid = tid >> 6;
  int wr = (wid >> 1) << 6, wc = (wid & 1) << 6;
  f32x4 acc[4][4] = {};
  for (int ks = 0; ks < K; ks += 64) {
#pragma unroll
    for (int l = 0; l < 4; ++l) {
      int c = tid + l * 256;
      int row = c >> 3, k8 = (c & 7) << 3;
      *(bf16x8*)&As[row][k8] =
          *(const bf16x8*)(A + (size_t)(mBase + row) * K + ks + k8);
      *(bf16x8*)&Bs[row][k8] =
          *(const bf16x8*)(BT + (size_t)(nBase + row) * K + ks + k8);
    }
    __syncthreads();
#pragma unroll
    for (int ksub = 0; ksub < 64; ksub += 32) {
      int kloc = ksub + ((lane >> 4) << 3);
      bf16x8 af[4], bfr[4];
#pragma unroll
      for (int m = 0; m < 4; ++m)
        af[m] = *(const bf16x8*)&As[wr + m * 16 + (lane & 15)][kloc];
#pragma unroll
      for (int n = 0; n < 4; ++n)
        bfr[n] = *(const bf16x8*)&Bs[wc + n * 16 + (lane & 15)][kloc];
#pragma unroll
      for (int m = 0; m < 4; ++m)
#pragma unroll
        for (int n = 0; n < 4; ++n)
          acc[m][n] = __builtin_amdgcn_mfma_f32_16x16x32_bf16(
              af[m], bfr[n], acc[m][n], 0, 0, 0);
    }
    __syncthreads();
  }
  int ldC = (int)(gridDim.y << 7);
#pragma unroll
  for (int n = 0; n < 4; ++n) {
    int cg = nBase + wc + n * 16 + (lane & 15);
    float bv = bias[cg];
#pragma unroll
    for (int m = 0; m < 4; ++m) {
      int rbase = mBase + wr + m * 16 + ((lane >> 4) << 2);
#pragma unroll
      for (int r = 0; r < 4; ++r) {
        float v = acc[m][n][r] + bv;
        size_t off = (size_t)(rbase + r) * ldC + cg;
        if (EPI == 0) {
          ((ushort*)Cout)[off] = f2bf(v);
        } else if (EPI == 1) {
          ((ushort*)Cout)[off] = f2bf(gelu_exact(v));
        } else {
          ((float*)Cout)[off] = v + res[off];
        }
      }
    }
  }
}

// ---------------------------------------------------------------------------
// K3: per-(window, head) attention (bf16 qkv in, bf16 o out)
// ---------------------------------------------------------------------------
__global__ __launch_bounds__(256) void k_attn(
    const ushort* __restrict__ qkv, const float* __restrict__ rpb,
    ushort* __restrict__ ob) {
  int win = blockIdx.x >> 2, head = blockIdx.x & 3;
  int wi = win & 63, whi = wi >> 3, wwi = wi & 7;
  __shared__ float qs[49][33], ks[49][33], vs[49][33];
  __shared__ float at[49][50];
  __shared__ int lab[49];
  int tid = threadIdx.x;
  const ushort* base = qkv + (size_t)win * 49 * 384 + head * 32;
  for (int idx = tid; idx < 1568; idx += 256) {
    int n = idx >> 5, d = idx & 31;
    const ushort* row = base + (size_t)n * 384;
    qs[n][d] = bf2f(row[d]) * kScale;
    ks[n][d] = bf2f(row[128 + d]);
    vs[n][d] = bf2f(row[256 + d]);
  }
  if (tid < 49) {
    int r = tid / 7, c = tid - (tid / 7) * 7;
    int hh = whi * 7 + r, ww = wwi * 7 + c;
    int rh = (hh < 49) ? 0 : ((hh < 53) ? 1 : 2);
    int rw = (ww < 49) ? 0 : ((ww < 53) ? 1 : 2);
    lab[tid] = rh * 3 + rw;
  }
  __syncthreads();
  for (int idx = tid; idx < 2401; idx += 256) {
    int i = idx / 49, j = idx - i * 49;
    float s = 0.f;
#pragma unroll
    for (int d = 0; d < 32; ++d) s += qs[i][d] * ks[j][d];
    int ri = i / 7, ci = i - ri * 7, rj = j / 7, cj = j - rj * 7;
    int ridx = (ri - rj + 6) * 13 + (ci - cj + 6);
    s += rpb[ridx * 4 + head];
    s += (lab[i] != lab[j]) ? -100.0f : 0.0f;
    at[i][j] = s;
  }
  __syncthreads();
  if (tid < 49) {
    for (int pass = 0; pass < 2; ++pass) {
      float m = -1e30f;
      for (int j = 0; j < 49; ++j) m = fmaxf(m, at[tid][j]);
      float sum = 0.f;
      for (int j = 0; j < 49; ++j) {
        float e = expf(at[tid][j] - m);
        at[tid][j] = e;
        sum += e;
      }
      float inv = 1.0f / sum;
      for (int j = 0; j < 49; ++j) at[tid][j] *= inv;
    }
  }
  __syncthreads();
  for (int idx = tid; idx < 1568; idx += 256) {
    int i = idx >> 5, d = idx & 31;
    float s = 0.f;
#pragma unroll
    for (int j = 0; j < 49; ++j) s += at[i][j] * vs[j][d];
    ob[((size_t)win * 49 + i) * 128 + head * 32 + d] = f2bf(s);
  }
}

// ---------------------------------------------------------------------------
// K4: per-window proj GEMM (49x128x128) + bias + LN(proj_ln) + exact GELU,
//     reverse partition + reverse shift + residual add. Writes xres = d_out.
// ---------------------------------------------------------------------------
__global__ __launch_bounds__(256) void k_proj(
    const ushort* __restrict__ ob, const float* __restrict__ pw,
    const float* __restrict__ pb, const float* __restrict__ lg,
    const float* __restrict__ lb, const float* __restrict__ x,
    float* __restrict__ xres) {
  int win = blockIdx.x;
  int bb = win >> 6, wi = win & 63, whi = wi >> 3, wwi = wi & 7;
  __shared__ float os[49][128];   // 25 KB
  __shared__ float pws[64][128];  // 32 KB (k-chunk of proj_w)
  int tid = threadIdx.x;
  int wv = tid >> 6, lane = tid & 63;
  for (int idx = tid; idx < 784; idx += 256) {
    int n = idx >> 4, d8 = (idx & 15) << 3;
    bf16x8 v = *(const bf16x8*)(ob + ((size_t)win * 49 + n) * 128 + d8);
#pragma unroll
    for (int j = 0; j < 8; ++j) os[n][d8 + j] = bf2f((ushort)v[j]);
  }
  float a0[13], a1[13];
#pragma unroll
  for (int t = 0; t < 13; ++t) { a0[t] = 0.f; a1[t] = 0.f; }
  for (int ks = 0; ks < 128; ks += 64) {
    __syncthreads();
    for (int idx = tid; idx < 2048; idx += 256) {
      int kk = idx >> 5, k4 = (idx & 31) << 2;
      *(float4*)&pws[kk][k4] =
          *(const float4*)(pw + (size_t)(ks + kk) * 128 + k4);
    }
    __syncthreads();
#pragma unroll
    for (int ti = 0; ti < 13; ++ti) {
      int t = wv * 13 + ti;
      if (t < 49) {
        float s0 = 0.f, s1 = 0.f;
        for (int k = 0; k < 64; ++k) {
          float ovv = os[t][ks + k];
          float2 w2v = *(const float2*)&pws[k][lane * 2];
          s0 += ovv * w2v.x;
          s1 += ovv * w2v.y;
        }
        a0[ti] += s0; a1[ti] += s1;
      }
    }
  }
  float2 pbv = *(const float2*)(pb + lane * 2);
  float2 lgv = *(const float2*)(lg + lane * 2);
  float2 lbv = *(const float2*)(lb + lane * 2);
#pragma unroll
  for (int ti = 0; ti < 13; ++ti) {
    int t = wv * 13 + ti;
    if (t < 49) {
      float y0 = a0[ti] + pbv.x, y1 = a1[ti] + pbv.y;
      float s = y0 + y1, sq = y0 * y0 + y1 * y1;
#pragma unroll
      for (int off = 1; off < 64; off <<= 1) {
        s += __shfl_xor(s, off);
        sq += __shfl_xor(sq, off);
      }
      float mu = s * kInvC, var = sq * kInvC - mu * mu;
      float rs = rsqrtf(var + kEps);
      y0 = (y0 - mu) * rs * lgv.x + lbv.x;
      y1 = (y1 - mu) * rs * lgv.y + lbv.y;
      y0 = gelu_exact(y0);
      y1 = gelu_exact(y1);
      int r = t / 7, c = t - (t / 7) * 7;
      int hs = whi * 7 + r + 3; if (hs >= 56) hs -= 56;
      int wsd = wwi * 7 + c + 3; if (wsd >= 56) wsd -= 56;
      size_t row = ((size_t)bb * 3136 + hs * 56 + wsd) * 128;
      float2 xv = *(const float2*)(x + row + lane * 2);
      float2 o2;
      o2.x = xv.x + y0;
      o2.y = xv.y + y1;
      *(float2*)(xres + row + lane * 2) = o2;
    }
  }
}

extern "C" void kernel_launch(void* const* d_in, const int* in_sizes, int n_in,
                              void* d_out, int out_size, void* d_ws,
                              size_t ws_size, hipStream_t stream) {
  (void)in_sizes; (void)n_in; (void)out_size; (void)ws_size;
  const float* x      = (const float*)d_in[0];
  const float* qkv_w  = (const float*)d_in[1];
  const float* qkv_b  = (const float*)d_in[2];
  const float* proj_w = (const float*)d_in[3];
  const float* proj_b = (const float*)d_in[4];
  const float* plg    = (const float*)d_in[5];
  const float* plb    = (const float*)d_in[6];
  const float* rpb    = (const float*)d_in[7];
  const float* n1g    = (const float*)d_in[8];
  const float* n1b    = (const float*)d_in[9];
  const float* n2g    = (const float*)d_in[10];
  const float* n2b    = (const float*)d_in[11];
  const float* w1     = (const float*)d_in[12];
  const float* b1     = (const float*)d_in[13];
  const float* w2     = (const float*)d_in[14];
  const float* b2     = (const float*)d_in[15];
  float* out = (float*)d_out;

  // ws layout (ushort units), total 231.6 MB
  ushort* wp   = (ushort*)d_ws;                         // 100352*128 (LN1; reused as LN2 out)
  ushort* qkvb = wp + (size_t)100352 * 128;             // 100352*384
  ushort* obb  = qkvb + (size_t)100352 * 384;           // 100352*128
  ushort* hb   = obb + (size_t)100352 * 128;            // 100352*512
  ushort* qkvT = hb + (size_t)100352 * 512;             // 384*128
  ushort* w1T  = qkvT + 384 * 128;                      // 512*128
  ushort* w2T  = w1T + 512 * 128;                       // 128*512

  k_prep<<<704, 256, 0, stream>>>(qkv_w, w1, w2, qkvT, w1T, w2T);
  k_ln1_part<<<25088, 256, 0, stream>>>(x, n1g, n1b, wp);
  k_gemm<128, 0><<<dim3(784, 3), 256, 0, stream>>>(wp, qkvT, qkv_b, nullptr, qkvb);
  k_attn<<<8192, 256, 0, stream>>>(qkvb, rpb, obb);
  k_proj<<<2048, 256, 0, stream>>>(obb, proj_w, proj_b, plg, plb, x, out);
  k_ln2<<<25088, 256, 0, stream>>>(out, n2g, n2b, wp);
  k_gemm<128, 1><<<dim3(784, 4), 256, 0, stream>>>(wp, w1T, b1, nullptr, hb);
  k_gemm<512, 2><<<dim3(784, 1), 256, 0, stream>>>(hb, w2T, b2, out, out);
}

// Round 3
// 514.633 us; speedup vs baseline: 2.8029x; 1.1179x over previous
//
#include <hip/hip_runtime.h>
#include <cstdint>
#include <cstddef>

typedef __attribute__((ext_vector_type(8))) short bf16x8;
typedef __attribute__((ext_vector_type(4))) float f32x4;

namespace {
constexpr float kScale = 0.17677669529663689f; // 32^-0.5
constexpr float kEps = 1e-6f;
constexpr float kInvC = 1.0f / 128.0f;

__device__ __forceinline__ float gelu_exact(float v) {
  return 0.5f * v * (1.0f + erff(v * 0.70710678118654752f));
}
__device__ __forceinline__ ushort f2bf(float f) {
  uint32_t u = __builtin_bit_cast(uint32_t, f);
  u += 0x7FFFu + ((u >> 16) & 1u);
  return (ushort)(u >> 16);
}
__device__ __forceinline__ float bf2f(ushort u) {
  return __builtin_bit_cast(float, (uint32_t)u << 16);
}
} // namespace

// ---------------------------------------------------------------------------
// K0: convert+transpose weights to bf16 [N][K] layout.
// qkvT[384][128], w1T[512][128], w2T[128][512], projT[128][128]
// ---------------------------------------------------------------------------
__global__ __launch_bounds__(256) void k_prep(
    const float* __restrict__ qkv_w, const float* __restrict__ w1,
    const float* __restrict__ w2, const float* __restrict__ pw,
    ushort* __restrict__ qkvT, ushort* __restrict__ w1T,
    ushort* __restrict__ w2T, ushort* __restrict__ projT) {
  int i = blockIdx.x * 256 + threadIdx.x;
  if (i < 49152) {
    int n = i >> 7, k = i & 127;
    qkvT[i] = f2bf(qkv_w[k * 384 + n]);
  } else if (i < 114688) {
    int j = i - 49152;
    int n = j >> 7, k = j & 127;
    w1T[j] = f2bf(w1[k * 512 + n]);
  } else if (i < 180224) {
    int j = i - 114688;
    int n = j >> 9, k = j & 511;
    w2T[j] = f2bf(w2[k * 128 + n]);
  } else if (i < 196608) {
    int j = i - 180224;
    int n = j >> 7, k = j & 127;
    projT[j] = f2bf(pw[k * 128 + n]);
  }
}

// ---------------------------------------------------------------------------
// K1: LN(norm1) + cyclic shift(-3,-3) + window partition -> bf16
// ---------------------------------------------------------------------------
__global__ __launch_bounds__(256) void k_ln1_part(
    const float* __restrict__ x, const float* __restrict__ g,
    const float* __restrict__ b, ushort* __restrict__ wp) {
  int wv = threadIdx.x >> 6, lane = threadIdx.x & 63;
  int tok = blockIdx.x * 4 + wv;               // 0..100351
  int win = tok / 49, n = tok - win * 49;
  int bb = win >> 6, wi = win & 63;
  int whi = wi >> 3, wwi = wi & 7;
  int r = n / 7, c = n - r * 7;
  int hs = whi * 7 + r + 3; if (hs >= 56) hs -= 56;
  int ws = wwi * 7 + c + 3; if (ws >= 56) ws -= 56;
  size_t src = ((size_t)bb * 3136 + hs * 56 + ws) * 128;
  float2 v = *(const float2*)(x + src + lane * 2);
  float s = v.x + v.y, sq = v.x * v.x + v.y * v.y;
#pragma unroll
  for (int off = 1; off < 64; off <<= 1) {
    s += __shfl_xor(s, off);
    sq += __shfl_xor(sq, off);
  }
  float mu = s * kInvC;
  float var = sq * kInvC - mu * mu;
  float rs = rsqrtf(var + kEps);
  float2 gg = *(const float2*)(g + lane * 2);
  float2 bv = *(const float2*)(b + lane * 2);
  float o0 = (v.x - mu) * rs * gg.x + bv.x;
  float o1 = (v.y - mu) * rs * gg.y + bv.y;
  uint p = (uint)f2bf(o0) | ((uint)f2bf(o1) << 16);
  ((uint*)wp)[(size_t)tok * 64 + lane] = p;
}

// ---------------------------------------------------------------------------
// K-LN2: LN(norm2) on xres (d_out) -> bf16 m
// ---------------------------------------------------------------------------
__global__ __launch_bounds__(256) void k_ln2(
    const float* __restrict__ x, const float* __restrict__ g,
    const float* __restrict__ b, ushort* __restrict__ m) {
  int wv = threadIdx.x >> 6, lane = threadIdx.x & 63;
  int tok = blockIdx.x * 4 + wv;
  float2 v = *(const float2*)(x + (size_t)tok * 128 + lane * 2);
  float s = v.x + v.y, sq = v.x * v.x + v.y * v.y;
#pragma unroll
  for (int off = 1; off < 64; off <<= 1) {
    s += __shfl_xor(s, off);
    sq += __shfl_xor(sq, off);
  }
  float mu = s * kInvC;
  float var = sq * kInvC - mu * mu;
  float rs = rsqrtf(var + kEps);
  float2 gg = *(const float2*)(g + lane * 2);
  float2 bv = *(const float2*)(b + lane * 2);
  float o0 = (v.x - mu) * rs * gg.x + bv.x;
  float o1 = (v.y - mu) * rs * gg.y + bv.y;
  uint p = (uint)f2bf(o0) | ((uint)f2bf(o1) << 16);
  ((uint*)m)[(size_t)tok * 64 + lane] = p;
}

// ---------------------------------------------------------------------------
// K-GEMM: C[M,N] = A[M,K](bf16) @ BT[N,K](bf16)^T, 128x128 tile, BK=64,
// 4 waves each 64x64 via 4x4 frags of mfma_f32_16x16x32_bf16.
// EPI 0: +bias -> bf16   EPI 1: gelu(+bias) -> bf16   EPI 2: +bias+res -> f32
// ---------------------------------------------------------------------------
template <int K, int EPI>
__global__ __launch_bounds__(256) void k_gemm(
    const ushort* __restrict__ A, const ushort* __restrict__ BT,
    const float* __restrict__ bias, const float* __restrict__ res,
    void* __restrict__ Cout) {
  __shared__ ushort As[128][72];  // [row][k], +8 pad -> 2-way (free) on b128
  __shared__ ushort Bs[128][72];  // [col][k]
  int tid = threadIdx.x;
  int mBase = blockIdx.x << 7;
  int nBase = blockIdx.y << 7;
  int lane = tid & 63, wid = tid >> 6;
  int wr = (wid >> 1) << 6, wc = (wid & 1) << 6;
  f32x4 acc[4][4] = {};
  for (int ks = 0; ks < K; ks += 64) {
#pragma unroll
    for (int l = 0; l < 4; ++l) {
      int c = tid + l * 256;
      int row = c >> 3, k8 = (c & 7) << 3;
      *(bf16x8*)&As[row][k8] =
          *(const bf16x8*)(A + (size_t)(mBase + row) * K + ks + k8);
      *(bf16x8*)&Bs[row][k8] =
          *(const bf16x8*)(BT + (size_t)(nBase + row) * K + ks + k8);
    }
    __syncthreads();
#pragma unroll
    for (int ksub = 0; ksub < 64; ksub += 32) {
      int kloc = ksub + ((lane >> 4) << 3);
      bf16x8 af[4], bfr[4];
#pragma unroll
      for (int m = 0; m < 4; ++m)
        af[m] = *(const bf16x8*)&As[wr + m * 16 + (lane & 15)][kloc];
#pragma unroll
      for (int n = 0; n < 4; ++n)
        bfr[n] = *(const bf16x8*)&Bs[wc + n * 16 + (lane & 15)][kloc];
#pragma unroll
      for (int m = 0; m < 4; ++m)
#pragma unroll
        for (int n = 0; n < 4; ++n)
          acc[m][n] = __builtin_amdgcn_mfma_f32_16x16x32_bf16(
              af[m], bfr[n], acc[m][n], 0, 0, 0);
    }
    __syncthreads();
  }
  int ldC = (int)(gridDim.y << 7);
#pragma unroll
  for (int n = 0; n < 4; ++n) {
    int cg = nBase + wc + n * 16 + (lane & 15);
    float bv = bias[cg];
#pragma unroll
    for (int m = 0; m < 4; ++m) {
      int rbase = mBase + wr + m * 16 + ((lane >> 4) << 2);
#pragma unroll
      for (int r = 0; r < 4; ++r) {
        float v = acc[m][n][r] + bv;
        size_t off = (size_t)(rbase + r) * ldC + cg;
        if (EPI == 0) {
          ((ushort*)Cout)[off] = f2bf(v);
        } else if (EPI == 1) {
          ((ushort*)Cout)[off] = f2bf(gelu_exact(v));
        } else {
          ((float*)Cout)[off] = v + res[off];
        }
      }
    }
  }
}

// ---------------------------------------------------------------------------
// K-PGEMM: fused proj: o[M,128] @ projT^T + pb -> row-LN(proj_ln) -> GELU
//          -> reverse window partition + reverse shift + residual -> out(f32)
// One 128x128 tile per block = full output rows, so LN is block-local.
// ---------------------------------------------------------------------------
__global__ __launch_bounds__(256) void k_pgemm(
    const ushort* __restrict__ A, const ushort* __restrict__ BT,
    const float* __restrict__ pb, const float* __restrict__ lg,
    const float* __restrict__ lb, const float* __restrict__ x,
    float* __restrict__ out) {
  __shared__ ushort As[128][72];
  __shared__ ushort Bs[128][72];
  __shared__ float red[4][64][2];
  int tid = threadIdx.x;
  int mBase = blockIdx.x << 7;
  int lane = tid & 63, wid = tid >> 6;
  int wr = (wid >> 1) << 6, wc = (wid & 1) << 6;
  f32x4 acc[4][4] = {};
  for (int ks = 0; ks < 128; ks += 64) {
#pragma unroll
    for (int l = 0; l < 4; ++l) {
      int c = tid + l * 256;
      int row = c >> 3, k8 = (c & 7) << 3;
      *(bf16x8*)&As[row][k8] =
          *(const bf16x8*)(A + (size_t)(mBase + row) * 128 + ks + k8);
      *(bf16x8*)&Bs[row][k8] =
          *(const bf16x8*)(BT + (size_t)row * 128 + ks + k8);
    }
    __syncthreads();
#pragma unroll
    for (int ksub = 0; ksub < 64; ksub += 32) {
      int kloc = ksub + ((lane >> 4) << 3);
      bf16x8 af[4], bfr[4];
#pragma unroll
      for (int m = 0; m < 4; ++m)
        af[m] = *(const bf16x8*)&As[wr + m * 16 + (lane & 15)][kloc];
#pragma unroll
      for (int n = 0; n < 4; ++n)
        bfr[n] = *(const bf16x8*)&Bs[wc + n * 16 + (lane & 15)][kloc];
#pragma unroll
      for (int m = 0; m < 4; ++m)
#pragma unroll
        for (int n = 0; n < 4; ++n)
          acc[m][n] = __builtin_amdgcn_mfma_f32_16x16x32_bf16(
              af[m], bfr[n], acc[m][n], 0, 0, 0);
    }
    __syncthreads();
  }
  // epilogue: bias add + row-LN partials
  float pbv[4], lgv[4], lbv[4];
#pragma unroll
  for (int n = 0; n < 4; ++n) {
    int cg = wc + n * 16 + (lane & 15);
    pbv[n] = pb[cg]; lgv[n] = lg[cg]; lbv[n] = lb[cg];
  }
  float ps[4][4], psq[4][4];
#pragma unroll
  for (int m = 0; m < 4; ++m)
#pragma unroll
    for (int r = 0; r < 4; ++r) {
      float s = 0.f, q = 0.f;
#pragma unroll
      for (int n = 0; n < 4; ++n) {
        float v = acc[m][n][r] + pbv[n];
        s += v; q += v * v;
      }
#pragma unroll
      for (int off = 1; off < 16; off <<= 1) {
        s += __shfl_xor(s, off);
        q += __shfl_xor(q, off);
      }
      ps[m][r] = s; psq[m][r] = q;
    }
  if ((lane & 15) == 0) {
#pragma unroll
    for (int m = 0; m < 4; ++m)
#pragma unroll
      for (int r = 0; r < 4; ++r) {
        int rl = m * 16 + ((lane >> 4) << 2) + r;
        red[wid][rl][0] = ps[m][r];
        red[wid][rl][1] = psq[m][r];
      }
  }
  __syncthreads();
#pragma unroll
  for (int m = 0; m < 4; ++m) {
#pragma unroll
    for (int r = 0; r < 4; ++r) {
      int rl = m * 16 + ((lane >> 4) << 2) + r;
      float s = ps[m][r] + red[wid ^ 1][rl][0];
      float q = psq[m][r] + red[wid ^ 1][rl][1];
      float mu = s * kInvC, var = q * kInvC - mu * mu;
      float rs = rsqrtf(var + kEps);
      int t = mBase + wr + rl;
      int win = t / 49, nn = t - win * 49;
      int bb = win >> 6, wi = win & 63;
      int whi = wi >> 3, wwi = wi & 7;
      int r7 = nn / 7, c7 = nn - r7 * 7;
      int hs = whi * 7 + r7 + 3; if (hs >= 56) hs -= 56;
      int wsd = wwi * 7 + c7 + 3; if (wsd >= 56) wsd -= 56;
      size_t rowb = ((size_t)bb * 3136 + hs * 56 + wsd) * 128;
#pragma unroll
      for (int n = 0; n < 4; ++n) {
        int cg = wc + n * 16 + (lane & 15);
        float y = (acc[m][n][r] + pbv[n] - mu) * rs * lgv[n] + lbv[n];
        y = gelu_exact(y);
        out[rowb + cg] = x[rowb + cg] + y;
      }
    }
  }
}

// ---------------------------------------------------------------------------
// K3: per-(window, head) attention (bf16 qkv in, bf16 o out)
// wave-parallel double softmax, float4 QK^T.
// ---------------------------------------------------------------------------
__global__ __launch_bounds__(256) void k_attn(
    const ushort* __restrict__ qkv, const float* __restrict__ rpb,
    ushort* __restrict__ ob) {
  int win = blockIdx.x >> 2, head = blockIdx.x & 3;
  int wi = win & 63, whi = wi >> 3, wwi = wi & 7;
  __shared__ float qs[49][44], ks[49][44], vs[49][44]; // pad 44: 16B-aligned f4
  __shared__ float at[49][50];
  __shared__ int lab[49];
  int tid = threadIdx.x;
  const ushort* base = qkv + (size_t)win * 49 * 384 + head * 32;
  for (int idx = tid; idx < 784; idx += 256) {
    int n = idx >> 4, d2 = (idx & 15) << 1;
    const ushort* row = base + (size_t)n * 384;
    uint q2 = *(const uint*)(row + d2);
    uint k2 = *(const uint*)(row + 128 + d2);
    uint v2 = *(const uint*)(row + 256 + d2);
    qs[n][d2]     = bf2f((ushort)(q2 & 0xffff)) * kScale;
    qs[n][d2 + 1] = bf2f((ushort)(q2 >> 16)) * kScale;
    ks[n][d2]     = bf2f((ushort)(k2 & 0xffff));
    ks[n][d2 + 1] = bf2f((ushort)(k2 >> 16));
    vs[n][d2]     = bf2f((ushort)(v2 & 0xffff));
    vs[n][d2 + 1] = bf2f((ushort)(v2 >> 16));
  }
  if (tid < 49) {
    int r = tid / 7, c = tid - (tid / 7) * 7;
    int hh = whi * 7 + r, ww = wwi * 7 + c;
    int rh = (hh < 49) ? 0 : ((hh < 53) ? 1 : 2);
    int rw = (ww < 49) ? 0 : ((ww < 53) ? 1 : 2);
    lab[tid] = rh * 3 + rw;
  }
  __syncthreads();
  for (int idx = tid; idx < 2401; idx += 256) {
    int i = idx / 49, j = idx - i * 49;
    float4 s4 = {0.f, 0.f, 0.f, 0.f};
#pragma unroll
    for (int d = 0; d < 32; d += 4) {
      float4 a = *(const float4*)&qs[i][d];
      float4 b = *(const float4*)&ks[j][d];
      s4.x += a.x * b.x; s4.y += a.y * b.y;
      s4.z += a.z * b.z; s4.w += a.w * b.w;
    }
    float s = (s4.x + s4.y) + (s4.z + s4.w);
    int ri = i / 7, ci = i - ri * 7, rj = j / 7, cj = j - rj * 7;
    int ridx = (ri - rj + 6) * 13 + (ci - cj + 6);
    s += rpb[ridx * 4 + head];
    s += (lab[i] != lab[j]) ? -100.0f : 0.0f;
    at[i][j] = s;
  }
  __syncthreads();
  {
    int r = tid >> 2, sub = tid & 3;
    if (r < 49) {
#pragma unroll
      for (int pass = 0; pass < 2; ++pass) {
        float m = -1e30f;
        for (int j = sub; j < 49; j += 4) m = fmaxf(m, at[r][j]);
        m = fmaxf(m, __shfl_xor(m, 1));
        m = fmaxf(m, __shfl_xor(m, 2));
        float sum = 0.f;
        for (int j = sub; j < 49; j += 4) {
          float e = expf(at[r][j] - m);
          at[r][j] = e;
          sum += e;
        }
        sum += __shfl_xor(sum, 1);
        sum += __shfl_xor(sum, 2);
        float inv = 1.0f / sum;
        for (int j = sub; j < 49; j += 4) at[r][j] *= inv;
      }
    }
  }
  __syncthreads();
  for (int idx = tid; idx < 1568; idx += 256) {
    int i = idx >> 5, d = idx & 31;
    float s = 0.f;
#pragma unroll
    for (int j = 0; j < 49; ++j) s += at[i][j] * vs[j][d];
    ob[((size_t)win * 49 + i) * 128 + head * 32 + d] = f2bf(s);
  }
}

extern "C" void kernel_launch(void* const* d_in, const int* in_sizes, int n_in,
                              void* d_out, int out_size, void* d_ws,
                              size_t ws_size, hipStream_t stream) {
  (void)in_sizes; (void)n_in; (void)out_size; (void)ws_size;
  const float* x      = (const float*)d_in[0];
  const float* qkv_w  = (const float*)d_in[1];
  const float* qkv_b  = (const float*)d_in[2];
  const float* proj_w = (const float*)d_in[3];
  const float* proj_b = (const float*)d_in[4];
  const float* plg    = (const float*)d_in[5];
  const float* plb    = (const float*)d_in[6];
  const float* rpb    = (const float*)d_in[7];
  const float* n1g    = (const float*)d_in[8];
  const float* n1b    = (const float*)d_in[9];
  const float* n2g    = (const float*)d_in[10];
  const float* n2b    = (const float*)d_in[11];
  const float* w1     = (const float*)d_in[12];
  const float* b1     = (const float*)d_in[13];
  const float* w2     = (const float*)d_in[14];
  const float* b2     = (const float*)d_in[15];
  float* out = (float*)d_out;

  // ws layout (ushort units), total ~232 MB
  ushort* wp   = (ushort*)d_ws;                         // 100352*128 (LN1; reused as LN2 out)
  ushort* qkvb = wp + (size_t)100352 * 128;             // 100352*384
  ushort* obb  = qkvb + (size_t)100352 * 384;           // 100352*128
  ushort* hb   = obb + (size_t)100352 * 128;            // 100352*512
  ushort* qkvT = hb + (size_t)100352 * 512;             // 384*128
  ushort* w1T  = qkvT + 384 * 128;                      // 512*128
  ushort* w2T  = w1T + 512 * 128;                       // 128*512
  ushort* pT   = w2T + 128 * 512;                       // 128*128

  k_prep<<<768, 256, 0, stream>>>(qkv_w, w1, w2, proj_w, qkvT, w1T, w2T, pT);
  k_ln1_part<<<25088, 256, 0, stream>>>(x, n1g, n1b, wp);
  k_gemm<128, 0><<<dim3(784, 3), 256, 0, stream>>>(wp, qkvT, qkv_b, nullptr, qkvb);
  k_attn<<<8192, 256, 0, stream>>>(qkvb, rpb, obb);
  k_pgemm<<<784, 256, 0, stream>>>(obb, pT, proj_b, plg, plb, x, out);
  k_ln2<<<25088, 256, 0, stream>>>(out, n2g, n2b, wp);
  k_gemm<128, 1><<<dim3(784, 4), 256, 0, stream>>>(wp, w1T, b1, nullptr, hb);
  k_gemm<512, 2><<<dim3(784, 1), 256, 0, stream>>>(hb, w2T, b2, out, out);
}

// Round 4
// 402.946 us; speedup vs baseline: 3.5798x; 1.2772x over previous
//
#include <hip/hip_runtime.h>
#include <cstdint>
#include <cstddef>

typedef __attribute__((ext_vector_type(8))) short bf16x8;
typedef __attribute__((ext_vector_type(4))) float f32x4;

namespace {
constexpr float kScale = 0.17677669529663689f; // 32^-0.5
constexpr float kEps = 1e-6f;
constexpr float kInvC = 1.0f / 128.0f;

__device__ __forceinline__ float gelu_exact(float v) {
  return 0.5f * v * (1.0f + erff(v * 0.70710678118654752f));
}
__device__ __forceinline__ ushort f2bf(float f) {
  uint32_t u = __builtin_bit_cast(uint32_t, f);
  u += 0x7FFFu + ((u >> 16) & 1u);
  return (ushort)(u >> 16);
}
__device__ __forceinline__ float bf2f(ushort u) {
  return __builtin_bit_cast(float, (uint32_t)u << 16);
}
} // namespace

// ---------------------------------------------------------------------------
// K0: convert+transpose weights to bf16 [N][K] layout.
// ---------------------------------------------------------------------------
__global__ __launch_bounds__(256) void k_prep(
    const float* __restrict__ qkv_w, const float* __restrict__ w1,
    const float* __restrict__ w2, const float* __restrict__ pw,
    ushort* __restrict__ qkvT, ushort* __restrict__ w1T,
    ushort* __restrict__ w2T, ushort* __restrict__ projT) {
  int i = blockIdx.x * 256 + threadIdx.x;
  if (i < 49152) {
    int n = i >> 7, k = i & 127;
    qkvT[i] = f2bf(qkv_w[k * 384 + n]);
  } else if (i < 114688) {
    int j = i - 49152;
    int n = j >> 7, k = j & 127;
    w1T[j] = f2bf(w1[k * 512 + n]);
  } else if (i < 180224) {
    int j = i - 114688;
    int n = j >> 9, k = j & 511;
    w2T[j] = f2bf(w2[k * 128 + n]);
  } else if (i < 196608) {
    int j = i - 180224;
    int n = j >> 7, k = j & 127;
    projT[j] = f2bf(pw[k * 128 + n]);
  }
}

// ---------------------------------------------------------------------------
// K0b: precompute bias+mask table TB[type(4)][head(4)][j(64)][i(64)] f32.
// type = ((whi==7)<<1) | (wwi==7). Padding (i>=49 || j>=49) = 0.
// ---------------------------------------------------------------------------
__global__ __launch_bounds__(256) void k_prep2(
    const float* __restrict__ rpb, float* __restrict__ TB) {
  int e = blockIdx.x * 256 + threadIdx.x;  // < 65536
  int i = e & 63, j = (e >> 6) & 63, h = (e >> 12) & 3, type = e >> 14;
  float v = 0.f;
  if (i < 49 && j < 49) {
    int ri = i / 7, ci = i - ri * 7, rj = j / 7, cj = j - rj * 7;
    int ridx = (ri - rj + 6) * 13 + (ci - cj + 6);
    float bias = rpb[ridx * 4 + h];
    int th = type >> 1, tw = type & 1;
    int labi = (th ? ((ri < 4) ? 1 : 2) : 0) * 3 + (tw ? ((ci < 4) ? 1 : 2) : 0);
    int labj = (th ? ((rj < 4) ? 1 : 2) : 0) * 3 + (tw ? ((cj < 4) ? 1 : 2) : 0);
    v = bias + ((labi != labj) ? -100.f : 0.f);
  }
  TB[e] = v;
}

// ---------------------------------------------------------------------------
// K1: LN(norm1) + cyclic shift(-3,-3) + window partition -> bf16
// ---------------------------------------------------------------------------
__global__ __launch_bounds__(256) void k_ln1_part(
    const float* __restrict__ x, const float* __restrict__ g,
    const float* __restrict__ b, ushort* __restrict__ wp) {
  int wv = threadIdx.x >> 6, lane = threadIdx.x & 63;
  int tok = blockIdx.x * 4 + wv;               // 0..100351
  int win = tok / 49, n = tok - win * 49;
  int bb = win >> 6, wi = win & 63;
  int whi = wi >> 3, wwi = wi & 7;
  int r = n / 7, c = n - r * 7;
  int hs = whi * 7 + r + 3; if (hs >= 56) hs -= 56;
  int ws = wwi * 7 + c + 3; if (ws >= 56) ws -= 56;
  size_t src = ((size_t)bb * 3136 + hs * 56 + ws) * 128;
  float2 v = *(const float2*)(x + src + lane * 2);
  float s = v.x + v.y, sq = v.x * v.x + v.y * v.y;
#pragma unroll
  for (int off = 1; off < 64; off <<= 1) {
    s += __shfl_xor(s, off);
    sq += __shfl_xor(sq, off);
  }
  float mu = s * kInvC;
  float var = sq * kInvC - mu * mu;
  float rs = rsqrtf(var + kEps);
  float2 gg = *(const float2*)(g + lane * 2);
  float2 bv = *(const float2*)(b + lane * 2);
  float o0 = (v.x - mu) * rs * gg.x + bv.x;
  float o1 = (v.y - mu) * rs * gg.y + bv.y;
  uint p = (uint)f2bf(o0) | ((uint)f2bf(o1) << 16);
  ((uint*)wp)[(size_t)tok * 64 + lane] = p;
}

// ---------------------------------------------------------------------------
// K-LN2: LN(norm2) on xres (d_out) -> bf16 m
// ---------------------------------------------------------------------------
__global__ __launch_bounds__(256) void k_ln2(
    const float* __restrict__ x, const float* __restrict__ g,
    const float* __restrict__ b, ushort* __restrict__ m) {
  int wv = threadIdx.x >> 6, lane = threadIdx.x & 63;
  int tok = blockIdx.x * 4 + wv;
  float2 v = *(const float2*)(x + (size_t)tok * 128 + lane * 2);
  float s = v.x + v.y, sq = v.x * v.x + v.y * v.y;
#pragma unroll
  for (int off = 1; off < 64; off <<= 1) {
    s += __shfl_xor(s, off);
    sq += __shfl_xor(sq, off);
  }
  float mu = s * kInvC;
  float var = sq * kInvC - mu * mu;
  float rs = rsqrtf(var + kEps);
  float2 gg = *(const float2*)(g + lane * 2);
  float2 bv = *(const float2*)(b + lane * 2);
  float o0 = (v.x - mu) * rs * gg.x + bv.x;
  float o1 = (v.y - mu) * rs * gg.y + bv.y;
  uint p = (uint)f2bf(o0) | ((uint)f2bf(o1) << 16);
  ((uint*)m)[(size_t)tok * 64 + lane] = p;
}

// ---------------------------------------------------------------------------
// K-GEMM: C[M,N] = A[M,K](bf16) @ BT[N,K](bf16)^T, 128x128 tile, BK=64.
// EPI 0: +bias -> bf16   EPI 1: gelu(+bias) -> bf16   EPI 2: +bias+res -> f32
// ---------------------------------------------------------------------------
template <int K, int EPI>
__global__ __launch_bounds__(256) void k_gemm(
    const ushort* __restrict__ A, const ushort* __restrict__ BT,
    const float* __restrict__ bias, const float* __restrict__ res,
    void* __restrict__ Cout) {
  __shared__ ushort As[128][72];
  __shared__ ushort Bs[128][72];
  int tid = threadIdx.x;
  int mBase = blockIdx.x << 7;
  int nBase = blockIdx.y << 7;
  int lane = tid & 63, wid = tid >> 6;
  int wr = (wid >> 1) << 6, wc = (wid & 1) << 6;
  f32x4 acc[4][4] = {};
  for (int ks = 0; ks < K; ks += 64) {
#pragma unroll
    for (int l = 0; l < 4; ++l) {
      int c = tid + l * 256;
      int row = c >> 3, k8 = (c & 7) << 3;
      *(bf16x8*)&As[row][k8] =
          *(const bf16x8*)(A + (size_t)(mBase + row) * K + ks + k8);
      *(bf16x8*)&Bs[row][k8] =
          *(const bf16x8*)(BT + (size_t)(nBase + row) * K + ks + k8);
    }
    __syncthreads();
#pragma unroll
    for (int ksub = 0; ksub < 64; ksub += 32) {
      int kloc = ksub + ((lane >> 4) << 3);
      bf16x8 af[4], bfr[4];
#pragma unroll
      for (int m = 0; m < 4; ++m)
        af[m] = *(const bf16x8*)&As[wr + m * 16 + (lane & 15)][kloc];
#pragma unroll
      for (int n = 0; n < 4; ++n)
        bfr[n] = *(const bf16x8*)&Bs[wc + n * 16 + (lane & 15)][kloc];
#pragma unroll
      for (int m = 0; m < 4; ++m)
#pragma unroll
        for (int n = 0; n < 4; ++n)
          acc[m][n] = __builtin_amdgcn_mfma_f32_16x16x32_bf16(
              af[m], bfr[n], acc[m][n], 0, 0, 0);
    }
    __syncthreads();
  }
  int ldC = (int)(gridDim.y << 7);
#pragma unroll
  for (int n = 0; n < 4; ++n) {
    int cg = nBase + wc + n * 16 + (lane & 15);
    float bv = bias[cg];
#pragma unroll
    for (int m = 0; m < 4; ++m) {
      int rbase = mBase + wr + m * 16 + ((lane >> 4) << 2);
#pragma unroll
      for (int r = 0; r < 4; ++r) {
        float v = acc[m][n][r] + bv;
        size_t off = (size_t)(rbase + r) * ldC + cg;
        if (EPI == 0) {
          ((ushort*)Cout)[off] = f2bf(v);
        } else if (EPI == 1) {
          ((ushort*)Cout)[off] = f2bf(gelu_exact(v));
        } else {
          ((float*)Cout)[off] = v + res[off];
        }
      }
    }
  }
}

// ---------------------------------------------------------------------------
// K-PGEMM: fused proj GEMM + bias + row-LN + GELU + reverse shift + residual.
// ---------------------------------------------------------------------------
__global__ __launch_bounds__(256) void k_pgemm(
    const ushort* __restrict__ A, const ushort* __restrict__ BT,
    const float* __restrict__ pb, const float* __restrict__ lg,
    const float* __restrict__ lb, const float* __restrict__ x,
    float* __restrict__ out) {
  __shared__ ushort As[128][72];
  __shared__ ushort Bs[128][72];
  __shared__ float red[4][64][2];
  int tid = threadIdx.x;
  int mBase = blockIdx.x << 7;
  int lane = tid & 63, wid = tid >> 6;
  int wr = (wid >> 1) << 6, wc = (wid & 1) << 6;
  f32x4 acc[4][4] = {};
  for (int ks = 0; ks < 128; ks += 64) {
#pragma unroll
    for (int l = 0; l < 4; ++l) {
      int c = tid + l * 256;
      int row = c >> 3, k8 = (c & 7) << 3;
      *(bf16x8*)&As[row][k8] =
          *(const bf16x8*)(A + (size_t)(mBase + row) * 128 + ks + k8);
      *(bf16x8*)&Bs[row][k8] =
          *(const bf16x8*)(BT + (size_t)row * 128 + ks + k8);
    }
    __syncthreads();
#pragma unroll
    for (int ksub = 0; ksub < 64; ksub += 32) {
      int kloc = ksub + ((lane >> 4) << 3);
      bf16x8 af[4], bfr[4];
#pragma unroll
      for (int m = 0; m < 4; ++m)
        af[m] = *(const bf16x8*)&As[wr + m * 16 + (lane & 15)][kloc];
#pragma unroll
      for (int n = 0; n < 4; ++n)
        bfr[n] = *(const bf16x8*)&Bs[wc + n * 16 + (lane & 15)][kloc];
#pragma unroll
      for (int m = 0; m < 4; ++m)
#pragma unroll
        for (int n = 0; n < 4; ++n)
          acc[m][n] = __builtin_amdgcn_mfma_f32_16x16x32_bf16(
              af[m], bfr[n], acc[m][n], 0, 0, 0);
    }
    __syncthreads();
  }
  float pbv[4], lgv[4], lbv[4];
#pragma unroll
  for (int n = 0; n < 4; ++n) {
    int cg = wc + n * 16 + (lane & 15);
    pbv[n] = pb[cg]; lgv[n] = lg[cg]; lbv[n] = lb[cg];
  }
  float ps[4][4], psq[4][4];
#pragma unroll
  for (int m = 0; m < 4; ++m)
#pragma unroll
    for (int r = 0; r < 4; ++r) {
      float s = 0.f, q = 0.f;
#pragma unroll
      for (int n = 0; n < 4; ++n) {
        float v = acc[m][n][r] + pbv[n];
        s += v; q += v * v;
      }
#pragma unroll
      for (int off = 1; off < 16; off <<= 1) {
        s += __shfl_xor(s, off);
        q += __shfl_xor(q, off);
      }
      ps[m][r] = s; psq[m][r] = q;
    }
  if ((lane & 15) == 0) {
#pragma unroll
    for (int m = 0; m < 4; ++m)
#pragma unroll
      for (int r = 0; r < 4; ++r) {
        int rl = m * 16 + ((lane >> 4) << 2) + r;
        red[wid][rl][0] = ps[m][r];
        red[wid][rl][1] = psq[m][r];
      }
  }
  __syncthreads();
#pragma unroll
  for (int m = 0; m < 4; ++m) {
#pragma unroll
    for (int r = 0; r < 4; ++r) {
      int rl = m * 16 + ((lane >> 4) << 2) + r;
      float s = ps[m][r] + red[wid ^ 1][rl][0];
      float q = psq[m][r] + red[wid ^ 1][rl][1];
      float mu = s * kInvC, var = q * kInvC - mu * mu;
      float rs = rsqrtf(var + kEps);
      int t = mBase + wr + rl;
      int win = t / 49, nn = t - win * 49;
      int bb = win >> 6, wi = win & 63;
      int whi = wi >> 3, wwi = wi & 7;
      int r7 = nn / 7, c7 = nn - r7 * 7;
      int hs = whi * 7 + r7 + 3; if (hs >= 56) hs -= 56;
      int wsd = wwi * 7 + c7 + 3; if (wsd >= 56) wsd -= 56;
      size_t rowb = ((size_t)bb * 3136 + hs * 56 + wsd) * 128;
#pragma unroll
      for (int n = 0; n < 4; ++n) {
        int cg = wc + n * 16 + (lane & 15);
        float y = (acc[m][n][r] + pbv[n] - mu) * rs * lgv[n] + lbv[n];
        y = gelu_exact(y);
        out[rowb + cg] = x[rowb + cg] + y;
      }
    }
  }
}

// ---------------------------------------------------------------------------
// K3: MFMA attention. 1 block = 1 window, 1 wave = 1 head.
// S^T = mfma(K, Q) so softmax axis (j) is the C-frag row coordinate.
// Double softmax in-register; P via LDS re-fragment; PV via mfma(P, V^T).
// ---------------------------------------------------------------------------
__global__ __launch_bounds__(256) void k_attn(
    const ushort* __restrict__ qkv, const float* __restrict__ TB,
    ushort* __restrict__ ob) {
  __shared__ ushort Pl[4][64][72];
  __shared__ ushort Vt[4][32][72];
  int tid = threadIdx.x;
  int lane = tid & 63, h = tid >> 6;
  int li = lane & 15, g = lane >> 4;
  int win = blockIdx.x;
  int wi = win & 63;
  int type = (((wi >> 3) == 7) ? 2 : 0) | (((wi & 7) == 7) ? 1 : 0);

  // --- QK^T: S^T[j][i], j = m*16 + g*4 + r, i = n*16 + li ---
  const ushort* qbase = qkv + (size_t)win * 49 * 384 + h * 32 + g * 8;
  bf16x8 kf[4], qf[4];
#pragma unroll
  for (int m = 0; m < 4; ++m) {
    kf[m] = *(const bf16x8*)(qbase + (size_t)(m * 16 + li) * 384 + 128);
    qf[m] = *(const bf16x8*)(qbase + (size_t)(m * 16 + li) * 384);
  }
  f32x4 zero = {0.f, 0.f, 0.f, 0.f};
  f32x4 st[4][4];
#pragma unroll
  for (int m = 0; m < 4; ++m)
#pragma unroll
    for (int n = 0; n < 4; ++n)
      st[m][n] = __builtin_amdgcn_mfma_f32_16x16x32_bf16(kf[m], qf[n], zero, 0, 0, 0);

  // --- V transpose into LDS: Vt[d][j] (zero j in [49,64)) ---
  if (lane < 49) {
#pragma unroll
    for (int dc = 0; dc < 4; ++dc) {
      bf16x8 vv = *(const bf16x8*)(qkv + ((size_t)win * 49 + lane) * 384 + 256 +
                                   h * 32 + dc * 8);
#pragma unroll
      for (int t = 0; t < 8; ++t) Vt[h][dc * 8 + t][lane] = (ushort)vv[t];
    }
  } else {
#pragma unroll
    for (int d = 0; d < 32; ++d) Vt[h][d][lane] = 0;
  }

  // --- bias+mask + double softmax (per i-row; j across m,r in-lane + g) ---
  const float* tb = TB + ((size_t)(type * 4 + h) << 12);
#pragma unroll
  for (int n = 0; n < 4; ++n) {
    int icol = n * 16 + li;
    float sv[3][4];
#pragma unroll
    for (int m = 0; m < 3; ++m)
#pragma unroll
      for (int r = 0; r < 4; ++r)
        sv[m][r] = st[m][n][r] * kScale + tb[(m * 16 + g * 4 + r) * 64 + icol];
    // m=3: only j=48 (g==0, r==0) is a real key position
    float sv3 = (g == 0) ? (st[3][n][0] * kScale + tb[48 * 64 + icol]) : -1e30f;
    // softmax pass 1
    float mx = sv3;
#pragma unroll
    for (int m = 0; m < 3; ++m)
#pragma unroll
      for (int r = 0; r < 4; ++r) mx = fmaxf(mx, sv[m][r]);
    mx = fmaxf(mx, __shfl_xor(mx, 16));
    mx = fmaxf(mx, __shfl_xor(mx, 32));
    float e[3][4], e3 = __expf(sv3 - mx);
    float sum = e3;
#pragma unroll
    for (int m = 0; m < 3; ++m)
#pragma unroll
      for (int r = 0; r < 4; ++r) { e[m][r] = __expf(sv[m][r] - mx); sum += e[m][r]; }
    sum += __shfl_xor(sum, 16);
    sum += __shfl_xor(sum, 32);
    float inv = 1.f / sum;
    // softmax pass 2 (exclude padded j again)
    float p3 = e3 * inv;
    float v3 = (g == 0) ? p3 : -1e30f;
    float mx2 = v3;
#pragma unroll
    for (int m = 0; m < 3; ++m)
#pragma unroll
      for (int r = 0; r < 4; ++r) mx2 = fmaxf(mx2, e[m][r] * inv);
    mx2 = fmaxf(mx2, __shfl_xor(mx2, 16));
    mx2 = fmaxf(mx2, __shfl_xor(mx2, 32));
    float e2[3][4], e23 = __expf(v3 - mx2);
    float sum2 = e23;
#pragma unroll
    for (int m = 0; m < 3; ++m)
#pragma unroll
      for (int r = 0; r < 4; ++r) { e2[m][r] = __expf(e[m][r] * inv - mx2); sum2 += e2[m][r]; }
    sum2 += __shfl_xor(sum2, 16);
    sum2 += __shfl_xor(sum2, 32);
    float inv2 = 1.f / sum2;
    // write P row icol as bf16 (pad j>=49 with zeros)
#pragma unroll
    for (int m = 0; m < 3; ++m) {
      uint u0 = (uint)f2bf(e2[m][0] * inv2) | ((uint)f2bf(e2[m][1] * inv2) << 16);
      uint u1 = (uint)f2bf(e2[m][2] * inv2) | ((uint)f2bf(e2[m][3] * inv2) << 16);
      *(uint*)&Pl[h][icol][m * 16 + g * 4]     = u0;
      *(uint*)&Pl[h][icol][m * 16 + g * 4 + 2] = u1;
    }
    uint u3 = (uint)f2bf(e23 * inv2); // lanes g!=0 give exp(-inf)=0
    *(uint*)&Pl[h][icol][48 + g * 4]     = u3;
    *(uint*)&Pl[h][icol][48 + g * 4 + 2] = 0u;
  }
  __syncthreads();

  // --- PV: O[i][d] = sum_j P[i][j] Vt[d][j] ---
  f32x4 oacc[4][2] = {};
#pragma unroll
  for (int ks = 0; ks < 2; ++ks) {
    int kloc = ks * 32 + g * 8;
    bf16x8 bf0 = *(const bf16x8*)&Vt[h][li][kloc];
    bf16x8 bf1 = *(const bf16x8*)&Vt[h][16 + li][kloc];
#pragma unroll
    for (int mi = 0; mi < 4; ++mi) {
      bf16x8 af = *(const bf16x8*)&Pl[h][mi * 16 + li][kloc];
      oacc[mi][0] = __builtin_amdgcn_mfma_f32_16x16x32_bf16(af, bf0, oacc[mi][0], 0, 0, 0);
      oacc[mi][1] = __builtin_amdgcn_mfma_f32_16x16x32_bf16(af, bf1, oacc[mi][1], 0, 0, 0);
    }
  }
  // --- store O rows i<49 ---
  ushort* obase = ob + (size_t)win * 49 * 128 + h * 32;
#pragma unroll
  for (int mi = 0; mi < 4; ++mi)
#pragma unroll
    for (int r = 0; r < 4; ++r) {
      int i = mi * 16 + g * 4 + r;
      if (mi < 3 || (g == 0 && r == 0)) {
        ushort* op = obase + (size_t)i * 128;
        op[li]      = f2bf(oacc[mi][0][r]);
        op[16 + li] = f2bf(oacc[mi][1][r]);
      }
    }
}

extern "C" void kernel_launch(void* const* d_in, const int* in_sizes, int n_in,
                              void* d_out, int out_size, void* d_ws,
                              size_t ws_size, hipStream_t stream) {
  (void)in_sizes; (void)n_in; (void)out_size; (void)ws_size;
  const float* x      = (const float*)d_in[0];
  const float* qkv_w  = (const float*)d_in[1];
  const float* qkv_b  = (const float*)d_in[2];
  const float* proj_w = (const float*)d_in[3];
  const float* proj_b = (const float*)d_in[4];
  const float* plg    = (const float*)d_in[5];
  const float* plb    = (const float*)d_in[6];
  const float* rpb    = (const float*)d_in[7];
  const float* n1g    = (const float*)d_in[8];
  const float* n1b    = (const float*)d_in[9];
  const float* n2g    = (const float*)d_in[10];
  const float* n2b    = (const float*)d_in[11];
  const float* w1     = (const float*)d_in[12];
  const float* b1     = (const float*)d_in[13];
  const float* w2     = (const float*)d_in[14];
  const float* b2     = (const float*)d_in[15];
  float* out = (float*)d_out;

  // ws layout (ushort units), ~232 MB
  ushort* wp   = (ushort*)d_ws;                         // 100352*128
  ushort* qkvb = wp + (size_t)100352 * 128;             // 100352*384
  ushort* obb  = qkvb + (size_t)100352 * 384;           // 100352*128
  ushort* hb   = obb + (size_t)100352 * 128;            // 100352*512
  ushort* qkvT = hb + (size_t)100352 * 512;             // 384*128
  ushort* w1T  = qkvT + 384 * 128;                      // 512*128
  ushort* w2T  = w1T + 512 * 128;                       // 128*512
  ushort* pT   = w2T + 128 * 512;                       // 128*128
  float*  TB   = (float*)(pT + 128 * 128);              // 4*4*64*64 f32

  k_prep<<<768, 256, 0, stream>>>(qkv_w, w1, w2, proj_w, qkvT, w1T, w2T, pT);
  k_prep2<<<256, 256, 0, stream>>>(rpb, TB);
  k_ln1_part<<<25088, 256, 0, stream>>>(x, n1g, n1b, wp);
  k_gemm<128, 0><<<dim3(784, 3), 256, 0, stream>>>(wp, qkvT, qkv_b, nullptr, qkvb);
  k_attn<<<2048, 256, 0, stream>>>(qkvb, TB, obb);
  k_pgemm<<<784, 256, 0, stream>>>(obb, pT, proj_b, plg, plb, x, out);
  k_ln2<<<25088, 256, 0, stream>>>(out, n2g, n2b, wp);
  k_gemm<128, 1><<<dim3(784, 4), 256, 0, stream>>>(wp, w1T, b1, nullptr, hb);
  k_gemm<512, 2><<<dim3(784, 1), 256, 0, stream>>>(hb, w2T, b2, out, out);
}

// Round 5
// 338.549 us; speedup vs baseline: 4.2607x; 1.1902x over previous
//
#include <hip/hip_runtime.h>
#include <cstdint>
#include <cstddef>

typedef __attribute__((ext_vector_type(8))) short bf16x8;
typedef __attribute__((ext_vector_type(4))) float f32x4;

namespace {
constexpr float kScale = 0.17677669529663689f; // 32^-0.5
constexpr float kEps = 1e-6f;
constexpr float kInvC = 1.0f / 128.0f;

__device__ __forceinline__ float gelu_exact(float v) {
  return 0.5f * v * (1.0f + erff(v * 0.70710678118654752f));
}
__device__ __forceinline__ ushort f2bf(float f) {
  uint32_t u = __builtin_bit_cast(uint32_t, f);
  u += 0x7FFFu + ((u >> 16) & 1u);
  return (ushort)(u >> 16);
}
__device__ __forceinline__ float bf2f(ushort u) {
  return __builtin_bit_cast(float, (uint32_t)u << 16);
}
} // namespace

// ---------------------------------------------------------------------------
// K0: convert+transpose weights to bf16 [N][K] layout.
// ---------------------------------------------------------------------------
__global__ __launch_bounds__(256) void k_prep(
    const float* __restrict__ qkv_w, const float* __restrict__ w1,
    const float* __restrict__ w2, const float* __restrict__ pw,
    ushort* __restrict__ qkvT, ushort* __restrict__ w1T,
    ushort* __restrict__ w2T, ushort* __restrict__ projT) {
  int i = blockIdx.x * 256 + threadIdx.x;
  if (i < 49152) {
    int n = i >> 7, k = i & 127;
    qkvT[i] = f2bf(qkv_w[k * 384 + n]);
  } else if (i < 114688) {
    int j = i - 49152;
    int n = j >> 7, k = j & 127;
    w1T[j] = f2bf(w1[k * 512 + n]);
  } else if (i < 180224) {
    int j = i - 114688;
    int n = j >> 9, k = j & 511;
    w2T[j] = f2bf(w2[k * 128 + n]);
  } else if (i < 196608) {
    int j = i - 180224;
    int n = j >> 7, k = j & 127;
    projT[j] = f2bf(pw[k * 128 + n]);
  }
}

// ---------------------------------------------------------------------------
// K0b: precompute bias+mask table TB[type(4)][head(4)][j(64)][i(64)] f32.
// ---------------------------------------------------------------------------
__global__ __launch_bounds__(256) void k_prep2(
    const float* __restrict__ rpb, float* __restrict__ TB) {
  int e = blockIdx.x * 256 + threadIdx.x;  // < 65536
  int i = e & 63, j = (e >> 6) & 63, h = (e >> 12) & 3, type = e >> 14;
  float v = 0.f;
  if (i < 49 && j < 49) {
    int ri = i / 7, ci = i - ri * 7, rj = j / 7, cj = j - rj * 7;
    int ridx = (ri - rj + 6) * 13 + (ci - cj + 6);
    float bias = rpb[ridx * 4 + h];
    int th = type >> 1, tw = type & 1;
    int labi = (th ? ((ri < 4) ? 1 : 2) : 0) * 3 + (tw ? ((ci < 4) ? 1 : 2) : 0);
    int labj = (th ? ((rj < 4) ? 1 : 2) : 0) * 3 + (tw ? ((cj < 4) ? 1 : 2) : 0);
    v = bias + ((labi != labj) ? -100.f : 0.f);
  }
  TB[e] = v;
}

// ---------------------------------------------------------------------------
// K1: LN(norm1) + cyclic shift(-3,-3) + window partition -> bf16
// ---------------------------------------------------------------------------
__global__ __launch_bounds__(256) void k_ln1_part(
    const float* __restrict__ x, const float* __restrict__ g,
    const float* __restrict__ b, ushort* __restrict__ wp) {
  int wv = threadIdx.x >> 6, lane = threadIdx.x & 63;
  int tok = blockIdx.x * 4 + wv;               // 0..100351
  int win = tok / 49, n = tok - win * 49;
  int bb = win >> 6, wi = win & 63;
  int whi = wi >> 3, wwi = wi & 7;
  int r = n / 7, c = n - r * 7;
  int hs = whi * 7 + r + 3; if (hs >= 56) hs -= 56;
  int ws = wwi * 7 + c + 3; if (ws >= 56) ws -= 56;
  size_t src = ((size_t)bb * 3136 + hs * 56 + ws) * 128;
  float2 v = *(const float2*)(x + src + lane * 2);
  float s = v.x + v.y, sq = v.x * v.x + v.y * v.y;
#pragma unroll
  for (int off = 1; off < 64; off <<= 1) {
    s += __shfl_xor(s, off);
    sq += __shfl_xor(sq, off);
  }
  float mu = s * kInvC;
  float var = sq * kInvC - mu * mu;
  float rs = rsqrtf(var + kEps);
  float2 gg = *(const float2*)(g + lane * 2);
  float2 bv = *(const float2*)(b + lane * 2);
  float o0 = (v.x - mu) * rs * gg.x + bv.x;
  float o1 = (v.y - mu) * rs * gg.y + bv.y;
  uint p = (uint)f2bf(o0) | ((uint)f2bf(o1) << 16);
  ((uint*)wp)[(size_t)tok * 64 + lane] = p;
}

// ---------------------------------------------------------------------------
// K-UNSHIFT: reverse window partition + reverse shift + residual + LN2.
// Per natural token: out = x + yb(bf16), wp = bf16(LN2(out)). Kills k_ln2.
// ---------------------------------------------------------------------------
__global__ __launch_bounds__(256) void k_unshift(
    const float* __restrict__ x, const ushort* __restrict__ yb,
    const float* __restrict__ g, const float* __restrict__ b,
    float* __restrict__ out, ushort* __restrict__ wp) {
  int wv = threadIdx.x >> 6, lane = threadIdx.x & 63;
  int tok = blockIdx.x * 4 + wv;               // natural: bb*3136 + ph*56 + pw
  int bb = tok / 3136, rem = tok - bb * 3136;
  int ph = rem / 56, pw = rem - ph * 56;
  int sh = ph + 53; if (sh >= 56) sh -= 56;    // (ph-3) mod 56
  int sw = pw + 53; if (sw >= 56) sw -= 56;
  int whi = sh / 7, r7 = sh - whi * 7;
  int wwi = sw / 7, c7 = sw - wwi * 7;
  int win = bb * 64 + whi * 8 + wwi, nn = r7 * 7 + c7;
  size_t row = (size_t)tok * 128;
  float2 xv = *(const float2*)(x + row + lane * 2);
  uint yv = ((const uint*)yb)[((size_t)win * 49 + nn) * 64 + lane];
  float o0 = xv.x + bf2f((ushort)(yv & 0xffff));
  float o1 = xv.y + bf2f((ushort)(yv >> 16));
  float2 ov; ov.x = o0; ov.y = o1;
  *(float2*)(out + row + lane * 2) = ov;
  float s = o0 + o1, sq = o0 * o0 + o1 * o1;
#pragma unroll
  for (int off = 1; off < 64; off <<= 1) {
    s += __shfl_xor(s, off);
    sq += __shfl_xor(sq, off);
  }
  float mu = s * kInvC;
  float var = sq * kInvC - mu * mu;
  float rs = rsqrtf(var + kEps);
  float2 gg = *(const float2*)(g + lane * 2);
  float2 bv = *(const float2*)(b + lane * 2);
  float m0 = (o0 - mu) * rs * gg.x + bv.x;
  float m1 = (o1 - mu) * rs * gg.y + bv.y;
  uint p = (uint)f2bf(m0) | ((uint)f2bf(m1) << 16);
  ((uint*)wp)[(size_t)tok * 64 + lane] = p;
}

// ---------------------------------------------------------------------------
// K-GEMM: C[M,N] = A[M,K](bf16) @ BT[N,K](bf16)^T, 128x128 tile, BK=64.
// EPI 0: +bias -> bf16   EPI 1: gelu(+bias) -> bf16   EPI 2: +bias+res -> f32
// ---------------------------------------------------------------------------
template <int K, int EPI>
__global__ __launch_bounds__(256) void k_gemm(
    const ushort* __restrict__ A, const ushort* __restrict__ BT,
    const float* __restrict__ bias, const float* __restrict__ res,
    void* __restrict__ Cout) {
  __shared__ ushort As[128][72];
  __shared__ ushort Bs[128][72];
  int tid = threadIdx.x;
  int mBase = blockIdx.x << 7;
  int nBase = blockIdx.y << 7;
  int lane = tid & 63, wid = tid >> 6;
  int wr = (wid >> 1) << 6, wc = (wid & 1) << 6;
  f32x4 acc[4][4] = {};
  for (int ks = 0; ks < K; ks += 64) {
#pragma unroll
    for (int l = 0; l < 4; ++l) {
      int c = tid + l * 256;
      int row = c >> 3, k8 = (c & 7) << 3;
      *(bf16x8*)&As[row][k8] =
          *(const bf16x8*)(A + (size_t)(mBase + row) * K + ks + k8);
      *(bf16x8*)&Bs[row][k8] =
          *(const bf16x8*)(BT + (size_t)(nBase + row) * K + ks + k8);
    }
    __syncthreads();
#pragma unroll
    for (int ksub = 0; ksub < 64; ksub += 32) {
      int kloc = ksub + ((lane >> 4) << 3);
      bf16x8 af[4], bfr[4];
#pragma unroll
      for (int m = 0; m < 4; ++m)
        af[m] = *(const bf16x8*)&As[wr + m * 16 + (lane & 15)][kloc];
#pragma unroll
      for (int n = 0; n < 4; ++n)
        bfr[n] = *(const bf16x8*)&Bs[wc + n * 16 + (lane & 15)][kloc];
#pragma unroll
      for (int m = 0; m < 4; ++m)
#pragma unroll
        for (int n = 0; n < 4; ++n)
          acc[m][n] = __builtin_amdgcn_mfma_f32_16x16x32_bf16(
              af[m], bfr[n], acc[m][n], 0, 0, 0);
    }
    __syncthreads();
  }
  int ldC = (int)(gridDim.y << 7);
#pragma unroll
  for (int n = 0; n < 4; ++n) {
    int cg = nBase + wc + n * 16 + (lane & 15);
    float bv = bias[cg];
#pragma unroll
    for (int m = 0; m < 4; ++m) {
      int rbase = mBase + wr + m * 16 + ((lane >> 4) << 2);
#pragma unroll
      for (int r = 0; r < 4; ++r) {
        float v = acc[m][n][r] + bv;
        size_t off = (size_t)(rbase + r) * ldC + cg;
        if (EPI == 0) {
          ((ushort*)Cout)[off] = f2bf(v);
        } else if (EPI == 1) {
          ((ushort*)Cout)[off] = f2bf(gelu_exact(v));
        } else {
          ((float*)Cout)[off] = v + res[off];
        }
      }
    }
  }
}

// ---------------------------------------------------------------------------
// K-PGEMM: proj GEMM + bias + row-LN(proj_ln) + GELU -> bf16 yb
// in window-token order (contiguous). Reverse shift handled by k_unshift.
// ---------------------------------------------------------------------------
__global__ __launch_bounds__(256) void k_pgemm(
    const ushort* __restrict__ A, const ushort* __restrict__ BT,
    const float* __restrict__ pb, const float* __restrict__ lg,
    const float* __restrict__ lb, ushort* __restrict__ yb) {
  __shared__ ushort As[128][72];
  __shared__ ushort Bs[128][72];
  __shared__ float red[4][64][2];
  int tid = threadIdx.x;
  int mBase = blockIdx.x << 7;
  int lane = tid & 63, wid = tid >> 6;
  int wr = (wid >> 1) << 6, wc = (wid & 1) << 6;
  f32x4 acc[4][4] = {};
  for (int ks = 0; ks < 128; ks += 64) {
#pragma unroll
    for (int l = 0; l < 4; ++l) {
      int c = tid + l * 256;
      int row = c >> 3, k8 = (c & 7) << 3;
      *(bf16x8*)&As[row][k8] =
          *(const bf16x8*)(A + (size_t)(mBase + row) * 128 + ks + k8);
      *(bf16x8*)&Bs[row][k8] =
          *(const bf16x8*)(BT + (size_t)row * 128 + ks + k8);
    }
    __syncthreads();
#pragma unroll
    for (int ksub = 0; ksub < 64; ksub += 32) {
      int kloc = ksub + ((lane >> 4) << 3);
      bf16x8 af[4], bfr[4];
#pragma unroll
      for (int m = 0; m < 4; ++m)
        af[m] = *(const bf16x8*)&As[wr + m * 16 + (lane & 15)][kloc];
#pragma unroll
      for (int n = 0; n < 4; ++n)
        bfr[n] = *(const bf16x8*)&Bs[wc + n * 16 + (lane & 15)][kloc];
#pragma unroll
      for (int m = 0; m < 4; ++m)
#pragma unroll
        for (int n = 0; n < 4; ++n)
          acc[m][n] = __builtin_amdgcn_mfma_f32_16x16x32_bf16(
              af[m], bfr[n], acc[m][n], 0, 0, 0);
    }
    __syncthreads();
  }
  float pbv[4], lgv[4], lbv[4];
#pragma unroll
  for (int n = 0; n < 4; ++n) {
    int cg = wc + n * 16 + (lane & 15);
    pbv[n] = pb[cg]; lgv[n] = lg[cg]; lbv[n] = lb[cg];
  }
  float ps[4][4], psq[4][4];
#pragma unroll
  for (int m = 0; m < 4; ++m)
#pragma unroll
    for (int r = 0; r < 4; ++r) {
      float s = 0.f, q = 0.f;
#pragma unroll
      for (int n = 0; n < 4; ++n) {
        float v = acc[m][n][r] + pbv[n];
        s += v; q += v * v;
      }
#pragma unroll
      for (int off = 1; off < 16; off <<= 1) {
        s += __shfl_xor(s, off);
        q += __shfl_xor(q, off);
      }
      ps[m][r] = s; psq[m][r] = q;
    }
  if ((lane & 15) == 0) {
#pragma unroll
    for (int m = 0; m < 4; ++m)
#pragma unroll
      for (int r = 0; r < 4; ++r) {
        int rl = m * 16 + ((lane >> 4) << 2) + r;
        red[wid][rl][0] = ps[m][r];
        red[wid][rl][1] = psq[m][r];
      }
  }
  __syncthreads();
#pragma unroll
  for (int m = 0; m < 4; ++m) {
#pragma unroll
    for (int r = 0; r < 4; ++r) {
      int rl = m * 16 + ((lane >> 4) << 2) + r;
      float s = ps[m][r] + red[wid ^ 1][rl][0];
      float q = psq[m][r] + red[wid ^ 1][rl][1];
      float mu = s * kInvC, var = q * kInvC - mu * mu;
      float rs = rsqrtf(var + kEps);
      size_t rowb = (size_t)(mBase + wr + rl) * 128;
#pragma unroll
      for (int n = 0; n < 4; ++n) {
        int cg = wc + n * 16 + (lane & 15);
        float y = (acc[m][n][r] + pbv[n] - mu) * rs * lgv[n] + lbv[n];
        yb[rowb + cg] = f2bf(gelu_exact(y));
      }
    }
  }
}

// ---------------------------------------------------------------------------
// K3: MFMA attention. 1 block = 1 window, 1 wave = 1 head.
// ---------------------------------------------------------------------------
__global__ __launch_bounds__(256) void k_attn(
    const ushort* __restrict__ qkv, const float* __restrict__ TB,
    ushort* __restrict__ ob) {
  __shared__ ushort Pl[4][64][72];
  __shared__ ushort Vt[4][32][72];
  int tid = threadIdx.x;
  int lane = tid & 63, h = tid >> 6;
  int li = lane & 15, g = lane >> 4;
  int win = blockIdx.x;
  int wi = win & 63;
  int type = (((wi >> 3) == 7) ? 2 : 0) | (((wi & 7) == 7) ? 1 : 0);

  const ushort* qbase = qkv + (size_t)win * 49 * 384 + h * 32 + g * 8;
  bf16x8 kf[4], qf[4];
#pragma unroll
  for (int m = 0; m < 4; ++m) {
    kf[m] = *(const bf16x8*)(qbase + (size_t)(m * 16 + li) * 384 + 128);
    qf[m] = *(const bf16x8*)(qbase + (size_t)(m * 16 + li) * 384);
  }
  f32x4 zero = {0.f, 0.f, 0.f, 0.f};
  f32x4 st[4][4];
#pragma unroll
  for (int m = 0; m < 4; ++m)
#pragma unroll
    for (int n = 0; n < 4; ++n)
      st[m][n] = __builtin_amdgcn_mfma_f32_16x16x32_bf16(kf[m], qf[n], zero, 0, 0, 0);

  if (lane < 49) {
#pragma unroll
    for (int dc = 0; dc < 4; ++dc) {
      bf16x8 vv = *(const bf16x8*)(qkv + ((size_t)win * 49 + lane) * 384 + 256 +
                                   h * 32 + dc * 8);
#pragma unroll
      for (int t = 0; t < 8; ++t) Vt[h][dc * 8 + t][lane] = (ushort)vv[t];
    }
  } else {
#pragma unroll
    for (int d = 0; d < 32; ++d) Vt[h][d][lane] = 0;
  }

  const float* tb = TB + ((size_t)(type * 4 + h) << 12);
#pragma unroll
  for (int n = 0; n < 4; ++n) {
    int icol = n * 16 + li;
    float sv[3][4];
#pragma unroll
    for (int m = 0; m < 3; ++m)
#pragma unroll
      for (int r = 0; r < 4; ++r)
        sv[m][r] = st[m][n][r] * kScale + tb[(m * 16 + g * 4 + r) * 64 + icol];
    float sv3 = (g == 0) ? (st[3][n][0] * kScale + tb[48 * 64 + icol]) : -1e30f;
    float mx = sv3;
#pragma unroll
    for (int m = 0; m < 3; ++m)
#pragma unroll
      for (int r = 0; r < 4; ++r) mx = fmaxf(mx, sv[m][r]);
    mx = fmaxf(mx, __shfl_xor(mx, 16));
    mx = fmaxf(mx, __shfl_xor(mx, 32));
    float e[3][4], e3 = __expf(sv3 - mx);
    float sum = e3;
#pragma unroll
    for (int m = 0; m < 3; ++m)
#pragma unroll
      for (int r = 0; r < 4; ++r) { e[m][r] = __expf(sv[m][r] - mx); sum += e[m][r]; }
    sum += __shfl_xor(sum, 16);
    sum += __shfl_xor(sum, 32);
    float inv = 1.f / sum;
    float p3 = e3 * inv;
    float v3 = (g == 0) ? p3 : -1e30f;
    float mx2 = v3;
#pragma unroll
    for (int m = 0; m < 3; ++m)
#pragma unroll
      for (int r = 0; r < 4; ++r) mx2 = fmaxf(mx2, e[m][r] * inv);
    mx2 = fmaxf(mx2, __shfl_xor(mx2, 16));
    mx2 = fmaxf(mx2, __shfl_xor(mx2, 32));
    float e2[3][4], e23 = __expf(v3 - mx2);
    float sum2 = e23;
#pragma unroll
    for (int m = 0; m < 3; ++m)
#pragma unroll
      for (int r = 0; r < 4; ++r) { e2[m][r] = __expf(e[m][r] * inv - mx2); sum2 += e2[m][r]; }
    sum2 += __shfl_xor(sum2, 16);
    sum2 += __shfl_xor(sum2, 32);
    float inv2 = 1.f / sum2;
#pragma unroll
    for (int m = 0; m < 3; ++m) {
      uint u0 = (uint)f2bf(e2[m][0] * inv2) | ((uint)f2bf(e2[m][1] * inv2) << 16);
      uint u1 = (uint)f2bf(e2[m][2] * inv2) | ((uint)f2bf(e2[m][3] * inv2) << 16);
      *(uint*)&Pl[h][icol][m * 16 + g * 4]     = u0;
      *(uint*)&Pl[h][icol][m * 16 + g * 4 + 2] = u1;
    }
    uint u3 = (uint)f2bf(e23 * inv2);
    *(uint*)&Pl[h][icol][48 + g * 4]     = u3;
    *(uint*)&Pl[h][icol][48 + g * 4 + 2] = 0u;
  }
  __syncthreads();

  f32x4 oacc[4][2] = {};
#pragma unroll
  for (int ks = 0; ks < 2; ++ks) {
    int kloc = ks * 32 + g * 8;
    bf16x8 bf0 = *(const bf16x8*)&Vt[h][li][kloc];
    bf16x8 bf1 = *(const bf16x8*)&Vt[h][16 + li][kloc];
#pragma unroll
    for (int mi = 0; mi < 4; ++mi) {
      bf16x8 af = *(const bf16x8*)&Pl[h][mi * 16 + li][kloc];
      oacc[mi][0] = __builtin_amdgcn_mfma_f32_16x16x32_bf16(af, bf0, oacc[mi][0], 0, 0, 0);
      oacc[mi][1] = __builtin_amdgcn_mfma_f32_16x16x32_bf16(af, bf1, oacc[mi][1], 0, 0, 0);
    }
  }
  ushort* obase = ob + (size_t)win * 49 * 128 + h * 32;
#pragma unroll
  for (int mi = 0; mi < 4; ++mi)
#pragma unroll
    for (int r = 0; r < 4; ++r) {
      int i = mi * 16 + g * 4 + r;
      if (mi < 3 || (g == 0 && r == 0)) {
        ushort* op = obase + (size_t)i * 128;
        op[li]      = f2bf(oacc[mi][0][r]);
        op[16 + li] = f2bf(oacc[mi][1][r]);
      }
    }
}

extern "C" void kernel_launch(void* const* d_in, const int* in_sizes, int n_in,
                              void* d_out, int out_size, void* d_ws,
                              size_t ws_size, hipStream_t stream) {
  (void)in_sizes; (void)n_in; (void)out_size; (void)ws_size;
  const float* x      = (const float*)d_in[0];
  const float* qkv_w  = (const float*)d_in[1];
  const float* qkv_b  = (const float*)d_in[2];
  const float* proj_w = (const float*)d_in[3];
  const float* proj_b = (const float*)d_in[4];
  const float* plg    = (const float*)d_in[5];
  const float* plb    = (const float*)d_in[6];
  const float* rpb    = (const float*)d_in[7];
  const float* n1g    = (const float*)d_in[8];
  const float* n1b    = (const float*)d_in[9];
  const float* n2g    = (const float*)d_in[10];
  const float* n2b    = (const float*)d_in[11];
  const float* w1     = (const float*)d_in[12];
  const float* b1     = (const float*)d_in[13];
  const float* w2     = (const float*)d_in[14];
  const float* b2     = (const float*)d_in[15];
  float* out = (float*)d_out;

  // ws layout (ushort units), ~233 MB
  ushort* wp   = (ushort*)d_ws;                         // 100352*128
  ushort* qkvb = wp + (size_t)100352 * 128;             // 100352*384
  ushort* obb  = qkvb + (size_t)100352 * 384;           // 100352*128
  ushort* hb   = obb + (size_t)100352 * 128;            // 100352*512
  ushort* qkvT = hb + (size_t)100352 * 512;             // 384*128
  ushort* w1T  = qkvT + 384 * 128;                      // 512*128
  ushort* w2T  = w1T + 512 * 128;                       // 128*512
  ushort* pT   = w2T + 128 * 512;                       // 128*128
  float*  TB   = (float*)(pT + 128 * 128);              // 4*4*64*64 f32
  ushort* yb   = qkvb;  // alias: qkvb dead after k_attn

  k_prep<<<768, 256, 0, stream>>>(qkv_w, w1, w2, proj_w, qkvT, w1T, w2T, pT);
  k_prep2<<<256, 256, 0, stream>>>(rpb, TB);
  k_ln1_part<<<25088, 256, 0, stream>>>(x, n1g, n1b, wp);
  k_gemm<128, 0><<<dim3(784, 3), 256, 0, stream>>>(wp, qkvT, qkv_b, nullptr, qkvb);
  k_attn<<<2048, 256, 0, stream>>>(qkvb, TB, obb);
  k_pgemm<<<784, 256, 0, stream>>>(obb, pT, proj_b, plg, plb, yb);
  k_unshift<<<25088, 256, 0, stream>>>(x, yb, n2g, n2b, out, wp);
  k_gemm<128, 1><<<dim3(784, 4), 256, 0, stream>>>(wp, w1T, b1, nullptr, hb);
  k_gemm<512, 2><<<dim3(784, 1), 256, 0, stream>>>(hb, w2T, b2, out, out);
}

// Round 6
// 320.713 us; speedup vs baseline: 4.4977x; 1.0556x over previous
//
#include <hip/hip_runtime.h>
#include <cstdint>
#include <cstddef>

typedef __attribute__((ext_vector_type(8))) short bf16x8;
typedef __attribute__((ext_vector_type(4))) float f32x4;

namespace {
constexpr float kScale = 0.17677669529663689f; // 32^-0.5
constexpr float kEps = 1e-6f;
constexpr float kInvC = 1.0f / 128.0f;

__device__ __forceinline__ float gelu_exact(float v) {
  return 0.5f * v * (1.0f + erff(v * 0.70710678118654752f));
}
__device__ __forceinline__ ushort f2bf(float f) {
  uint32_t u = __builtin_bit_cast(uint32_t, f);
  u += 0x7FFFu + ((u >> 16) & 1u);
  return (ushort)(u >> 16);
}
__device__ __forceinline__ float bf2f(ushort u) {
  return __builtin_bit_cast(float, (uint32_t)u << 16);
}
} // namespace

// ---------------------------------------------------------------------------
// K0: convert+transpose weights to bf16 [N][K] layout.
// ---------------------------------------------------------------------------
__global__ __launch_bounds__(256) void k_prep(
    const float* __restrict__ qkv_w, const float* __restrict__ w1,
    const float* __restrict__ w2, const float* __restrict__ pw,
    ushort* __restrict__ qkvT, ushort* __restrict__ w1T,
    ushort* __restrict__ w2T, ushort* __restrict__ projT) {
  int i = blockIdx.x * 256 + threadIdx.x;
  if (i < 49152) {
    int n = i >> 7, k = i & 127;
    qkvT[i] = f2bf(qkv_w[k * 384 + n]);
  } else if (i < 114688) {
    int j = i - 49152;
    int n = j >> 7, k = j & 127;
    w1T[j] = f2bf(w1[k * 512 + n]);
  } else if (i < 180224) {
    int j = i - 114688;
    int n = j >> 9, k = j & 511;
    w2T[j] = f2bf(w2[k * 128 + n]);
  } else if (i < 196608) {
    int j = i - 180224;
    int n = j >> 7, k = j & 127;
    projT[j] = f2bf(pw[k * 128 + n]);
  }
}

// ---------------------------------------------------------------------------
// K0b: precompute bias+mask table TB[type(4)][head(4)][j(64)][i(64)] f32.
// ---------------------------------------------------------------------------
__global__ __launch_bounds__(256) void k_prep2(
    const float* __restrict__ rpb, float* __restrict__ TB) {
  int e = blockIdx.x * 256 + threadIdx.x;  // < 65536
  int i = e & 63, j = (e >> 6) & 63, h = (e >> 12) & 3, type = e >> 14;
  float v = 0.f;
  if (i < 49 && j < 49) {
    int ri = i / 7, ci = i - ri * 7, rj = j / 7, cj = j - rj * 7;
    int ridx = (ri - rj + 6) * 13 + (ci - cj + 6);
    float bias = rpb[ridx * 4 + h];
    int th = type >> 1, tw = type & 1;
    int labi = (th ? ((ri < 4) ? 1 : 2) : 0) * 3 + (tw ? ((ci < 4) ? 1 : 2) : 0);
    int labj = (th ? ((rj < 4) ? 1 : 2) : 0) * 3 + (tw ? ((cj < 4) ? 1 : 2) : 0);
    v = bias + ((labi != labj) ? -100.f : 0.f);
  }
  TB[e] = v;
}

// ---------------------------------------------------------------------------
// K1: LN(norm1) + cyclic shift(-3,-3) + window partition -> bf16
// ---------------------------------------------------------------------------
__global__ __launch_bounds__(256) void k_ln1_part(
    const float* __restrict__ x, const float* __restrict__ g,
    const float* __restrict__ b, ushort* __restrict__ wp) {
  int wv = threadIdx.x >> 6, lane = threadIdx.x & 63;
  int tok = blockIdx.x * 4 + wv;               // 0..100351
  int win = tok / 49, n = tok - win * 49;
  int bb = win >> 6, wi = win & 63;
  int whi = wi >> 3, wwi = wi & 7;
  int r = n / 7, c = n - r * 7;
  int hs = whi * 7 + r + 3; if (hs >= 56) hs -= 56;
  int ws = wwi * 7 + c + 3; if (ws >= 56) ws -= 56;
  size_t src = ((size_t)bb * 3136 + hs * 56 + ws) * 128;
  float2 v = *(const float2*)(x + src + lane * 2);
  float s = v.x + v.y, sq = v.x * v.x + v.y * v.y;
#pragma unroll
  for (int off = 1; off < 64; off <<= 1) {
    s += __shfl_xor(s, off);
    sq += __shfl_xor(sq, off);
  }
  float mu = s * kInvC;
  float var = sq * kInvC - mu * mu;
  float rs = rsqrtf(var + kEps);
  float2 gg = *(const float2*)(g + lane * 2);
  float2 bv = *(const float2*)(b + lane * 2);
  float o0 = (v.x - mu) * rs * gg.x + bv.x;
  float o1 = (v.y - mu) * rs * gg.y + bv.y;
  uint p = (uint)f2bf(o0) | ((uint)f2bf(o1) << 16);
  ((uint*)wp)[(size_t)tok * 64 + lane] = p;
}

// ---------------------------------------------------------------------------
// K-UNSHIFT: reverse window partition + reverse shift + residual + LN2.
// ---------------------------------------------------------------------------
__global__ __launch_bounds__(256) void k_unshift(
    const float* __restrict__ x, const ushort* __restrict__ yb,
    const float* __restrict__ g, const float* __restrict__ b,
    float* __restrict__ out, ushort* __restrict__ wp) {
  int wv = threadIdx.x >> 6, lane = threadIdx.x & 63;
  int tok = blockIdx.x * 4 + wv;               // natural: bb*3136 + ph*56 + pw
  int bb = tok / 3136, rem = tok - bb * 3136;
  int ph = rem / 56, pw = rem - ph * 56;
  int sh = ph + 53; if (sh >= 56) sh -= 56;    // (ph-3) mod 56
  int sw = pw + 53; if (sw >= 56) sw -= 56;
  int whi = sh / 7, r7 = sh - whi * 7;
  int wwi = sw / 7, c7 = sw - wwi * 7;
  int win = bb * 64 + whi * 8 + wwi, nn = r7 * 7 + c7;
  size_t row = (size_t)tok * 128;
  float2 xv = *(const float2*)(x + row + lane * 2);
  uint yv = ((const uint*)yb)[((size_t)win * 49 + nn) * 64 + lane];
  float o0 = xv.x + bf2f((ushort)(yv & 0xffff));
  float o1 = xv.y + bf2f((ushort)(yv >> 16));
  float2 ov; ov.x = o0; ov.y = o1;
  *(float2*)(out + row + lane * 2) = ov;
  float s = o0 + o1, sq = o0 * o0 + o1 * o1;
#pragma unroll
  for (int off = 1; off < 64; off <<= 1) {
    s += __shfl_xor(s, off);
    sq += __shfl_xor(sq, off);
  }
  float mu = s * kInvC;
  float var = sq * kInvC - mu * mu;
  float rs = rsqrtf(var + kEps);
  float2 gg = *(const float2*)(g + lane * 2);
  float2 bv = *(const float2*)(b + lane * 2);
  float m0 = (o0 - mu) * rs * gg.x + bv.x;
  float m1 = (o1 - mu) * rs * gg.y + bv.y;
  uint p = (uint)f2bf(m0) | ((uint)f2bf(m1) << 16);
  ((uint*)wp)[(size_t)tok * 64 + lane] = p;
}

// ---------------------------------------------------------------------------
// K-QKV: C[M,384] = A[M,128] @ qkvT^T + bias -> bf16, LDS-staged wide stores.
// ---------------------------------------------------------------------------
__global__ __launch_bounds__(256) void k_qkv(
    const ushort* __restrict__ A, const ushort* __restrict__ BT,
    const float* __restrict__ bias, ushort* __restrict__ C) {
  __shared__ ushort sbuf[2 * 128 * 72];
  ushort (*As)[72] = (ushort(*)[72])sbuf;
  ushort (*Bs)[72] = (ushort(*)[72])(sbuf + 128 * 72);
  int tid = threadIdx.x;
  int mBase = blockIdx.x << 7;
  int nBase = blockIdx.y << 7;
  int lane = tid & 63, wid = tid >> 6;
  int li = lane & 15, g = lane >> 4;
  int wr = (wid >> 1) << 6, wc = (wid & 1) << 6;
  f32x4 acc[4][4] = {};
  for (int ks = 0; ks < 128; ks += 64) {
#pragma unroll
    for (int l = 0; l < 4; ++l) {
      int c = tid + l * 256;
      int row = c >> 3, k8 = (c & 7) << 3;
      *(bf16x8*)&As[row][k8] =
          *(const bf16x8*)(A + (size_t)(mBase + row) * 128 + ks + k8);
      *(bf16x8*)&Bs[row][k8] =
          *(const bf16x8*)(BT + (size_t)(nBase + row) * 128 + ks + k8);
    }
    __syncthreads();
#pragma unroll
    for (int ksub = 0; ksub < 64; ksub += 32) {
      int kloc = ksub + g * 8;
      bf16x8 af[4], bfr[4];
#pragma unroll
      for (int m = 0; m < 4; ++m)
        af[m] = *(const bf16x8*)&As[wr + m * 16 + li][kloc];
#pragma unroll
      for (int n = 0; n < 4; ++n)
        bfr[n] = *(const bf16x8*)&Bs[wc + n * 16 + li][kloc];
#pragma unroll
      for (int m = 0; m < 4; ++m)
#pragma unroll
        for (int n = 0; n < 4; ++n)
          acc[m][n] = __builtin_amdgcn_mfma_f32_16x16x32_bf16(
              af[m], bfr[n], acc[m][n], 0, 0, 0);
    }
    __syncthreads();
  }
  // stage C through LDS (overlay), then contiguous bf16x8 stores
  ushort (*Cs)[136] = (ushort(*)[136])sbuf;
#pragma unroll
  for (int n = 0; n < 4; ++n) {
    float bv = bias[nBase + wc + n * 16 + li];
#pragma unroll
    for (int m = 0; m < 4; ++m) {
      int rbase = wr + m * 16 + (g << 2);
#pragma unroll
      for (int r = 0; r < 4; ++r)
        Cs[rbase + r][wc + n * 16 + li] = f2bf(acc[m][n][r] + bv);
    }
  }
  __syncthreads();
#pragma unroll
  for (int it = 0; it < 8; ++it) {
    int chunk = tid + it * 256;  // 2048 chunks of 8 ushorts
    int row = chunk >> 4, c8 = (chunk & 15) << 3;
    *(bf16x8*)(C + (size_t)(mBase + row) * 384 + nBase + c8) =
        *(const bf16x8*)&Cs[row][c8];
  }
}

// ---------------------------------------------------------------------------
// K-PGEMM: proj GEMM + bias + row-LN(proj_ln) + GELU -> bf16 yb (contiguous),
// LDS-staged wide stores.
// ---------------------------------------------------------------------------
__global__ __launch_bounds__(256) void k_pgemm(
    const ushort* __restrict__ A, const ushort* __restrict__ BT,
    const float* __restrict__ pb, const float* __restrict__ lg,
    const float* __restrict__ lb, ushort* __restrict__ yb) {
  __shared__ ushort sbuf[2 * 128 * 72];
  __shared__ float red[4][64][2];
  ushort (*As)[72] = (ushort(*)[72])sbuf;
  ushort (*Bs)[72] = (ushort(*)[72])(sbuf + 128 * 72);
  int tid = threadIdx.x;
  int mBase = blockIdx.x << 7;
  int lane = tid & 63, wid = tid >> 6;
  int li = lane & 15, g = lane >> 4;
  int wr = (wid >> 1) << 6, wc = (wid & 1) << 6;
  f32x4 acc[4][4] = {};
  for (int ks = 0; ks < 128; ks += 64) {
#pragma unroll
    for (int l = 0; l < 4; ++l) {
      int c = tid + l * 256;
      int row = c >> 3, k8 = (c & 7) << 3;
      *(bf16x8*)&As[row][k8] =
          *(const bf16x8*)(A + (size_t)(mBase + row) * 128 + ks + k8);
      *(bf16x8*)&Bs[row][k8] =
          *(const bf16x8*)(BT + (size_t)row * 128 + ks + k8);
    }
    __syncthreads();
#pragma unroll
    for (int ksub = 0; ksub < 64; ksub += 32) {
      int kloc = ksub + g * 8;
      bf16x8 af[4], bfr[4];
#pragma unroll
      for (int m = 0; m < 4; ++m)
        af[m] = *(const bf16x8*)&As[wr + m * 16 + li][kloc];
#pragma unroll
      for (int n = 0; n < 4; ++n)
        bfr[n] = *(const bf16x8*)&Bs[wc + n * 16 + li][kloc];
#pragma unroll
      for (int m = 0; m < 4; ++m)
#pragma unroll
        for (int n = 0; n < 4; ++n)
          acc[m][n] = __builtin_amdgcn_mfma_f32_16x16x32_bf16(
              af[m], bfr[n], acc[m][n], 0, 0, 0);
    }
    __syncthreads();
  }
  float pbv[4], lgv[4], lbv[4];
#pragma unroll
  for (int n = 0; n < 4; ++n) {
    int cg = wc + n * 16 + li;
    pbv[n] = pb[cg]; lgv[n] = lg[cg]; lbv[n] = lb[cg];
  }
  float ps[4][4], psq[4][4];
#pragma unroll
  for (int m = 0; m < 4; ++m)
#pragma unroll
    for (int r = 0; r < 4; ++r) {
      float s = 0.f, q = 0.f;
#pragma unroll
      for (int n = 0; n < 4; ++n) {
        float v = acc[m][n][r] + pbv[n];
        s += v; q += v * v;
      }
#pragma unroll
      for (int off = 1; off < 16; off <<= 1) {
        s += __shfl_xor(s, off);
        q += __shfl_xor(q, off);
      }
      ps[m][r] = s; psq[m][r] = q;
    }
  if (li == 0) {
#pragma unroll
    for (int m = 0; m < 4; ++m)
#pragma unroll
      for (int r = 0; r < 4; ++r) {
        int rl = m * 16 + (g << 2) + r;
        red[wid][rl][0] = ps[m][r];
        red[wid][rl][1] = psq[m][r];
      }
  }
  __syncthreads();
  ushort (*Cs)[136] = (ushort(*)[136])sbuf;
#pragma unroll
  for (int m = 0; m < 4; ++m) {
#pragma unroll
    for (int r = 0; r < 4; ++r) {
      int rl = m * 16 + (g << 2) + r;
      float s = ps[m][r] + red[wid ^ 1][rl][0];
      float q = psq[m][r] + red[wid ^ 1][rl][1];
      float mu = s * kInvC, var = q * kInvC - mu * mu;
      float rs = rsqrtf(var + kEps);
#pragma unroll
      for (int n = 0; n < 4; ++n) {
        float y = (acc[m][n][r] + pbv[n] - mu) * rs * lgv[n] + lbv[n];
        Cs[wr + rl][wc + n * 16 + li] = f2bf(gelu_exact(y));
      }
    }
  }
  __syncthreads();
#pragma unroll
  for (int it = 0; it < 8; ++it) {
    int chunk = tid + it * 256;  // 2048 chunks of 8 ushorts
    int row = chunk >> 4, c8 = (chunk & 15) << 3;
    *(bf16x8*)(yb + (size_t)(mBase + row) * 128 + c8) =
        *(const bf16x8*)&Cs[row][c8];
  }
}

// ---------------------------------------------------------------------------
// K3: MFMA attention. 1 block = 1 window, 1 wave = 1 head. LDS-staged O store.
// ---------------------------------------------------------------------------
__global__ __launch_bounds__(256) void k_attn(
    const ushort* __restrict__ qkv, const float* __restrict__ TB,
    ushort* __restrict__ ob) {
  __shared__ ushort Pl[4][64][72];
  __shared__ ushort Vt[4][32][72];
  int tid = threadIdx.x;
  int lane = tid & 63, h = tid >> 6;
  int li = lane & 15, g = lane >> 4;
  int win = blockIdx.x;
  int wi = win & 63;
  int type = (((wi >> 3) == 7) ? 2 : 0) | (((wi & 7) == 7) ? 1 : 0);

  const ushort* qbase = qkv + (size_t)win * 49 * 384 + h * 32 + g * 8;
  bf16x8 kf[4], qf[4];
#pragma unroll
  for (int m = 0; m < 4; ++m) {
    kf[m] = *(const bf16x8*)(qbase + (size_t)(m * 16 + li) * 384 + 128);
    qf[m] = *(const bf16x8*)(qbase + (size_t)(m * 16 + li) * 384);
  }
  f32x4 zero = {0.f, 0.f, 0.f, 0.f};
  f32x4 st[4][4];
#pragma unroll
  for (int m = 0; m < 4; ++m)
#pragma unroll
    for (int n = 0; n < 4; ++n)
      st[m][n] = __builtin_amdgcn_mfma_f32_16x16x32_bf16(kf[m], qf[n], zero, 0, 0, 0);

  if (lane < 49) {
#pragma unroll
    for (int dc = 0; dc < 4; ++dc) {
      bf16x8 vv = *(const bf16x8*)(qkv + ((size_t)win * 49 + lane) * 384 + 256 +
                                   h * 32 + dc * 8);
#pragma unroll
      for (int t = 0; t < 8; ++t) Vt[h][dc * 8 + t][lane] = (ushort)vv[t];
    }
  } else {
#pragma unroll
    for (int d = 0; d < 32; ++d) Vt[h][d][lane] = 0;
  }

  const float* tb = TB + ((size_t)(type * 4 + h) << 12);
#pragma unroll
  for (int n = 0; n < 4; ++n) {
    int icol = n * 16 + li;
    float sv[3][4];
#pragma unroll
    for (int m = 0; m < 3; ++m)
#pragma unroll
      for (int r = 0; r < 4; ++r)
        sv[m][r] = st[m][n][r] * kScale + tb[(m * 16 + g * 4 + r) * 64 + icol];
    float sv3 = (g == 0) ? (st[3][n][0] * kScale + tb[48 * 64 + icol]) : -1e30f;
    float mx = sv3;
#pragma unroll
    for (int m = 0; m < 3; ++m)
#pragma unroll
      for (int r = 0; r < 4; ++r) mx = fmaxf(mx, sv[m][r]);
    mx = fmaxf(mx, __shfl_xor(mx, 16));
    mx = fmaxf(mx, __shfl_xor(mx, 32));
    float e[3][4], e3 = __expf(sv3 - mx);
    float sum = e3;
#pragma unroll
    for (int m = 0; m < 3; ++m)
#pragma unroll
      for (int r = 0; r < 4; ++r) { e[m][r] = __expf(sv[m][r] - mx); sum += e[m][r]; }
    sum += __shfl_xor(sum, 16);
    sum += __shfl_xor(sum, 32);
    float inv = 1.f / sum;
    float p3 = e3 * inv;
    float v3 = (g == 0) ? p3 : -1e30f;
    float mx2 = v3;
#pragma unroll
    for (int m = 0; m < 3; ++m)
#pragma unroll
      for (int r = 0; r < 4; ++r) mx2 = fmaxf(mx2, e[m][r] * inv);
    mx2 = fmaxf(mx2, __shfl_xor(mx2, 16));
    mx2 = fmaxf(mx2, __shfl_xor(mx2, 32));
    float e2[3][4], e23 = __expf(v3 - mx2);
    float sum2 = e23;
#pragma unroll
    for (int m = 0; m < 3; ++m)
#pragma unroll
      for (int r = 0; r < 4; ++r) { e2[m][r] = __expf(e[m][r] * inv - mx2); sum2 += e2[m][r]; }
    sum2 += __shfl_xor(sum2, 16);
    sum2 += __shfl_xor(sum2, 32);
    float inv2 = 1.f / sum2;
#pragma unroll
    for (int m = 0; m < 3; ++m) {
      uint u0 = (uint)f2bf(e2[m][0] * inv2) | ((uint)f2bf(e2[m][1] * inv2) << 16);
      uint u1 = (uint)f2bf(e2[m][2] * inv2) | ((uint)f2bf(e2[m][3] * inv2) << 16);
      *(uint*)&Pl[h][icol][m * 16 + g * 4]     = u0;
      *(uint*)&Pl[h][icol][m * 16 + g * 4 + 2] = u1;
    }
    uint u3 = (uint)f2bf(e23 * inv2);
    *(uint*)&Pl[h][icol][48 + g * 4]     = u3;
    *(uint*)&Pl[h][icol][48 + g * 4 + 2] = 0u;
  }
  __syncthreads();

  f32x4 oacc[4][2] = {};
#pragma unroll
  for (int ks = 0; ks < 2; ++ks) {
    int kloc = ks * 32 + g * 8;
    bf16x8 bf0 = *(const bf16x8*)&Vt[h][li][kloc];
    bf16x8 bf1 = *(const bf16x8*)&Vt[h][16 + li][kloc];
#pragma unroll
    for (int mi = 0; mi < 4; ++mi) {
      bf16x8 af = *(const bf16x8*)&Pl[h][mi * 16 + li][kloc];
      oacc[mi][0] = __builtin_amdgcn_mfma_f32_16x16x32_bf16(af, bf0, oacc[mi][0], 0, 0, 0);
      oacc[mi][1] = __builtin_amdgcn_mfma_f32_16x16x32_bf16(af, bf1, oacc[mi][1], 0, 0, 0);
    }
  }
  // stage O (49 x 32 per head) into Pl[h] (stride 40), then wide stores
  ushort* OlH = &Pl[h][0][0];
#pragma unroll
  for (int mi = 0; mi < 4; ++mi)
#pragma unroll
    for (int r = 0; r < 4; ++r) {
      int i = mi * 16 + g * 4 + r;
      if (mi < 3 || (g == 0 && r == 0)) {
        OlH[i * 40 + li]      = f2bf(oacc[mi][0][r]);
        OlH[i * 40 + 16 + li] = f2bf(oacc[mi][1][r]);
      }
    }
  __syncthreads();
  ushort* obase = ob + (size_t)win * 49 * 128;
#pragma unroll
  for (int it = 0; it < 4; ++it) {
    int chunk = tid + it * 256;  // 784 chunks of 8 ushorts
    if (chunk < 784) {
      int row = chunk >> 4, c8 = (chunk & 15) << 3;
      int h2 = c8 >> 5, d8 = c8 & 31;
      bf16x8 v = *(const bf16x8*)(&Pl[h2][0][0] + row * 40 + d8);
      *(bf16x8*)(obase + (size_t)row * 128 + c8) = v;
    }
  }
}

// ---------------------------------------------------------------------------
// K-MLP: fused  gelu(LN2out @ W1 + b1) @ W2 + b2 + out  per 32-token tile.
// h[32][512] lives in LDS; W1T/W2T served from L2.
// ---------------------------------------------------------------------------
__global__ __launch_bounds__(256) void k_mlp(
    const ushort* __restrict__ wp, const ushort* __restrict__ w1T,
    const float* __restrict__ b1, const ushort* __restrict__ w2T,
    const float* __restrict__ b2, float* __restrict__ out) {
  __shared__ ushort a_s[32][136];
  __shared__ ushort h[32][520];
  int tid = threadIdx.x;
  int lane = tid & 63, w = tid >> 6;
  int li = lane & 15, g = lane >> 4;
  int tokBase = blockIdx.x << 5;
  // load A tile (32 x 128 bf16)
#pragma unroll
  for (int it = 0; it < 2; ++it) {
    int chunk = tid + it * 256;  // 512 chunks of 8
    int row = chunk >> 4, c8 = (chunk & 15) << 3;
    *(bf16x8*)&a_s[row][c8] =
        *(const bf16x8*)(wp + (size_t)(tokBase + row) * 128 + c8);
  }
  __syncthreads();
  // phase 1: h = gelu(A @ W1 + b1); wave w -> cols [w*128, w*128+128)
  int wc1 = w << 7;
  f32x4 acc1[2][8] = {};
#pragma unroll
  for (int kk = 0; kk < 4; ++kk) {
    bf16x8 af0 = *(const bf16x8*)&a_s[li][kk * 32 + g * 8];
    bf16x8 af1 = *(const bf16x8*)&a_s[16 + li][kk * 32 + g * 8];
#pragma unroll
    for (int n = 0; n < 8; ++n) {
      bf16x8 bf = *(const bf16x8*)(w1T + (size_t)(wc1 + n * 16 + li) * 128 +
                                   kk * 32 + g * 8);
      acc1[0][n] = __builtin_amdgcn_mfma_f32_16x16x32_bf16(af0, bf, acc1[0][n], 0, 0, 0);
      acc1[1][n] = __builtin_amdgcn_mfma_f32_16x16x32_bf16(af1, bf, acc1[1][n], 0, 0, 0);
    }
  }
#pragma unroll
  for (int n = 0; n < 8; ++n) {
    float bb = b1[wc1 + n * 16 + li];
#pragma unroll
    for (int m = 0; m < 2; ++m)
#pragma unroll
      for (int r = 0; r < 4; ++r)
        h[m * 16 + g * 4 + r][wc1 + n * 16 + li] =
            f2bf(gelu_exact(acc1[m][n][r] + bb));
  }
  __syncthreads();
  // phase 2: out_tile = h @ W2 + b2; wave w -> cols [w*32, w*32+32)
  int wc2 = w << 5;
  f32x4 acc2[2][2] = {};
#pragma unroll
  for (int ks = 0; ks < 16; ++ks) {
    bf16x8 af0 = *(const bf16x8*)&h[li][ks * 32 + g * 8];
    bf16x8 af1 = *(const bf16x8*)&h[16 + li][ks * 32 + g * 8];
#pragma unroll
    for (int n = 0; n < 2; ++n) {
      bf16x8 bf = *(const bf16x8*)(w2T + (size_t)(wc2 + n * 16 + li) * 512 +
                                   ks * 32 + g * 8);
      acc2[0][n] = __builtin_amdgcn_mfma_f32_16x16x32_bf16(af0, bf, acc2[0][n], 0, 0, 0);
      acc2[1][n] = __builtin_amdgcn_mfma_f32_16x16x32_bf16(af1, bf, acc2[1][n], 0, 0, 0);
    }
  }
  __syncthreads();  // h reads done; reuse as f32 out staging
  float (*out_s)[130] = (float(*)[130])h;
#pragma unroll
  for (int n = 0; n < 2; ++n) {
    float bb = b2[wc2 + n * 16 + li];
#pragma unroll
    for (int m = 0; m < 2; ++m)
#pragma unroll
      for (int r = 0; r < 4; ++r)
        out_s[m * 16 + g * 4 + r][wc2 + n * 16 + li] = acc2[m][n][r] + bb;
  }
  __syncthreads();
  // cooperative residual add + coalesced float4 store
#pragma unroll
  for (int it = 0; it < 4; ++it) {
    int c4 = tid + it * 256;  // 1024 float4 chunks
    int row = c4 >> 5, cc = (c4 & 31) << 2;
    float* p = out + (size_t)(tokBase + row) * 128 + cc;
    float4 r4 = *(const float4*)p;
    r4.x += out_s[row][cc];
    r4.y += out_s[row][cc + 1];
    r4.z += out_s[row][cc + 2];
    r4.w += out_s[row][cc + 3];
    *(float4*)p = r4;
  }
}

extern "C" void kernel_launch(void* const* d_in, const int* in_sizes, int n_in,
                              void* d_out, int out_size, void* d_ws,
                              size_t ws_size, hipStream_t stream) {
  (void)in_sizes; (void)n_in; (void)out_size; (void)ws_size;
  const float* x      = (const float*)d_in[0];
  const float* qkv_w  = (const float*)d_in[1];
  const float* qkv_b  = (const float*)d_in[2];
  const float* proj_w = (const float*)d_in[3];
  const float* proj_b = (const float*)d_in[4];
  const float* plg    = (const float*)d_in[5];
  const float* plb    = (const float*)d_in[6];
  const float* rpb    = (const float*)d_in[7];
  const float* n1g    = (const float*)d_in[8];
  const float* n1b    = (const float*)d_in[9];
  const float* n2g    = (const float*)d_in[10];
  const float* n2b    = (const float*)d_in[11];
  const float* w1     = (const float*)d_in[12];
  const float* b1     = (const float*)d_in[13];
  const float* w2     = (const float*)d_in[14];
  const float* b2     = (const float*)d_in[15];
  float* out = (float*)d_out;

  // ws layout (ushort units), ~129 MB
  ushort* wp   = (ushort*)d_ws;                         // 100352*128
  ushort* qkvb = wp + (size_t)100352 * 128;             // 100352*384
  ushort* obb  = qkvb + (size_t)100352 * 384;           // 100352*128
  ushort* qkvT = obb + (size_t)100352 * 128;            // 384*128
  ushort* w1T  = qkvT + 384 * 128;                      // 512*128
  ushort* w2T  = w1T + 512 * 128;                       // 128*512
  ushort* pT   = w2T + 128 * 512;                       // 128*128
  float*  TB   = (float*)(pT + 128 * 128);              // 4*4*64*64 f32
  ushort* yb   = qkvb;  // alias: qkvb dead after k_attn

  k_prep<<<768, 256, 0, stream>>>(qkv_w, w1, w2, proj_w, qkvT, w1T, w2T, pT);
  k_prep2<<<256, 256, 0, stream>>>(rpb, TB);
  k_ln1_part<<<25088, 256, 0, stream>>>(x, n1g, n1b, wp);
  k_qkv<<<dim3(784, 3), 256, 0, stream>>>(wp, qkvT, qkv_b, qkvb);
  k_attn<<<2048, 256, 0, stream>>>(qkvb, TB, obb);
  k_pgemm<<<784, 256, 0, stream>>>(obb, pT, proj_b, plg, plb, yb);
  k_unshift<<<25088, 256, 0, stream>>>(x, yb, n2g, n2b, out, wp);
  k_mlp<<<3136, 256, 0, stream>>>(wp, w1T, b1, w2T, b2, out);
}

// Round 7
// 310.727 us; speedup vs baseline: 4.6422x; 1.0321x over previous
//
#include <hip/hip_runtime.h>
#include <cstdint>
#include <cstddef>

typedef __attribute__((ext_vector_type(8))) short bf16x8;
typedef __attribute__((ext_vector_type(4))) float f32x4;

namespace {
constexpr float kScale = 0.17677669529663689f; // 32^-0.5
constexpr float kEps = 1e-6f;
constexpr float kInvC = 1.0f / 128.0f;

__device__ __forceinline__ float gelu_exact(float v) {
  return 0.5f * v * (1.0f + erff(v * 0.70710678118654752f));
}
__device__ __forceinline__ ushort f2bf(float f) {
  uint32_t u = __builtin_bit_cast(uint32_t, f);
  u += 0x7FFFu + ((u >> 16) & 1u);
  return (ushort)(u >> 16);
}
__device__ __forceinline__ float bf2f(ushort u) {
  return __builtin_bit_cast(float, (uint32_t)u << 16);
}
} // namespace

// ---------------------------------------------------------------------------
// K0: convert+transpose weights to bf16 [N][K] layout.
// ---------------------------------------------------------------------------
__global__ __launch_bounds__(256) void k_prep(
    const float* __restrict__ qkv_w, const float* __restrict__ w1,
    const float* __restrict__ w2, const float* __restrict__ pw,
    ushort* __restrict__ qkvT, ushort* __restrict__ w1T,
    ushort* __restrict__ w2T, ushort* __restrict__ projT) {
  int i = blockIdx.x * 256 + threadIdx.x;
  if (i < 49152) {
    int n = i >> 7, k = i & 127;
    qkvT[i] = f2bf(qkv_w[k * 384 + n]);
  } else if (i < 114688) {
    int j = i - 49152;
    int n = j >> 7, k = j & 127;
    w1T[j] = f2bf(w1[k * 512 + n]);
  } else if (i < 180224) {
    int j = i - 114688;
    int n = j >> 9, k = j & 511;
    w2T[j] = f2bf(w2[k * 128 + n]);
  } else if (i < 196608) {
    int j = i - 180224;
    int n = j >> 7, k = j & 127;
    projT[j] = f2bf(pw[k * 128 + n]);
  }
}

// ---------------------------------------------------------------------------
// K0b: precompute bias+mask table TB[type(4)][head(4)][j(64)][i(64)] f32.
// ---------------------------------------------------------------------------
__global__ __launch_bounds__(256) void k_prep2(
    const float* __restrict__ rpb, float* __restrict__ TB) {
  int e = blockIdx.x * 256 + threadIdx.x;  // < 65536
  int i = e & 63, j = (e >> 6) & 63, h = (e >> 12) & 3, type = e >> 14;
  float v = 0.f;
  if (i < 49 && j < 49) {
    int ri = i / 7, ci = i - ri * 7, rj = j / 7, cj = j - rj * 7;
    int ridx = (ri - rj + 6) * 13 + (ci - cj + 6);
    float bias = rpb[ridx * 4 + h];
    int th = type >> 1, tw = type & 1;
    int labi = (th ? ((ri < 4) ? 1 : 2) : 0) * 3 + (tw ? ((ci < 4) ? 1 : 2) : 0);
    int labj = (th ? ((rj < 4) ? 1 : 2) : 0) * 3 + (tw ? ((cj < 4) ? 1 : 2) : 0);
    v = bias + ((labi != labj) ? -100.f : 0.f);
  }
  TB[e] = v;
}

// ---------------------------------------------------------------------------
// K1: LN(norm1) + cyclic shift(-3,-3) + window partition -> bf16
// ---------------------------------------------------------------------------
__global__ __launch_bounds__(256) void k_ln1_part(
    const float* __restrict__ x, const float* __restrict__ g,
    const float* __restrict__ b, ushort* __restrict__ wp) {
  int wv = threadIdx.x >> 6, lane = threadIdx.x & 63;
  int tok = blockIdx.x * 4 + wv;               // 0..100351
  int win = tok / 49, n = tok - win * 49;
  int bb = win >> 6, wi = win & 63;
  int whi = wi >> 3, wwi = wi & 7;
  int r = n / 7, c = n - r * 7;
  int hs = whi * 7 + r + 3; if (hs >= 56) hs -= 56;
  int ws = wwi * 7 + c + 3; if (ws >= 56) ws -= 56;
  size_t src = ((size_t)bb * 3136 + hs * 56 + ws) * 128;
  float2 v = *(const float2*)(x + src + lane * 2);
  float s = v.x + v.y, sq = v.x * v.x + v.y * v.y;
#pragma unroll
  for (int off = 1; off < 64; off <<= 1) {
    s += __shfl_xor(s, off);
    sq += __shfl_xor(sq, off);
  }
  float mu = s * kInvC;
  float var = sq * kInvC - mu * mu;
  float rs = rsqrtf(var + kEps);
  float2 gg = *(const float2*)(g + lane * 2);
  float2 bv = *(const float2*)(b + lane * 2);
  float o0 = (v.x - mu) * rs * gg.x + bv.x;
  float o1 = (v.y - mu) * rs * gg.y + bv.y;
  uint p = (uint)f2bf(o0) | ((uint)f2bf(o1) << 16);
  ((uint*)wp)[(size_t)tok * 64 + lane] = p;
}

// ---------------------------------------------------------------------------
// K-UNSHIFT: reverse window partition + reverse shift + residual + LN2.
// ---------------------------------------------------------------------------
__global__ __launch_bounds__(256) void k_unshift(
    const float* __restrict__ x, const ushort* __restrict__ yb,
    const float* __restrict__ g, const float* __restrict__ b,
    float* __restrict__ out, ushort* __restrict__ wp) {
  int wv = threadIdx.x >> 6, lane = threadIdx.x & 63;
  int tok = blockIdx.x * 4 + wv;               // natural: bb*3136 + ph*56 + pw
  int bb = tok / 3136, rem = tok - bb * 3136;
  int ph = rem / 56, pw = rem - ph * 56;
  int sh = ph + 53; if (sh >= 56) sh -= 56;    // (ph-3) mod 56
  int sw = pw + 53; if (sw >= 56) sw -= 56;
  int whi = sh / 7, r7 = sh - whi * 7;
  int wwi = sw / 7, c7 = sw - wwi * 7;
  int win = bb * 64 + whi * 8 + wwi, nn = r7 * 7 + c7;
  size_t row = (size_t)tok * 128;
  float2 xv = *(const float2*)(x + row + lane * 2);
  uint yv = ((const uint*)yb)[((size_t)win * 49 + nn) * 64 + lane];
  float o0 = xv.x + bf2f((ushort)(yv & 0xffff));
  float o1 = xv.y + bf2f((ushort)(yv >> 16));
  float2 ov; ov.x = o0; ov.y = o1;
  *(float2*)(out + row + lane * 2) = ov;
  float s = o0 + o1, sq = o0 * o0 + o1 * o1;
#pragma unroll
  for (int off = 1; off < 64; off <<= 1) {
    s += __shfl_xor(s, off);
    sq += __shfl_xor(sq, off);
  }
  float mu = s * kInvC;
  float var = sq * kInvC - mu * mu;
  float rs = rsqrtf(var + kEps);
  float2 gg = *(const float2*)(g + lane * 2);
  float2 bv = *(const float2*)(b + lane * 2);
  float m0 = (o0 - mu) * rs * gg.x + bv.x;
  float m1 = (o1 - mu) * rs * gg.y + bv.y;
  uint p = (uint)f2bf(m0) | ((uint)f2bf(m1) << 16);
  ((uint*)wp)[(size_t)tok * 64 + lane] = p;
}

// ---------------------------------------------------------------------------
// K-QKV: C[M,384] = A[M,128] @ qkvT^T + bias -> bf16, LDS-staged wide stores.
// grid (3, 784): consecutive blocks share the A-tile (L2 reuse).
// ---------------------------------------------------------------------------
__global__ __launch_bounds__(256) void k_qkv(
    const ushort* __restrict__ A, const ushort* __restrict__ BT,
    const float* __restrict__ bias, ushort* __restrict__ C) {
  __shared__ ushort sbuf[2 * 128 * 72];
  ushort (*As)[72] = (ushort(*)[72])sbuf;
  ushort (*Bs)[72] = (ushort(*)[72])(sbuf + 128 * 72);
  int tid = threadIdx.x;
  int mBase = blockIdx.y << 7;
  int nBase = blockIdx.x << 7;
  int lane = tid & 63, wid = tid >> 6;
  int li = lane & 15, g = lane >> 4;
  int wr = (wid >> 1) << 6, wc = (wid & 1) << 6;
  f32x4 acc[4][4] = {};
  for (int ks = 0; ks < 128; ks += 64) {
#pragma unroll
    for (int l = 0; l < 4; ++l) {
      int c = tid + l * 256;
      int row = c >> 3, k8 = (c & 7) << 3;
      *(bf16x8*)&As[row][k8] =
          *(const bf16x8*)(A + (size_t)(mBase + row) * 128 + ks + k8);
      *(bf16x8*)&Bs[row][k8] =
          *(const bf16x8*)(BT + (size_t)(nBase + row) * 128 + ks + k8);
    }
    __syncthreads();
#pragma unroll
    for (int ksub = 0; ksub < 64; ksub += 32) {
      int kloc = ksub + g * 8;
      bf16x8 af[4], bfr[4];
#pragma unroll
      for (int m = 0; m < 4; ++m)
        af[m] = *(const bf16x8*)&As[wr + m * 16 + li][kloc];
#pragma unroll
      for (int n = 0; n < 4; ++n)
        bfr[n] = *(const bf16x8*)&Bs[wc + n * 16 + li][kloc];
#pragma unroll
      for (int m = 0; m < 4; ++m)
#pragma unroll
        for (int n = 0; n < 4; ++n)
          acc[m][n] = __builtin_amdgcn_mfma_f32_16x16x32_bf16(
              af[m], bfr[n], acc[m][n], 0, 0, 0);
    }
    __syncthreads();
  }
  ushort (*Cs)[136] = (ushort(*)[136])sbuf;
#pragma unroll
  for (int n = 0; n < 4; ++n) {
    float bv = bias[nBase + wc + n * 16 + li];
#pragma unroll
    for (int m = 0; m < 4; ++m) {
      int rbase = wr + m * 16 + (g << 2);
#pragma unroll
      for (int r = 0; r < 4; ++r)
        Cs[rbase + r][wc + n * 16 + li] = f2bf(acc[m][n][r] + bv);
    }
  }
  __syncthreads();
#pragma unroll
  for (int it = 0; it < 8; ++it) {
    int chunk = tid + it * 256;  // 2048 chunks of 8 ushorts
    int row = chunk >> 4, c8 = (chunk & 15) << 3;
    *(bf16x8*)(C + (size_t)(mBase + row) * 384 + nBase + c8) =
        *(const bf16x8*)&Cs[row][c8];
  }
}

// ---------------------------------------------------------------------------
// K-MLP1: hb[M,512] = gelu(A[M,128] @ w1T^T + b1) -> bf16, staged stores.
// grid (4, 784): consecutive blocks share the A-tile.
// ---------------------------------------------------------------------------
__global__ __launch_bounds__(256) void k_mlp1(
    const ushort* __restrict__ A, const ushort* __restrict__ BT,
    const float* __restrict__ bias, ushort* __restrict__ hb) {
  __shared__ ushort sbuf[2 * 128 * 72];
  ushort (*As)[72] = (ushort(*)[72])sbuf;
  ushort (*Bs)[72] = (ushort(*)[72])(sbuf + 128 * 72);
  int tid = threadIdx.x;
  int mBase = blockIdx.y << 7;
  int nBase = blockIdx.x << 7;
  int lane = tid & 63, wid = tid >> 6;
  int li = lane & 15, g = lane >> 4;
  int wr = (wid >> 1) << 6, wc = (wid & 1) << 6;
  f32x4 acc[4][4] = {};
  for (int ks = 0; ks < 128; ks += 64) {
#pragma unroll
    for (int l = 0; l < 4; ++l) {
      int c = tid + l * 256;
      int row = c >> 3, k8 = (c & 7) << 3;
      *(bf16x8*)&As[row][k8] =
          *(const bf16x8*)(A + (size_t)(mBase + row) * 128 + ks + k8);
      *(bf16x8*)&Bs[row][k8] =
          *(const bf16x8*)(BT + (size_t)(nBase + row) * 128 + ks + k8);
    }
    __syncthreads();
#pragma unroll
    for (int ksub = 0; ksub < 64; ksub += 32) {
      int kloc = ksub + g * 8;
      bf16x8 af[4], bfr[4];
#pragma unroll
      for (int m = 0; m < 4; ++m)
        af[m] = *(const bf16x8*)&As[wr + m * 16 + li][kloc];
#pragma unroll
      for (int n = 0; n < 4; ++n)
        bfr[n] = *(const bf16x8*)&Bs[wc + n * 16 + li][kloc];
#pragma unroll
      for (int m = 0; m < 4; ++m)
#pragma unroll
        for (int n = 0; n < 4; ++n)
          acc[m][n] = __builtin_amdgcn_mfma_f32_16x16x32_bf16(
              af[m], bfr[n], acc[m][n], 0, 0, 0);
    }
    __syncthreads();
  }
  ushort (*Cs)[136] = (ushort(*)[136])sbuf;
#pragma unroll
  for (int n = 0; n < 4; ++n) {
    float bv = bias[nBase + wc + n * 16 + li];
#pragma unroll
    for (int m = 0; m < 4; ++m) {
      int rbase = wr + m * 16 + (g << 2);
#pragma unroll
      for (int r = 0; r < 4; ++r)
        Cs[rbase + r][wc + n * 16 + li] = f2bf(gelu_exact(acc[m][n][r] + bv));
    }
  }
  __syncthreads();
#pragma unroll
  for (int it = 0; it < 8; ++it) {
    int chunk = tid + it * 256;
    int row = chunk >> 4, c8 = (chunk & 15) << 3;
    *(bf16x8*)(hb + (size_t)(mBase + row) * 512 + nBase + c8) =
        *(const bf16x8*)&Cs[row][c8];
  }
}

// ---------------------------------------------------------------------------
// K-MLP2: out[M,128] += hb[M,512] @ w2T^T + b2   (f32 RMW, 64B-contig stores)
// ---------------------------------------------------------------------------
__global__ __launch_bounds__(256) void k_mlp2(
    const ushort* __restrict__ A, const ushort* __restrict__ BT,
    const float* __restrict__ bias, float* __restrict__ out) {
  __shared__ ushort As[128][72];
  __shared__ ushort Bs[128][72];
  int tid = threadIdx.x;
  int mBase = blockIdx.x << 7;
  int lane = tid & 63, wid = tid >> 6;
  int li = lane & 15, g = lane >> 4;
  int wr = (wid >> 1) << 6, wc = (wid & 1) << 6;
  f32x4 acc[4][4] = {};
  for (int ks = 0; ks < 512; ks += 64) {
#pragma unroll
    for (int l = 0; l < 4; ++l) {
      int c = tid + l * 256;
      int row = c >> 3, k8 = (c & 7) << 3;
      *(bf16x8*)&As[row][k8] =
          *(const bf16x8*)(A + (size_t)(mBase + row) * 512 + ks + k8);
      *(bf16x8*)&Bs[row][k8] =
          *(const bf16x8*)(BT + (size_t)row * 512 + ks + k8);
    }
    __syncthreads();
#pragma unroll
    for (int ksub = 0; ksub < 64; ksub += 32) {
      int kloc = ksub + g * 8;
      bf16x8 af[4], bfr[4];
#pragma unroll
      for (int m = 0; m < 4; ++m)
        af[m] = *(const bf16x8*)&As[wr + m * 16 + li][kloc];
#pragma unroll
      for (int n = 0; n < 4; ++n)
        bfr[n] = *(const bf16x8*)&Bs[wc + n * 16 + li][kloc];
#pragma unroll
      for (int m = 0; m < 4; ++m)
#pragma unroll
        for (int n = 0; n < 4; ++n)
          acc[m][n] = __builtin_amdgcn_mfma_f32_16x16x32_bf16(
              af[m], bfr[n], acc[m][n], 0, 0, 0);
    }
    __syncthreads();
  }
#pragma unroll
  for (int n = 0; n < 4; ++n) {
    int cg = wc + n * 16 + li;
    float bv = bias[cg];
#pragma unroll
    for (int m = 0; m < 4; ++m) {
      int rbase = mBase + wr + m * 16 + (g << 2);
#pragma unroll
      for (int r = 0; r < 4; ++r) {
        size_t off = (size_t)(rbase + r) * 128 + cg;
        out[off] += acc[m][n][r] + bv;
      }
    }
  }
}

// ---------------------------------------------------------------------------
// K-PGEMM: proj GEMM + bias + row-LN(proj_ln) + GELU -> bf16 yb (contiguous),
// LDS-staged wide stores.
// ---------------------------------------------------------------------------
__global__ __launch_bounds__(256) void k_pgemm(
    const ushort* __restrict__ A, const ushort* __restrict__ BT,
    const float* __restrict__ pb, const float* __restrict__ lg,
    const float* __restrict__ lb, ushort* __restrict__ yb) {
  __shared__ ushort sbuf[2 * 128 * 72];
  __shared__ float red[4][64][2];
  ushort (*As)[72] = (ushort(*)[72])sbuf;
  ushort (*Bs)[72] = (ushort(*)[72])(sbuf + 128 * 72);
  int tid = threadIdx.x;
  int mBase = blockIdx.x << 7;
  int lane = tid & 63, wid = tid >> 6;
  int li = lane & 15, g = lane >> 4;
  int wr = (wid >> 1) << 6, wc = (wid & 1) << 6;
  f32x4 acc[4][4] = {};
  for (int ks = 0; ks < 128; ks += 64) {
#pragma unroll
    for (int l = 0; l < 4; ++l) {
      int c = tid + l * 256;
      int row = c >> 3, k8 = (c & 7) << 3;
      *(bf16x8*)&As[row][k8] =
          *(const bf16x8*)(A + (size_t)(mBase + row) * 128 + ks + k8);
      *(bf16x8*)&Bs[row][k8] =
          *(const bf16x8*)(BT + (size_t)row * 128 + ks + k8);
    }
    __syncthreads();
#pragma unroll
    for (int ksub = 0; ksub < 64; ksub += 32) {
      int kloc = ksub + g * 8;
      bf16x8 af[4], bfr[4];
#pragma unroll
      for (int m = 0; m < 4; ++m)
        af[m] = *(const bf16x8*)&As[wr + m * 16 + li][kloc];
#pragma unroll
      for (int n = 0; n < 4; ++n)
        bfr[n] = *(const bf16x8*)&Bs[wc + n * 16 + li][kloc];
#pragma unroll
      for (int m = 0; m < 4; ++m)
#pragma unroll
        for (int n = 0; n < 4; ++n)
          acc[m][n] = __builtin_amdgcn_mfma_f32_16x16x32_bf16(
              af[m], bfr[n], acc[m][n], 0, 0, 0);
    }
    __syncthreads();
  }
  float pbv[4], lgv[4], lbv[4];
#pragma unroll
  for (int n = 0; n < 4; ++n) {
    int cg = wc + n * 16 + li;
    pbv[n] = pb[cg]; lgv[n] = lg[cg]; lbv[n] = lb[cg];
  }
  float ps[4][4], psq[4][4];
#pragma unroll
  for (int m = 0; m < 4; ++m)
#pragma unroll
    for (int r = 0; r < 4; ++r) {
      float s = 0.f, q = 0.f;
#pragma unroll
      for (int n = 0; n < 4; ++n) {
        float v = acc[m][n][r] + pbv[n];
        s += v; q += v * v;
      }
#pragma unroll
      for (int off = 1; off < 16; off <<= 1) {
        s += __shfl_xor(s, off);
        q += __shfl_xor(q, off);
      }
      ps[m][r] = s; psq[m][r] = q;
    }
  if (li == 0) {
#pragma unroll
    for (int m = 0; m < 4; ++m)
#pragma unroll
      for (int r = 0; r < 4; ++r) {
        int rl = m * 16 + (g << 2) + r;
        red[wid][rl][0] = ps[m][r];
        red[wid][rl][1] = psq[m][r];
      }
  }
  __syncthreads();
  ushort (*Cs)[136] = (ushort(*)[136])sbuf;
#pragma unroll
  for (int m = 0; m < 4; ++m) {
#pragma unroll
    for (int r = 0; r < 4; ++r) {
      int rl = m * 16 + (g << 2) + r;
      float s = ps[m][r] + red[wid ^ 1][rl][0];
      float q = psq[m][r] + red[wid ^ 1][rl][1];
      float mu = s * kInvC, var = q * kInvC - mu * mu;
      float rs = rsqrtf(var + kEps);
#pragma unroll
      for (int n = 0; n < 4; ++n) {
        float y = (acc[m][n][r] + pbv[n] - mu) * rs * lgv[n] + lbv[n];
        Cs[wr + rl][wc + n * 16 + li] = f2bf(gelu_exact(y));
      }
    }
  }
  __syncthreads();
#pragma unroll
  for (int it = 0; it < 8; ++it) {
    int chunk = tid + it * 256;
    int row = chunk >> 4, c8 = (chunk & 15) << 3;
    *(bf16x8*)(yb + (size_t)(mBase + row) * 128 + c8) =
        *(const bf16x8*)&Cs[row][c8];
  }
}

// ---------------------------------------------------------------------------
// K3: MFMA attention. 1 block = 1 window, 1 wave = 1 head. LDS-staged O store.
// ---------------------------------------------------------------------------
__global__ __launch_bounds__(256) void k_attn(
    const ushort* __restrict__ qkv, const float* __restrict__ TB,
    ushort* __restrict__ ob) {
  __shared__ ushort Pl[4][64][72];
  __shared__ ushort Vt[4][32][72];
  int tid = threadIdx.x;
  int lane = tid & 63, h = tid >> 6;
  int li = lane & 15, g = lane >> 4;
  int win = blockIdx.x;
  int wi = win & 63;
  int type = (((wi >> 3) == 7) ? 2 : 0) | (((wi & 7) == 7) ? 1 : 0);

  const ushort* qbase = qkv + (size_t)win * 49 * 384 + h * 32 + g * 8;
  bf16x8 kf[4], qf[4];
#pragma unroll
  for (int m = 0; m < 4; ++m) {
    kf[m] = *(const bf16x8*)(qbase + (size_t)(m * 16 + li) * 384 + 128);
    qf[m] = *(const bf16x8*)(qbase + (size_t)(m * 16 + li) * 384);
  }
  f32x4 zero = {0.f, 0.f, 0.f, 0.f};
  f32x4 st[4][4];
#pragma unroll
  for (int m = 0; m < 4; ++m)
#pragma unroll
    for (int n = 0; n < 4; ++n)
      st[m][n] = __builtin_amdgcn_mfma_f32_16x16x32_bf16(kf[m], qf[n], zero, 0, 0, 0);

  if (lane < 49) {
#pragma unroll
    for (int dc = 0; dc < 4; ++dc) {
      bf16x8 vv = *(const bf16x8*)(qkv + ((size_t)win * 49 + lane) * 384 + 256 +
                                   h * 32 + dc * 8);
#pragma unroll
      for (int t = 0; t < 8; ++t) Vt[h][dc * 8 + t][lane] = (ushort)vv[t];
    }
  } else {
#pragma unroll
    for (int d = 0; d < 32; ++d) Vt[h][d][lane] = 0;
  }

  const float* tb = TB + ((size_t)(type * 4 + h) << 12);
#pragma unroll
  for (int n = 0; n < 4; ++n) {
    int icol = n * 16 + li;
    float sv[3][4];
#pragma unroll
    for (int m = 0; m < 3; ++m)
#pragma unroll
      for (int r = 0; r < 4; ++r)
        sv[m][r] = st[m][n][r] * kScale + tb[(m * 16 + g * 4 + r) * 64 + icol];
    float sv3 = (g == 0) ? (st[3][n][0] * kScale + tb[48 * 64 + icol]) : -1e30f;
    float mx = sv3;
#pragma unroll
    for (int m = 0; m < 3; ++m)
#pragma unroll
      for (int r = 0; r < 4; ++r) mx = fmaxf(mx, sv[m][r]);
    mx = fmaxf(mx, __shfl_xor(mx, 16));
    mx = fmaxf(mx, __shfl_xor(mx, 32));
    float e[3][4], e3 = __expf(sv3 - mx);
    float sum = e3;
#pragma unroll
    for (int m = 0; m < 3; ++m)
#pragma unroll
      for (int r = 0; r < 4; ++r) { e[m][r] = __expf(sv[m][r] - mx); sum += e[m][r]; }
    sum += __shfl_xor(sum, 16);
    sum += __shfl_xor(sum, 32);
    float inv = 1.f / sum;
    float p3 = e3 * inv;
    float v3 = (g == 0) ? p3 : -1e30f;
    float mx2 = v3;
#pragma unroll
    for (int m = 0; m < 3; ++m)
#pragma unroll
      for (int r = 0; r < 4; ++r) mx2 = fmaxf(mx2, e[m][r] * inv);
    mx2 = fmaxf(mx2, __shfl_xor(mx2, 16));
    mx2 = fmaxf(mx2, __shfl_xor(mx2, 32));
    float e2[3][4], e23 = __expf(v3 - mx2);
    float sum2 = e23;
#pragma unroll
    for (int m = 0; m < 3; ++m)
#pragma unroll
      for (int r = 0; r < 4; ++r) { e2[m][r] = __expf(e[m][r] * inv - mx2); sum2 += e2[m][r]; }
    sum2 += __shfl_xor(sum2, 16);
    sum2 += __shfl_xor(sum2, 32);
    float inv2 = 1.f / sum2;
#pragma unroll
    for (int m = 0; m < 3; ++m) {
      uint u0 = (uint)f2bf(e2[m][0] * inv2) | ((uint)f2bf(e2[m][1] * inv2) << 16);
      uint u1 = (uint)f2bf(e2[m][2] * inv2) | ((uint)f2bf(e2[m][3] * inv2) << 16);
      *(uint*)&Pl[h][icol][m * 16 + g * 4]     = u0;
      *(uint*)&Pl[h][icol][m * 16 + g * 4 + 2] = u1;
    }
    uint u3 = (uint)f2bf(e23 * inv2);
    *(uint*)&Pl[h][icol][48 + g * 4]     = u3;
    *(uint*)&Pl[h][icol][48 + g * 4 + 2] = 0u;
  }
  __syncthreads();

  f32x4 oacc[4][2] = {};
#pragma unroll
  for (int ks = 0; ks < 2; ++ks) {
    int kloc = ks * 32 + g * 8;
    bf16x8 bf0 = *(const bf16x8*)&Vt[h][li][kloc];
    bf16x8 bf1 = *(const bf16x8*)&Vt[h][16 + li][kloc];
#pragma unroll
    for (int mi = 0; mi < 4; ++mi) {
      bf16x8 af = *(const bf16x8*)&Pl[h][mi * 16 + li][kloc];
      oacc[mi][0] = __builtin_amdgcn_mfma_f32_16x16x32_bf16(af, bf0, oacc[mi][0], 0, 0, 0);
      oacc[mi][1] = __builtin_amdgcn_mfma_f32_16x16x32_bf16(af, bf1, oacc[mi][1], 0, 0, 0);
    }
  }
  // stage O (49 x 32 per head) into Pl[h] (stride 40), then wide stores
  ushort* OlH = &Pl[h][0][0];
#pragma unroll
  for (int mi = 0; mi < 4; ++mi)
#pragma unroll
    for (int r = 0; r < 4; ++r) {
      int i = mi * 16 + g * 4 + r;
      if (mi < 3 || (g == 0 && r == 0)) {
        OlH[i * 40 + li]      = f2bf(oacc[mi][0][r]);
        OlH[i * 40 + 16 + li] = f2bf(oacc[mi][1][r]);
      }
    }
  __syncthreads();
  ushort* obase = ob + (size_t)win * 49 * 128;
#pragma unroll
  for (int it = 0; it < 4; ++it) {
    int chunk = tid + it * 256;  // 784 chunks of 8 ushorts
    if (chunk < 784) {
      int row = chunk >> 4, c8 = (chunk & 15) << 3;
      int h2 = c8 >> 5, d8 = c8 & 31;
      bf16x8 v = *(const bf16x8*)(&Pl[h2][0][0] + row * 40 + d8);
      *(bf16x8*)(obase + (size_t)row * 128 + c8) = v;
    }
  }
}

extern "C" void kernel_launch(void* const* d_in, const int* in_sizes, int n_in,
                              void* d_out, int out_size, void* d_ws,
                              size_t ws_size, hipStream_t stream) {
  (void)in_sizes; (void)n_in; (void)out_size; (void)ws_size;
  const float* x      = (const float*)d_in[0];
  const float* qkv_w  = (const float*)d_in[1];
  const float* qkv_b  = (const float*)d_in[2];
  const float* proj_w = (const float*)d_in[3];
  const float* proj_b = (const float*)d_in[4];
  const float* plg    = (const float*)d_in[5];
  const float* plb    = (const float*)d_in[6];
  const float* rpb    = (const float*)d_in[7];
  const float* n1g    = (const float*)d_in[8];
  const float* n1b    = (const float*)d_in[9];
  const float* n2g    = (const float*)d_in[10];
  const float* n2b    = (const float*)d_in[11];
  const float* w1     = (const float*)d_in[12];
  const float* b1     = (const float*)d_in[13];
  const float* w2     = (const float*)d_in[14];
  const float* b2     = (const float*)d_in[15];
  float* out = (float*)d_out;

  // ws layout (ushort units), ~233 MB
  ushort* wp   = (ushort*)d_ws;                         // 100352*128
  ushort* qkvb = wp + (size_t)100352 * 128;             // 100352*384
  ushort* obb  = qkvb + (size_t)100352 * 384;           // 100352*128
  ushort* hb   = obb + (size_t)100352 * 128;            // 100352*512
  ushort* qkvT = hb + (size_t)100352 * 512;             // 384*128
  ushort* w1T  = qkvT + 384 * 128;                      // 512*128
  ushort* w2T  = w1T + 512 * 128;                       // 128*512
  ushort* pT   = w2T + 128 * 512;                       // 128*128
  float*  TB   = (float*)(pT + 128 * 128);              // 4*4*64*64 f32
  ushort* yb   = qkvb;  // alias: qkvb dead after k_attn

  k_prep<<<768, 256, 0, stream>>>(qkv_w, w1, w2, proj_w, qkvT, w1T, w2T, pT);
  k_prep2<<<256, 256, 0, stream>>>(rpb, TB);
  k_ln1_part<<<25088, 256, 0, stream>>>(x, n1g, n1b, wp);
  k_qkv<<<dim3(3, 784), 256, 0, stream>>>(wp, qkvT, qkv_b, qkvb);
  k_attn<<<2048, 256, 0, stream>>>(qkvb, TB, obb);
  k_pgemm<<<784, 256, 0, stream>>>(obb, pT, proj_b, plg, plb, yb);
  k_unshift<<<25088, 256, 0, stream>>>(x, yb, n2g, n2b, out, wp);
  k_mlp1<<<dim3(4, 784), 256, 0, stream>>>(wp, w1T, b1, hb);
  k_mlp2<<<784, 256, 0, stream>>>(hb, w2T, b2, out);
}

// Round 8
// 299.081 us; speedup vs baseline: 4.8230x; 1.0389x over previous
//
#include <hip/hip_runtime.h>
#include <cstdint>
#include <cstddef>

typedef __attribute__((ext_vector_type(8))) short bf16x8;
typedef __attribute__((ext_vector_type(4))) float f32x4;

namespace {
constexpr float kScale = 0.17677669529663689f; // 32^-0.5
constexpr float kEps = 1e-6f;
constexpr float kInvC = 1.0f / 128.0f;

// tanh-form GELU via hardware exp; |err| vs exact erf-GELU < 3e-3.
__device__ __forceinline__ float gelu_fast(float v) {
  float u = 0.7978845608028654f * v * (1.0f + 0.044715f * v * v);
  float e = __expf(2.0f * u);
  float t = 1.0f - 2.0f / (e + 1.0f);
  return 0.5f * v * (1.0f + t);
}
__device__ __forceinline__ ushort f2bf(float f) {
  uint32_t u = __builtin_bit_cast(uint32_t, f);
  u += 0x7FFFu + ((u >> 16) & 1u);
  return (ushort)(u >> 16);
}
__device__ __forceinline__ float bf2f(ushort u) {
  return __builtin_bit_cast(float, (uint32_t)u << 16);
}
} // namespace

// ---------------------------------------------------------------------------
// K0: convert+transpose weights to bf16 [N][K] layout.
// ---------------------------------------------------------------------------
__global__ __launch_bounds__(256) void k_prep(
    const float* __restrict__ qkv_w, const float* __restrict__ w1,
    const float* __restrict__ w2, const float* __restrict__ pw,
    ushort* __restrict__ qkvT, ushort* __restrict__ w1T,
    ushort* __restrict__ w2T, ushort* __restrict__ projT) {
  int i = blockIdx.x * 256 + threadIdx.x;
  if (i < 49152) {
    int n = i >> 7, k = i & 127;
    qkvT[i] = f2bf(qkv_w[k * 384 + n]);
  } else if (i < 114688) {
    int j = i - 49152;
    int n = j >> 7, k = j & 127;
    w1T[j] = f2bf(w1[k * 512 + n]);
  } else if (i < 180224) {
    int j = i - 114688;
    int n = j >> 9, k = j & 511;
    w2T[j] = f2bf(w2[k * 128 + n]);
  } else if (i < 196608) {
    int j = i - 180224;
    int n = j >> 7, k = j & 127;
    projT[j] = f2bf(pw[k * 128 + n]);
  }
}

// ---------------------------------------------------------------------------
// K0b: precompute bias+mask table TB[type(4)][head(4)][j(64)][i(64)] f32.
// ---------------------------------------------------------------------------
__global__ __launch_bounds__(256) void k_prep2(
    const float* __restrict__ rpb, float* __restrict__ TB) {
  int e = blockIdx.x * 256 + threadIdx.x;  // < 65536
  int i = e & 63, j = (e >> 6) & 63, h = (e >> 12) & 3, type = e >> 14;
  float v = 0.f;
  if (i < 49 && j < 49) {
    int ri = i / 7, ci = i - ri * 7, rj = j / 7, cj = j - rj * 7;
    int ridx = (ri - rj + 6) * 13 + (ci - cj + 6);
    float bias = rpb[ridx * 4 + h];
    int th = type >> 1, tw = type & 1;
    int labi = (th ? ((ri < 4) ? 1 : 2) : 0) * 3 + (tw ? ((ci < 4) ? 1 : 2) : 0);
    int labj = (th ? ((rj < 4) ? 1 : 2) : 0) * 3 + (tw ? ((cj < 4) ? 1 : 2) : 0);
    v = bias + ((labi != labj) ? -100.f : 0.f);
  }
  TB[e] = v;
}

// ---------------------------------------------------------------------------
// K1: LN(norm1) + cyclic shift(-3,-3) + window partition -> bf16
// float4 loads, half-wave (32-lane) per token. 8 tokens/block.
// ---------------------------------------------------------------------------
__global__ __launch_bounds__(256) void k_ln1_part(
    const float* __restrict__ x, const float* __restrict__ g,
    const float* __restrict__ b, ushort* __restrict__ wp) {
  int lane = threadIdx.x & 63, wv = threadIdx.x >> 6;
  int half = lane >> 5, l32 = lane & 31;
  int tok = blockIdx.x * 8 + wv * 2 + half;    // 0..100351
  int win = tok / 49, n = tok - win * 49;
  int bb = win >> 6, wi = win & 63;
  int whi = wi >> 3, wwi = wi & 7;
  int r = n / 7, c = n - r * 7;
  int hs = whi * 7 + r + 3; if (hs >= 56) hs -= 56;
  int ws = wwi * 7 + c + 3; if (ws >= 56) ws -= 56;
  size_t src = ((size_t)bb * 3136 + hs * 56 + ws) * 128;
  float4 v = *(const float4*)(x + src + l32 * 4);
  float s = v.x + v.y + v.z + v.w;
  float sq = v.x * v.x + v.y * v.y + v.z * v.z + v.w * v.w;
#pragma unroll
  for (int off = 1; off < 32; off <<= 1) {
    s += __shfl_xor(s, off);
    sq += __shfl_xor(sq, off);
  }
  float mu = s * kInvC;
  float var = sq * kInvC - mu * mu;
  float rs = rsqrtf(var + kEps);
  float4 gg = *(const float4*)(g + l32 * 4);
  float4 bv = *(const float4*)(b + l32 * 4);
  float o0 = (v.x - mu) * rs * gg.x + bv.x;
  float o1 = (v.y - mu) * rs * gg.y + bv.y;
  float o2 = (v.z - mu) * rs * gg.z + bv.z;
  float o3 = (v.w - mu) * rs * gg.w + bv.w;
  uint2 p;
  p.x = (uint)f2bf(o0) | ((uint)f2bf(o1) << 16);
  p.y = (uint)f2bf(o2) | ((uint)f2bf(o3) << 16);
  ((uint2*)wp)[(size_t)tok * 32 + l32] = p;
}

// ---------------------------------------------------------------------------
// K-UNSHIFT: reverse window partition + reverse shift + residual + LN2.
// float4/uint2, half-wave per token. 8 tokens/block.
// ---------------------------------------------------------------------------
__global__ __launch_bounds__(256) void k_unshift(
    const float* __restrict__ x, const ushort* __restrict__ yb,
    const float* __restrict__ g, const float* __restrict__ b,
    float* __restrict__ out, ushort* __restrict__ wp) {
  int lane = threadIdx.x & 63, wv = threadIdx.x >> 6;
  int half = lane >> 5, l32 = lane & 31;
  int tok = blockIdx.x * 8 + wv * 2 + half;    // natural order
  int bb = tok / 3136, rem = tok - bb * 3136;
  int ph = rem / 56, pw = rem - ph * 56;
  int sh = ph + 53; if (sh >= 56) sh -= 56;    // (ph-3) mod 56
  int sw = pw + 53; if (sw >= 56) sw -= 56;
  int whi = sh / 7, r7 = sh - whi * 7;
  int wwi = sw / 7, c7 = sw - wwi * 7;
  int win = bb * 64 + whi * 8 + wwi, nn = r7 * 7 + c7;
  size_t row = (size_t)tok * 128;
  float4 xv = *(const float4*)(x + row + l32 * 4);
  uint2 yv = ((const uint2*)yb)[((size_t)win * 49 + nn) * 32 + l32];
  float o0 = xv.x + bf2f((ushort)(yv.x & 0xffff));
  float o1 = xv.y + bf2f((ushort)(yv.x >> 16));
  float o2 = xv.z + bf2f((ushort)(yv.y & 0xffff));
  float o3 = xv.w + bf2f((ushort)(yv.y >> 16));
  float4 ov; ov.x = o0; ov.y = o1; ov.z = o2; ov.w = o3;
  *(float4*)(out + row + l32 * 4) = ov;
  float s = o0 + o1 + o2 + o3;
  float sq = o0 * o0 + o1 * o1 + o2 * o2 + o3 * o3;
#pragma unroll
  for (int off = 1; off < 32; off <<= 1) {
    s += __shfl_xor(s, off);
    sq += __shfl_xor(sq, off);
  }
  float mu = s * kInvC;
  float var = sq * kInvC - mu * mu;
  float rs = rsqrtf(var + kEps);
  float4 gg = *(const float4*)(g + l32 * 4);
  float4 bv = *(const float4*)(b + l32 * 4);
  float m0 = (o0 - mu) * rs * gg.x + bv.x;
  float m1 = (o1 - mu) * rs * gg.y + bv.y;
  float m2 = (o2 - mu) * rs * gg.z + bv.z;
  float m3 = (o3 - mu) * rs * gg.w + bv.w;
  uint2 p;
  p.x = (uint)f2bf(m0) | ((uint)f2bf(m1) << 16);
  p.y = (uint)f2bf(m2) | ((uint)f2bf(m3) << 16);
  ((uint2*)wp)[(size_t)tok * 32 + l32] = p;
}

// ---------------------------------------------------------------------------
// K-GEMM-WIDE: C[M, NCHUNKS*128] = A[M,128] @ BT^T + bias, K=128.
// A staged ONCE per block (full K); loop over N-chunks; C staged through the
// Bs region for contiguous bf16x8 stores. EPI 0: bias. EPI 1: bias+gelu.
// ---------------------------------------------------------------------------
template <int NCHUNKS, int EPI>
__global__ __launch_bounds__(256) void k_gemm_wide(
    const ushort* __restrict__ A, const ushort* __restrict__ BT,
    const float* __restrict__ bias, ushort* __restrict__ C) {
  __shared__ ushort As[128][136];
  __shared__ ushort Bs[128][136];
  constexpr int ldC = NCHUNKS * 128;
  int tid = threadIdx.x;
  int mBase = blockIdx.x << 7;
  int lane = tid & 63, wid = tid >> 6;
  int li = lane & 15, g = lane >> 4;
  int wr = (wid >> 1) << 6, wc = (wid & 1) << 6;
  // stage A once: 128 rows x 128 k
#pragma unroll
  for (int l = 0; l < 8; ++l) {
    int ch = tid + l * 256;
    int row = ch >> 4, k8 = (ch & 15) << 3;
    *(bf16x8*)&As[row][k8] =
        *(const bf16x8*)(A + (size_t)(mBase + row) * 128 + k8);
  }
  for (int nc = 0; nc < NCHUNKS; ++nc) {
    int nBase = nc << 7;
    __syncthreads();  // A visible (nc=0) / previous chunk's Cs reads done
#pragma unroll
    for (int l = 0; l < 8; ++l) {
      int ch = tid + l * 256;
      int row = ch >> 4, k8 = (ch & 15) << 3;
      *(bf16x8*)&Bs[row][k8] =
          *(const bf16x8*)(BT + (size_t)(nBase + row) * 128 + k8);
    }
    __syncthreads();
    f32x4 acc[4][4] = {};
#pragma unroll
    for (int ksub = 0; ksub < 128; ksub += 32) {
      int kloc = ksub + g * 8;
      bf16x8 af[4], bfr[4];
#pragma unroll
      for (int m = 0; m < 4; ++m)
        af[m] = *(const bf16x8*)&As[wr + m * 16 + li][kloc];
#pragma unroll
      for (int n = 0; n < 4; ++n)
        bfr[n] = *(const bf16x8*)&Bs[wc + n * 16 + li][kloc];
#pragma unroll
      for (int m = 0; m < 4; ++m)
#pragma unroll
        for (int n = 0; n < 4; ++n)
          acc[m][n] = __builtin_amdgcn_mfma_f32_16x16x32_bf16(
              af[m], bfr[n], acc[m][n], 0, 0, 0);
    }
    __syncthreads();  // Bs MFMA reads done -> safe to overlay Cs
#pragma unroll
    for (int n = 0; n < 4; ++n) {
      float bv = bias[nBase + wc + n * 16 + li];
#pragma unroll
      for (int m = 0; m < 4; ++m) {
        int rl = wr + m * 16 + (g << 2);
#pragma unroll
        for (int r = 0; r < 4; ++r) {
          float v = acc[m][n][r] + bv;
          if (EPI == 1) v = gelu_fast(v);
          Bs[rl + r][wc + n * 16 + li] = f2bf(v);
        }
      }
    }
    __syncthreads();
#pragma unroll
    for (int l = 0; l < 8; ++l) {
      int ch = tid + l * 256;
      int row = ch >> 4, c8 = (ch & 15) << 3;
      *(bf16x8*)(C + (size_t)(mBase + row) * ldC + nBase + c8) =
          *(const bf16x8*)&Bs[row][c8];
    }
  }
}

// ---------------------------------------------------------------------------
// K-MLP2: out[M,128] += hb[M,512] @ w2T^T + b2   (f32 RMW, 64B-contig stores)
// ---------------------------------------------------------------------------
__global__ __launch_bounds__(256) void k_mlp2(
    const ushort* __restrict__ A, const ushort* __restrict__ BT,
    const float* __restrict__ bias, float* __restrict__ out) {
  __shared__ ushort As[128][72];
  __shared__ ushort Bs[128][72];
  int tid = threadIdx.x;
  int mBase = blockIdx.x << 7;
  int lane = tid & 63, wid = tid >> 6;
  int li = lane & 15, g = lane >> 4;
  int wr = (wid >> 1) << 6, wc = (wid & 1) << 6;
  f32x4 acc[4][4] = {};
  for (int ks = 0; ks < 512; ks += 64) {
#pragma unroll
    for (int l = 0; l < 4; ++l) {
      int c = tid + l * 256;
      int row = c >> 3, k8 = (c & 7) << 3;
      *(bf16x8*)&As[row][k8] =
          *(const bf16x8*)(A + (size_t)(mBase + row) * 512 + ks + k8);
      *(bf16x8*)&Bs[row][k8] =
          *(const bf16x8*)(BT + (size_t)row * 512 + ks + k8);
    }
    __syncthreads();
#pragma unroll
    for (int ksub = 0; ksub < 64; ksub += 32) {
      int kloc = ksub + g * 8;
      bf16x8 af[4], bfr[4];
#pragma unroll
      for (int m = 0; m < 4; ++m)
        af[m] = *(const bf16x8*)&As[wr + m * 16 + li][kloc];
#pragma unroll
      for (int n = 0; n < 4; ++n)
        bfr[n] = *(const bf16x8*)&Bs[wc + n * 16 + li][kloc];
#pragma unroll
      for (int m = 0; m < 4; ++m)
#pragma unroll
        for (int n = 0; n < 4; ++n)
          acc[m][n] = __builtin_amdgcn_mfma_f32_16x16x32_bf16(
              af[m], bfr[n], acc[m][n], 0, 0, 0);
    }
    __syncthreads();
  }
#pragma unroll
  for (int n = 0; n < 4; ++n) {
    int cg = wc + n * 16 + li;
    float bv = bias[cg];
#pragma unroll
    for (int m = 0; m < 4; ++m) {
      int rbase = mBase + wr + m * 16 + (g << 2);
#pragma unroll
      for (int r = 0; r < 4; ++r) {
        size_t off = (size_t)(rbase + r) * 128 + cg;
        out[off] += acc[m][n][r] + bv;
      }
    }
  }
}

// ---------------------------------------------------------------------------
// K-PGEMM: proj GEMM + bias + row-LN(proj_ln) + GELU -> bf16 yb (contiguous),
// LDS-staged wide stores.
// ---------------------------------------------------------------------------
__global__ __launch_bounds__(256) void k_pgemm(
    const ushort* __restrict__ A, const ushort* __restrict__ BT,
    const float* __restrict__ pb, const float* __restrict__ lg,
    const float* __restrict__ lb, ushort* __restrict__ yb) {
  __shared__ ushort sbuf[2 * 128 * 72];
  __shared__ float red[4][64][2];
  ushort (*As)[72] = (ushort(*)[72])sbuf;
  ushort (*Bs)[72] = (ushort(*)[72])(sbuf + 128 * 72);
  int tid = threadIdx.x;
  int mBase = blockIdx.x << 7;
  int lane = tid & 63, wid = tid >> 6;
  int li = lane & 15, g = lane >> 4;
  int wr = (wid >> 1) << 6, wc = (wid & 1) << 6;
  f32x4 acc[4][4] = {};
  for (int ks = 0; ks < 128; ks += 64) {
#pragma unroll
    for (int l = 0; l < 4; ++l) {
      int c = tid + l * 256;
      int row = c >> 3, k8 = (c & 7) << 3;
      *(bf16x8*)&As[row][k8] =
          *(const bf16x8*)(A + (size_t)(mBase + row) * 128 + ks + k8);
      *(bf16x8*)&Bs[row][k8] =
          *(const bf16x8*)(BT + (size_t)row * 128 + ks + k8);
    }
    __syncthreads();
#pragma unroll
    for (int ksub = 0; ksub < 64; ksub += 32) {
      int kloc = ksub + g * 8;
      bf16x8 af[4], bfr[4];
#pragma unroll
      for (int m = 0; m < 4; ++m)
        af[m] = *(const bf16x8*)&As[wr + m * 16 + li][kloc];
#pragma unroll
      for (int n = 0; n < 4; ++n)
        bfr[n] = *(const bf16x8*)&Bs[wc + n * 16 + li][kloc];
#pragma unroll
      for (int m = 0; m < 4; ++m)
#pragma unroll
        for (int n = 0; n < 4; ++n)
          acc[m][n] = __builtin_amdgcn_mfma_f32_16x16x32_bf16(
              af[m], bfr[n], acc[m][n], 0, 0, 0);
    }
    __syncthreads();
  }
  float pbv[4], lgv[4], lbv[4];
#pragma unroll
  for (int n = 0; n < 4; ++n) {
    int cg = wc + n * 16 + li;
    pbv[n] = pb[cg]; lgv[n] = lg[cg]; lbv[n] = lb[cg];
  }
  float ps[4][4], psq[4][4];
#pragma unroll
  for (int m = 0; m < 4; ++m)
#pragma unroll
    for (int r = 0; r < 4; ++r) {
      float s = 0.f, q = 0.f;
#pragma unroll
      for (int n = 0; n < 4; ++n) {
        float v = acc[m][n][r] + pbv[n];
        s += v; q += v * v;
      }
#pragma unroll
      for (int off = 1; off < 16; off <<= 1) {
        s += __shfl_xor(s, off);
        q += __shfl_xor(q, off);
      }
      ps[m][r] = s; psq[m][r] = q;
    }
  if (li == 0) {
#pragma unroll
    for (int m = 0; m < 4; ++m)
#pragma unroll
      for (int r = 0; r < 4; ++r) {
        int rl = m * 16 + (g << 2) + r;
        red[wid][rl][0] = ps[m][r];
        red[wid][rl][1] = psq[m][r];
      }
  }
  __syncthreads();
  ushort (*Cs)[136] = (ushort(*)[136])sbuf;
#pragma unroll
  for (int m = 0; m < 4; ++m) {
#pragma unroll
    for (int r = 0; r < 4; ++r) {
      int rl = m * 16 + (g << 2) + r;
      float s = ps[m][r] + red[wid ^ 1][rl][0];
      float q = psq[m][r] + red[wid ^ 1][rl][1];
      float mu = s * kInvC, var = q * kInvC - mu * mu;
      float rs = rsqrtf(var + kEps);
#pragma unroll
      for (int n = 0; n < 4; ++n) {
        float y = (acc[m][n][r] + pbv[n] - mu) * rs * lgv[n] + lbv[n];
        Cs[wr + rl][wc + n * 16 + li] = f2bf(gelu_fast(y));
      }
    }
  }
  __syncthreads();
#pragma unroll
  for (int it = 0; it < 8; ++it) {
    int chunk = tid + it * 256;
    int row = chunk >> 4, c8 = (chunk & 15) << 3;
    *(bf16x8*)(yb + (size_t)(mBase + row) * 128 + c8) =
        *(const bf16x8*)&Cs[row][c8];
  }
}

// ---------------------------------------------------------------------------
// K3: MFMA attention. 1 block = 1 window, 1 wave = 1 head. LDS-staged O store.
// ---------------------------------------------------------------------------
__global__ __launch_bounds__(256) void k_attn(
    const ushort* __restrict__ qkv, const float* __restrict__ TB,
    ushort* __restrict__ ob) {
  __shared__ ushort Pl[4][64][72];
  __shared__ ushort Vt[4][32][72];
  int tid = threadIdx.x;
  int lane = tid & 63, h = tid >> 6;
  int li = lane & 15, g = lane >> 4;
  int win = blockIdx.x;
  int wi = win & 63;
  int type = (((wi >> 3) == 7) ? 2 : 0) | (((wi & 7) == 7) ? 1 : 0);

  const ushort* qbase = qkv + (size_t)win * 49 * 384 + h * 32 + g * 8;
  bf16x8 kf[4], qf[4];
#pragma unroll
  for (int m = 0; m < 4; ++m) {
    kf[m] = *(const bf16x8*)(qbase + (size_t)(m * 16 + li) * 384 + 128);
    qf[m] = *(const bf16x8*)(qbase + (size_t)(m * 16 + li) * 384);
  }
  f32x4 zero = {0.f, 0.f, 0.f, 0.f};
  f32x4 st[4][4];
#pragma unroll
  for (int m = 0; m < 4; ++m)
#pragma unroll
    for (int n = 0; n < 4; ++n)
      st[m][n] = __builtin_amdgcn_mfma_f32_16x16x32_bf16(kf[m], qf[n], zero, 0, 0, 0);

  if (lane < 49) {
#pragma unroll
    for (int dc = 0; dc < 4; ++dc) {
      bf16x8 vv = *(const bf16x8*)(qkv + ((size_t)win * 49 + lane) * 384 + 256 +
                                   h * 32 + dc * 8);
#pragma unroll
      for (int t = 0; t < 8; ++t) Vt[h][dc * 8 + t][lane] = (ushort)vv[t];
    }
  } else {
#pragma unroll
    for (int d = 0; d < 32; ++d) Vt[h][d][lane] = 0;
  }

  const float* tb = TB + ((size_t)(type * 4 + h) << 12);
#pragma unroll
  for (int n = 0; n < 4; ++n) {
    int icol = n * 16 + li;
    float sv[3][4];
#pragma unroll
    for (int m = 0; m < 3; ++m)
#pragma unroll
      for (int r = 0; r < 4; ++r)
        sv[m][r] = st[m][n][r] * kScale + tb[(m * 16 + g * 4 + r) * 64 + icol];
    float sv3 = (g == 0) ? (st[3][n][0] * kScale + tb[48 * 64 + icol]) : -1e30f;
    float mx = sv3;
#pragma unroll
    for (int m = 0; m < 3; ++m)
#pragma unroll
      for (int r = 0; r < 4; ++r) mx = fmaxf(mx, sv[m][r]);
    mx = fmaxf(mx, __shfl_xor(mx, 16));
    mx = fmaxf(mx, __shfl_xor(mx, 32));
    float e[3][4], e3 = __expf(sv3 - mx);
    float sum = e3;
#pragma unroll
    for (int m = 0; m < 3; ++m)
#pragma unroll
      for (int r = 0; r < 4; ++r) { e[m][r] = __expf(sv[m][r] - mx); sum += e[m][r]; }
    sum += __shfl_xor(sum, 16);
    sum += __shfl_xor(sum, 32);
    float inv = 1.f / sum;
    float p3 = e3 * inv;
    float v3 = (g == 0) ? p3 : -1e30f;
    float mx2 = v3;
#pragma unroll
    for (int m = 0; m < 3; ++m)
#pragma unroll
      for (int r = 0; r < 4; ++r) mx2 = fmaxf(mx2, e[m][r] * inv);
    mx2 = fmaxf(mx2, __shfl_xor(mx2, 16));
    mx2 = fmaxf(mx2, __shfl_xor(mx2, 32));
    float e2[3][4], e23 = __expf(v3 - mx2);
    float sum2 = e23;
#pragma unroll
    for (int m = 0; m < 3; ++m)
#pragma unroll
      for (int r = 0; r < 4; ++r) { e2[m][r] = __expf(e[m][r] * inv - mx2); sum2 += e2[m][r]; }
    sum2 += __shfl_xor(sum2, 16);
    sum2 += __shfl_xor(sum2, 32);
    float inv2 = 1.f / sum2;
#pragma unroll
    for (int m = 0; m < 3; ++m) {
      uint u0 = (uint)f2bf(e2[m][0] * inv2) | ((uint)f2bf(e2[m][1] * inv2) << 16);
      uint u1 = (uint)f2bf(e2[m][2] * inv2) | ((uint)f2bf(e2[m][3] * inv2) << 16);
      *(uint*)&Pl[h][icol][m * 16 + g * 4]     = u0;
      *(uint*)&Pl[h][icol][m * 16 + g * 4 + 2] = u1;
    }
    uint u3 = (uint)f2bf(e23 * inv2);
    *(uint*)&Pl[h][icol][48 + g * 4]     = u3;
    *(uint*)&Pl[h][icol][48 + g * 4 + 2] = 0u;
  }
  __syncthreads();

  f32x4 oacc[4][2] = {};
#pragma unroll
  for (int ks = 0; ks < 2; ++ks) {
    int kloc = ks * 32 + g * 8;
    bf16x8 bf0 = *(const bf16x8*)&Vt[h][li][kloc];
    bf16x8 bf1 = *(const bf16x8*)&Vt[h][16 + li][kloc];
#pragma unroll
    for (int mi = 0; mi < 4; ++mi) {
      bf16x8 af = *(const bf16x8*)&Pl[h][mi * 16 + li][kloc];
      oacc[mi][0] = __builtin_amdgcn_mfma_f32_16x16x32_bf16(af, bf0, oacc[mi][0], 0, 0, 0);
      oacc[mi][1] = __builtin_amdgcn_mfma_f32_16x16x32_bf16(af, bf1, oacc[mi][1], 0, 0, 0);
    }
  }
  // stage O (49 x 32 per head) into Pl[h] (stride 40), then wide stores
  ushort* OlH = &Pl[h][0][0];
#pragma unroll
  for (int mi = 0; mi < 4; ++mi)
#pragma unroll
    for (int r = 0; r < 4; ++r) {
      int i = mi * 16 + g * 4 + r;
      if (mi < 3 || (g == 0 && r == 0)) {
        OlH[i * 40 + li]      = f2bf(oacc[mi][0][r]);
        OlH[i * 40 + 16 + li] = f2bf(oacc[mi][1][r]);
      }
    }
  __syncthreads();
  ushort* obase = ob + (size_t)win * 49 * 128;
#pragma unroll
  for (int it = 0; it < 4; ++it) {
    int chunk = tid + it * 256;  // 784 chunks of 8 ushorts
    if (chunk < 784) {
      int row = chunk >> 4, c8 = (chunk & 15) << 3;
      int h2 = c8 >> 5, d8 = c8 & 31;
      bf16x8 v = *(const bf16x8*)(&Pl[h2][0][0] + row * 40 + d8);
      *(bf16x8*)(obase + (size_t)row * 128 + c8) = v;
    }
  }
}

extern "C" void kernel_launch(void* const* d_in, const int* in_sizes, int n_in,
                              void* d_out, int out_size, void* d_ws,
                              size_t ws_size, hipStream_t stream) {
  (void)in_sizes; (void)n_in; (void)out_size; (void)ws_size;
  const float* x      = (const float*)d_in[0];
  const float* qkv_w  = (const float*)d_in[1];
  const float* qkv_b  = (const float*)d_in[2];
  const float* proj_w = (const float*)d_in[3];
  const float* proj_b = (const float*)d_in[4];
  const float* plg    = (const float*)d_in[5];
  const float* plb    = (const float*)d_in[6];
  const float* rpb    = (const float*)d_in[7];
  const float* n1g    = (const float*)d_in[8];
  const float* n1b    = (const float*)d_in[9];
  const float* n2g    = (const float*)d_in[10];
  const float* n2b    = (const float*)d_in[11];
  const float* w1     = (const float*)d_in[12];
  const float* b1     = (const float*)d_in[13];
  const float* w2     = (const float*)d_in[14];
  const float* b2     = (const float*)d_in[15];
  float* out = (float*)d_out;

  // ws layout (ushort units), ~233 MB
  ushort* wp   = (ushort*)d_ws;                         // 100352*128
  ushort* qkvb = wp + (size_t)100352 * 128;             // 100352*384
  ushort* obb  = qkvb + (size_t)100352 * 384;           // 100352*128
  ushort* hb   = obb + (size_t)100352 * 128;            // 100352*512
  ushort* qkvT = hb + (size_t)100352 * 512;             // 384*128
  ushort* w1T  = qkvT + 384 * 128;                      // 512*128
  ushort* w2T  = w1T + 512 * 128;                       // 128*512
  ushort* pT   = w2T + 128 * 512;                       // 128*128
  float*  TB   = (float*)(pT + 128 * 128);              // 4*4*64*64 f32
  ushort* yb   = qkvb;  // alias: qkvb dead after k_attn

  k_prep<<<768, 256, 0, stream>>>(qkv_w, w1, w2, proj_w, qkvT, w1T, w2T, pT);
  k_prep2<<<256, 256, 0, stream>>>(rpb, TB);
  k_ln1_part<<<12544, 256, 0, stream>>>(x, n1g, n1b, wp);
  k_gemm_wide<3, 0><<<784, 256, 0, stream>>>(wp, qkvT, qkv_b, qkvb);
  k_attn<<<2048, 256, 0, stream>>>(qkvb, TB, obb);
  k_pgemm<<<784, 256, 0, stream>>>(obb, pT, proj_b, plg, plb, yb);
  k_unshift<<<12544, 256, 0, stream>>>(x, yb, n2g, n2b, out, wp);
  k_gemm_wide<4, 1><<<784, 256, 0, stream>>>(wp, w1T, b1, hb);
  k_mlp2<<<784, 256, 0, stream>>>(hb, w2T, b2, out);
}

// Round 9
// 251.634 us; speedup vs baseline: 5.7324x; 1.1886x over previous
//
#include <hip/hip_runtime.h>
#include <cstdint>
#include <cstddef>

typedef __attribute__((ext_vector_type(8))) short bf16x8;
typedef __attribute__((ext_vector_type(4))) float f32x4;

namespace {
constexpr float kScale = 0.17677669529663689f; // 32^-0.5
constexpr float kEps = 1e-6f;
constexpr float kInvC = 1.0f / 128.0f;

// tanh-form GELU via hardware exp; |err| vs exact erf-GELU < 3e-3.
__device__ __forceinline__ float gelu_fast(float v) {
  float u = 0.7978845608028654f * v * (1.0f + 0.044715f * v * v);
  float e = __expf(2.0f * u);
  float t = 1.0f - 2.0f / (e + 1.0f);
  return 0.5f * v * (1.0f + t);
}
__device__ __forceinline__ ushort f2bf(float f) {
  uint32_t u = __builtin_bit_cast(uint32_t, f);
  u += 0x7FFFu + ((u >> 16) & 1u);
  return (ushort)(u >> 16);
}
__device__ __forceinline__ float bf2f(ushort u) {
  return __builtin_bit_cast(float, (uint32_t)u << 16);
}
// async global->LDS, 16B per lane. LDS dest is wave-uniform base + lane*16.
__device__ __forceinline__ void gl16(const ushort* g, ushort* l) {
  __builtin_amdgcn_global_load_lds(
      (const __attribute__((address_space(1))) void*)g,
      (__attribute__((address_space(3))) void*)l, 16, 0, 0);
}
} // namespace

// ---------------------------------------------------------------------------
// K0: convert+transpose weights to bf16 [N][K] layout.
// ---------------------------------------------------------------------------
__global__ __launch_bounds__(256) void k_prep(
    const float* __restrict__ qkv_w, const float* __restrict__ w1,
    const float* __restrict__ w2, const float* __restrict__ pw,
    ushort* __restrict__ qkvT, ushort* __restrict__ w1T,
    ushort* __restrict__ w2T, ushort* __restrict__ projT) {
  int i = blockIdx.x * 256 + threadIdx.x;
  if (i < 49152) {
    int n = i >> 7, k = i & 127;
    qkvT[i] = f2bf(qkv_w[k * 384 + n]);
  } else if (i < 114688) {
    int j = i - 49152;
    int n = j >> 7, k = j & 127;
    w1T[j] = f2bf(w1[k * 512 + n]);
  } else if (i < 180224) {
    int j = i - 114688;
    int n = j >> 9, k = j & 511;
    w2T[j] = f2bf(w2[k * 128 + n]);
  } else if (i < 196608) {
    int j = i - 180224;
    int n = j >> 7, k = j & 127;
    projT[j] = f2bf(pw[k * 128 + n]);
  }
}

// ---------------------------------------------------------------------------
// K0b: precompute bias+mask table TB[type(4)][head(4)][j(64)][i(64)] f32.
// ---------------------------------------------------------------------------
__global__ __launch_bounds__(256) void k_prep2(
    const float* __restrict__ rpb, float* __restrict__ TB) {
  int e = blockIdx.x * 256 + threadIdx.x;  // < 65536
  int i = e & 63, j = (e >> 6) & 63, h = (e >> 12) & 3, type = e >> 14;
  float v = 0.f;
  if (i < 49 && j < 49) {
    int ri = i / 7, ci = i - ri * 7, rj = j / 7, cj = j - rj * 7;
    int ridx = (ri - rj + 6) * 13 + (ci - cj + 6);
    float bias = rpb[ridx * 4 + h];
    int th = type >> 1, tw = type & 1;
    int labi = (th ? ((ri < 4) ? 1 : 2) : 0) * 3 + (tw ? ((ci < 4) ? 1 : 2) : 0);
    int labj = (th ? ((rj < 4) ? 1 : 2) : 0) * 3 + (tw ? ((cj < 4) ? 1 : 2) : 0);
    v = bias + ((labi != labj) ? -100.f : 0.f);
  }
  TB[e] = v;
}

// ---------------------------------------------------------------------------
// K1: LN(norm1) + cyclic shift(-3,-3) + window partition -> bf16
// ---------------------------------------------------------------------------
__global__ __launch_bounds__(256) void k_ln1_part(
    const float* __restrict__ x, const float* __restrict__ g,
    const float* __restrict__ b, ushort* __restrict__ wp) {
  int lane = threadIdx.x & 63, wv = threadIdx.x >> 6;
  int half = lane >> 5, l32 = lane & 31;
  int tok = blockIdx.x * 8 + wv * 2 + half;    // 0..100351
  int win = tok / 49, n = tok - win * 49;
  int bb = win >> 6, wi = win & 63;
  int whi = wi >> 3, wwi = wi & 7;
  int r = n / 7, c = n - r * 7;
  int hs = whi * 7 + r + 3; if (hs >= 56) hs -= 56;
  int ws = wwi * 7 + c + 3; if (ws >= 56) ws -= 56;
  size_t src = ((size_t)bb * 3136 + hs * 56 + ws) * 128;
  float4 v = *(const float4*)(x + src + l32 * 4);
  float s = v.x + v.y + v.z + v.w;
  float sq = v.x * v.x + v.y * v.y + v.z * v.z + v.w * v.w;
#pragma unroll
  for (int off = 1; off < 32; off <<= 1) {
    s += __shfl_xor(s, off);
    sq += __shfl_xor(sq, off);
  }
  float mu = s * kInvC;
  float var = sq * kInvC - mu * mu;
  float rs = rsqrtf(var + kEps);
  float4 gg = *(const float4*)(g + l32 * 4);
  float4 bv = *(const float4*)(b + l32 * 4);
  float o0 = (v.x - mu) * rs * gg.x + bv.x;
  float o1 = (v.y - mu) * rs * gg.y + bv.y;
  float o2 = (v.z - mu) * rs * gg.z + bv.z;
  float o3 = (v.w - mu) * rs * gg.w + bv.w;
  uint2 p;
  p.x = (uint)f2bf(o0) | ((uint)f2bf(o1) << 16);
  p.y = (uint)f2bf(o2) | ((uint)f2bf(o3) << 16);
  ((uint2*)wp)[(size_t)tok * 32 + l32] = p;
}

// ---------------------------------------------------------------------------
// K-UNSHIFT: reverse window partition + reverse shift + residual + LN2.
// ---------------------------------------------------------------------------
__global__ __launch_bounds__(256) void k_unshift(
    const float* __restrict__ x, const ushort* __restrict__ yb,
    const float* __restrict__ g, const float* __restrict__ b,
    float* __restrict__ out, ushort* __restrict__ wp) {
  int lane = threadIdx.x & 63, wv = threadIdx.x >> 6;
  int half = lane >> 5, l32 = lane & 31;
  int tok = blockIdx.x * 8 + wv * 2 + half;    // natural order
  int bb = tok / 3136, rem = tok - bb * 3136;
  int ph = rem / 56, pw = rem - ph * 56;
  int sh = ph + 53; if (sh >= 56) sh -= 56;    // (ph-3) mod 56
  int sw = pw + 53; if (sw >= 56) sw -= 56;
  int whi = sh / 7, r7 = sh - whi * 7;
  int wwi = sw / 7, c7 = sw - wwi * 7;
  int win = bb * 64 + whi * 8 + wwi, nn = r7 * 7 + c7;
  size_t row = (size_t)tok * 128;
  float4 xv = *(const float4*)(x + row + l32 * 4);
  uint2 yv = ((const uint2*)yb)[((size_t)win * 49 + nn) * 32 + l32];
  float o0 = xv.x + bf2f((ushort)(yv.x & 0xffff));
  float o1 = xv.y + bf2f((ushort)(yv.x >> 16));
  float o2 = xv.z + bf2f((ushort)(yv.y & 0xffff));
  float o3 = xv.w + bf2f((ushort)(yv.y >> 16));
  float4 ov; ov.x = o0; ov.y = o1; ov.z = o2; ov.w = o3;
  *(float4*)(out + row + l32 * 4) = ov;
  float s = o0 + o1 + o2 + o3;
  float sq = o0 * o0 + o1 * o1 + o2 * o2 + o3 * o3;
#pragma unroll
  for (int off = 1; off < 32; off <<= 1) {
    s += __shfl_xor(s, off);
    sq += __shfl_xor(sq, off);
  }
  float mu = s * kInvC;
  float var = sq * kInvC - mu * mu;
  float rs = rsqrtf(var + kEps);
  float4 gg = *(const float4*)(g + l32 * 4);
  float4 bv = *(const float4*)(b + l32 * 4);
  float m0 = (o0 - mu) * rs * gg.x + bv.x;
  float m1 = (o1 - mu) * rs * gg.y + bv.y;
  float m2 = (o2 - mu) * rs * gg.z + bv.z;
  float m3 = (o3 - mu) * rs * gg.w + bv.w;
  uint2 p;
  p.x = (uint)f2bf(m0) | ((uint)f2bf(m1) << 16);
  p.y = (uint)f2bf(m2) | ((uint)f2bf(m3) << 16);
  ((uint2*)wp)[(size_t)tok * 32 + l32] = p;
}

// ---------------------------------------------------------------------------
// K-GEMM2: C[M,LDC chunk] = A[M,K] @ BT[N,K]^T + bias. 128x128 tile, BK=64,
// global_load_lds (width 16) staging into linear [128][64] LDS tiles.
// EPI 0: bias -> bf16. EPI 1: bias+gelu -> bf16. Stores staged via Cs overlay.
// ---------------------------------------------------------------------------
template <int K, int LDC, int EPI>
__global__ __launch_bounds__(256) void k_gemm2(
    const ushort* __restrict__ A, const ushort* __restrict__ BT,
    const float* __restrict__ bias, ushort* __restrict__ C) {
  __shared__ ushort sbuf[128 * 128];  // 32 KB: As|Bs, overlaid by Cs
  ushort (*As)[64] = (ushort(*)[64])sbuf;
  ushort (*Bs)[64] = (ushort(*)[64])(sbuf + 128 * 64);
  int tid = threadIdx.x;
  int nBase = blockIdx.x << 7;
  int mBase = blockIdx.y << 7;
  int lane = tid & 63, wid = tid >> 6;
  int li = lane & 15, g = lane >> 4;
  int wr = (wid >> 1) << 6, wc = (wid & 1) << 6;
  f32x4 acc[4][4] = {};
  for (int ks = 0; ks < K; ks += 64) {
#pragma unroll
    for (int l = 0; l < 4; ++l) {
      int c = l * 256 + tid;
      int row = c >> 3, k8 = (c & 7) << 3;
      int lo = (l * 256 + wid * 64) * 8;  // wave-uniform LDS offset (ushorts)
      gl16(A + (size_t)(mBase + row) * K + ks + k8, sbuf + lo);
      gl16(BT + (size_t)(nBase + row) * K + ks + k8, sbuf + 128 * 64 + lo);
    }
    __syncthreads();
#pragma unroll
    for (int ksub = 0; ksub < 64; ksub += 32) {
      int kloc = ksub + g * 8;
      bf16x8 af[4], bfr[4];
#pragma unroll
      for (int m = 0; m < 4; ++m)
        af[m] = *(const bf16x8*)&As[wr + m * 16 + li][kloc];
#pragma unroll
      for (int n = 0; n < 4; ++n)
        bfr[n] = *(const bf16x8*)&Bs[wc + n * 16 + li][kloc];
#pragma unroll
      for (int m = 0; m < 4; ++m)
#pragma unroll
        for (int n = 0; n < 4; ++n)
          acc[m][n] = __builtin_amdgcn_mfma_f32_16x16x32_bf16(
              af[m], bfr[n], acc[m][n], 0, 0, 0);
    }
    __syncthreads();
  }
  ushort (*Cs)[128] = (ushort(*)[128])sbuf;
#pragma unroll
  for (int n = 0; n < 4; ++n) {
    float bv = bias[nBase + wc + n * 16 + li];
#pragma unroll
    for (int m = 0; m < 4; ++m) {
      int rb = wr + m * 16 + (g << 2);
#pragma unroll
      for (int r = 0; r < 4; ++r) {
        float v = acc[m][n][r] + bv;
        if (EPI == 1) v = gelu_fast(v);
        Cs[rb + r][wc + n * 16 + li] = f2bf(v);
      }
    }
  }
  __syncthreads();
#pragma unroll
  for (int it = 0; it < 8; ++it) {
    int ch = tid + it * 256;
    int row = ch >> 4, c8 = (ch & 15) << 3;
    *(bf16x8*)(C + (size_t)(mBase + row) * LDC + nBase + c8) =
        *(const bf16x8*)&Cs[row][c8];
  }
}

// ---------------------------------------------------------------------------
// K-MLP2: out[M,128] += hb[M,512] @ w2T^T + b2. gload_lds staging, K=512.
// ---------------------------------------------------------------------------
__global__ __launch_bounds__(256) void k_mlp2(
    const ushort* __restrict__ A, const ushort* __restrict__ BT,
    const float* __restrict__ bias, float* __restrict__ out) {
  __shared__ ushort sbuf[128 * 128];
  ushort (*As)[64] = (ushort(*)[64])sbuf;
  ushort (*Bs)[64] = (ushort(*)[64])(sbuf + 128 * 64);
  int tid = threadIdx.x;
  int mBase = blockIdx.x << 7;
  int lane = tid & 63, wid = tid >> 6;
  int li = lane & 15, g = lane >> 4;
  int wr = (wid >> 1) << 6, wc = (wid & 1) << 6;
  f32x4 acc[4][4] = {};
  for (int ks = 0; ks < 512; ks += 64) {
#pragma unroll
    for (int l = 0; l < 4; ++l) {
      int c = l * 256 + tid;
      int row = c >> 3, k8 = (c & 7) << 3;
      int lo = (l * 256 + wid * 64) * 8;
      gl16(A + (size_t)(mBase + row) * 512 + ks + k8, sbuf + lo);
      gl16(BT + (size_t)row * 512 + ks + k8, sbuf + 128 * 64 + lo);
    }
    __syncthreads();
#pragma unroll
    for (int ksub = 0; ksub < 64; ksub += 32) {
      int kloc = ksub + g * 8;
      bf16x8 af[4], bfr[4];
#pragma unroll
      for (int m = 0; m < 4; ++m)
        af[m] = *(const bf16x8*)&As[wr + m * 16 + li][kloc];
#pragma unroll
      for (int n = 0; n < 4; ++n)
        bfr[n] = *(const bf16x8*)&Bs[wc + n * 16 + li][kloc];
#pragma unroll
      for (int m = 0; m < 4; ++m)
#pragma unroll
        for (int n = 0; n < 4; ++n)
          acc[m][n] = __builtin_amdgcn_mfma_f32_16x16x32_bf16(
              af[m], bfr[n], acc[m][n], 0, 0, 0);
    }
    __syncthreads();
  }
#pragma unroll
  for (int n = 0; n < 4; ++n) {
    int cg = wc + n * 16 + li;
    float bv = bias[cg];
#pragma unroll
    for (int m = 0; m < 4; ++m) {
      int rbase = mBase + wr + m * 16 + (g << 2);
#pragma unroll
      for (int r = 0; r < 4; ++r) {
        size_t off = (size_t)(rbase + r) * 128 + cg;
        out[off] += acc[m][n][r] + bv;
      }
    }
  }
}

// ---------------------------------------------------------------------------
// K-PGEMM: proj GEMM + bias + row-LN(proj_ln) + GELU -> bf16 yb (contiguous).
// gload_lds staging; LDS-staged wide stores.
// ---------------------------------------------------------------------------
__global__ __launch_bounds__(256) void k_pgemm(
    const ushort* __restrict__ A, const ushort* __restrict__ BT,
    const float* __restrict__ pb, const float* __restrict__ lg,
    const float* __restrict__ lb, ushort* __restrict__ yb) {
  __shared__ ushort sbuf[128 * 128];
  __shared__ float red[4][64][2];
  ushort (*As)[64] = (ushort(*)[64])sbuf;
  ushort (*Bs)[64] = (ushort(*)[64])(sbuf + 128 * 64);
  int tid = threadIdx.x;
  int mBase = blockIdx.x << 7;
  int lane = tid & 63, wid = tid >> 6;
  int li = lane & 15, g = lane >> 4;
  int wr = (wid >> 1) << 6, wc = (wid & 1) << 6;
  f32x4 acc[4][4] = {};
  for (int ks = 0; ks < 128; ks += 64) {
#pragma unroll
    for (int l = 0; l < 4; ++l) {
      int c = l * 256 + tid;
      int row = c >> 3, k8 = (c & 7) << 3;
      int lo = (l * 256 + wid * 64) * 8;
      gl16(A + (size_t)(mBase + row) * 128 + ks + k8, sbuf + lo);
      gl16(BT + (size_t)row * 128 + ks + k8, sbuf + 128 * 64 + lo);
    }
    __syncthreads();
#pragma unroll
    for (int ksub = 0; ksub < 64; ksub += 32) {
      int kloc = ksub + g * 8;
      bf16x8 af[4], bfr[4];
#pragma unroll
      for (int m = 0; m < 4; ++m)
        af[m] = *(const bf16x8*)&As[wr + m * 16 + li][kloc];
#pragma unroll
      for (int n = 0; n < 4; ++n)
        bfr[n] = *(const bf16x8*)&Bs[wc + n * 16 + li][kloc];
#pragma unroll
      for (int m = 0; m < 4; ++m)
#pragma unroll
        for (int n = 0; n < 4; ++n)
          acc[m][n] = __builtin_amdgcn_mfma_f32_16x16x32_bf16(
              af[m], bfr[n], acc[m][n], 0, 0, 0);
    }
    __syncthreads();
  }
  float pbv[4], lgv[4], lbv[4];
#pragma unroll
  for (int n = 0; n < 4; ++n) {
    int cg = wc + n * 16 + li;
    pbv[n] = pb[cg]; lgv[n] = lg[cg]; lbv[n] = lb[cg];
  }
  float ps[4][4], psq[4][4];
#pragma unroll
  for (int m = 0; m < 4; ++m)
#pragma unroll
    for (int r = 0; r < 4; ++r) {
      float s = 0.f, q = 0.f;
#pragma unroll
      for (int n = 0; n < 4; ++n) {
        float v = acc[m][n][r] + pbv[n];
        s += v; q += v * v;
      }
#pragma unroll
      for (int off = 1; off < 16; off <<= 1) {
        s += __shfl_xor(s, off);
        q += __shfl_xor(q, off);
      }
      ps[m][r] = s; psq[m][r] = q;
    }
  if (li == 0) {
#pragma unroll
    for (int m = 0; m < 4; ++m)
#pragma unroll
      for (int r = 0; r < 4; ++r) {
        int rl = m * 16 + (g << 2) + r;
        red[wid][rl][0] = ps[m][r];
        red[wid][rl][1] = psq[m][r];
      }
  }
  __syncthreads();
  ushort (*Cs)[128] = (ushort(*)[128])sbuf;
#pragma unroll
  for (int m = 0; m < 4; ++m) {
#pragma unroll
    for (int r = 0; r < 4; ++r) {
      int rl = m * 16 + (g << 2) + r;
      float s = ps[m][r] + red[wid ^ 1][rl][0];
      float q = psq[m][r] + red[wid ^ 1][rl][1];
      float mu = s * kInvC, var = q * kInvC - mu * mu;
      float rs = rsqrtf(var + kEps);
#pragma unroll
      for (int n = 0; n < 4; ++n) {
        float y = (acc[m][n][r] + pbv[n] - mu) * rs * lgv[n] + lbv[n];
        Cs[wr + rl][wc + n * 16 + li] = f2bf(gelu_fast(y));
      }
    }
  }
  __syncthreads();
#pragma unroll
  for (int it = 0; it < 8; ++it) {
    int ch = tid + it * 256;
    int row = ch >> 4, c8 = (ch & 15) << 3;
    *(bf16x8*)(yb + (size_t)(mBase + row) * 128 + c8) =
        *(const bf16x8*)&Cs[row][c8];
  }
}

// ---------------------------------------------------------------------------
// K3: MFMA attention. 1 block = 1 window, 1 wave = 1 head. LDS-staged O store.
// ---------------------------------------------------------------------------
__global__ __launch_bounds__(256) void k_attn(
    const ushort* __restrict__ qkv, const float* __restrict__ TB,
    ushort* __restrict__ ob) {
  __shared__ ushort Pl[4][64][72];
  __shared__ ushort Vt[4][32][72];
  int tid = threadIdx.x;
  int lane = tid & 63, h = tid >> 6;
  int li = lane & 15, g = lane >> 4;
  int win = blockIdx.x;
  int wi = win & 63;
  int type = (((wi >> 3) == 7) ? 2 : 0) | (((wi & 7) == 7) ? 1 : 0);

  const ushort* qbase = qkv + (size_t)win * 49 * 384 + h * 32 + g * 8;
  bf16x8 kf[4], qf[4];
#pragma unroll
  for (int m = 0; m < 4; ++m) {
    kf[m] = *(const bf16x8*)(qbase + (size_t)(m * 16 + li) * 384 + 128);
    qf[m] = *(const bf16x8*)(qbase + (size_t)(m * 16 + li) * 384);
  }
  f32x4 zero = {0.f, 0.f, 0.f, 0.f};
  f32x4 st[4][4];
#pragma unroll
  for (int m = 0; m < 4; ++m)
#pragma unroll
    for (int n = 0; n < 4; ++n)
      st[m][n] = __builtin_amdgcn_mfma_f32_16x16x32_bf16(kf[m], qf[n], zero, 0, 0, 0);

  if (lane < 49) {
#pragma unroll
    for (int dc = 0; dc < 4; ++dc) {
      bf16x8 vv = *(const bf16x8*)(qkv + ((size_t)win * 49 + lane) * 384 + 256 +
                                   h * 32 + dc * 8);
#pragma unroll
      for (int t = 0; t < 8; ++t) Vt[h][dc * 8 + t][lane] = (ushort)vv[t];
    }
  } else {
#pragma unroll
    for (int d = 0; d < 32; ++d) Vt[h][d][lane] = 0;
  }

  const float* tb = TB + ((size_t)(type * 4 + h) << 12);
#pragma unroll
  for (int n = 0; n < 4; ++n) {
    int icol = n * 16 + li;
    float sv[3][4];
#pragma unroll
    for (int m = 0; m < 3; ++m)
#pragma unroll
      for (int r = 0; r < 4; ++r)
        sv[m][r] = st[m][n][r] * kScale + tb[(m * 16 + g * 4 + r) * 64 + icol];
    float sv3 = (g == 0) ? (st[3][n][0] * kScale + tb[48 * 64 + icol]) : -1e30f;
    float mx = sv3;
#pragma unroll
    for (int m = 0; m < 3; ++m)
#pragma unroll
      for (int r = 0; r < 4; ++r) mx = fmaxf(mx, sv[m][r]);
    mx = fmaxf(mx, __shfl_xor(mx, 16));
    mx = fmaxf(mx, __shfl_xor(mx, 32));
    float e[3][4], e3 = __expf(sv3 - mx);
    float sum = e3;
#pragma unroll
    for (int m = 0; m < 3; ++m)
#pragma unroll
      for (int r = 0; r < 4; ++r) { e[m][r] = __expf(sv[m][r] - mx); sum += e[m][r]; }
    sum += __shfl_xor(sum, 16);
    sum += __shfl_xor(sum, 32);
    float inv = 1.f / sum;
    float p3 = e3 * inv;
    float v3 = (g == 0) ? p3 : -1e30f;
    float mx2 = v3;
#pragma unroll
    for (int m = 0; m < 3; ++m)
#pragma unroll
      for (int r = 0; r < 4; ++r) mx2 = fmaxf(mx2, e[m][r] * inv);
    mx2 = fmaxf(mx2, __shfl_xor(mx2, 16));
    mx2 = fmaxf(mx2, __shfl_xor(mx2, 32));
    float e2[3][4], e23 = __expf(v3 - mx2);
    float sum2 = e23;
#pragma unroll
    for (int m = 0; m < 3; ++m)
#pragma unroll
      for (int r = 0; r < 4; ++r) { e2[m][r] = __expf(e[m][r] * inv - mx2); sum2 += e2[m][r]; }
    sum2 += __shfl_xor(sum2, 16);
    sum2 += __shfl_xor(sum2, 32);
    float inv2 = 1.f / sum2;
#pragma unroll
    for (int m = 0; m < 3; ++m) {
      uint u0 = (uint)f2bf(e2[m][0] * inv2) | ((uint)f2bf(e2[m][1] * inv2) << 16);
      uint u1 = (uint)f2bf(e2[m][2] * inv2) | ((uint)f2bf(e2[m][3] * inv2) << 16);
      *(uint*)&Pl[h][icol][m * 16 + g * 4]     = u0;
      *(uint*)&Pl[h][icol][m * 16 + g * 4 + 2] = u1;
    }
    uint u3 = (uint)f2bf(e23 * inv2);
    *(uint*)&Pl[h][icol][48 + g * 4]     = u3;
    *(uint*)&Pl[h][icol][48 + g * 4 + 2] = 0u;
  }
  __syncthreads();

  f32x4 oacc[4][2] = {};
#pragma unroll
  for (int ks = 0; ks < 2; ++ks) {
    int kloc = ks * 32 + g * 8;
    bf16x8 bf0 = *(const bf16x8*)&Vt[h][li][kloc];
    bf16x8 bf1 = *(const bf16x8*)&Vt[h][16 + li][kloc];
#pragma unroll
    for (int mi = 0; mi < 4; ++mi) {
      bf16x8 af = *(const bf16x8*)&Pl[h][mi * 16 + li][kloc];
      oacc[mi][0] = __builtin_amdgcn_mfma_f32_16x16x32_bf16(af, bf0, oacc[mi][0], 0, 0, 0);
      oacc[mi][1] = __builtin_amdgcn_mfma_f32_16x16x32_bf16(af, bf1, oacc[mi][1], 0, 0, 0);
    }
  }
  // stage O (49 x 32 per head) into Pl[h] (stride 40), then wide stores
  ushort* OlH = &Pl[h][0][0];
#pragma unroll
  for (int mi = 0; mi < 4; ++mi)
#pragma unroll
    for (int r = 0; r < 4; ++r) {
      int i = mi * 16 + g * 4 + r;
      if (mi < 3 || (g == 0 && r == 0)) {
        OlH[i * 40 + li]      = f2bf(oacc[mi][0][r]);
        OlH[i * 40 + 16 + li] = f2bf(oacc[mi][1][r]);
      }
    }
  __syncthreads();
  ushort* obase = ob + (size_t)win * 49 * 128;
#pragma unroll
  for (int it = 0; it < 4; ++it) {
    int chunk = tid + it * 256;  // 784 chunks of 8 ushorts
    if (chunk < 784) {
      int row = chunk >> 4, c8 = (chunk & 15) << 3;
      int h2 = c8 >> 5, d8 = c8 & 31;
      bf16x8 v = *(const bf16x8*)(&Pl[h2][0][0] + row * 40 + d8);
      *(bf16x8*)(obase + (size_t)row * 128 + c8) = v;
    }
  }
}

extern "C" void kernel_launch(void* const* d_in, const int* in_sizes, int n_in,
                              void* d_out, int out_size, void* d_ws,
                              size_t ws_size, hipStream_t stream) {
  (void)in_sizes; (void)n_in; (void)out_size; (void)ws_size;
  const float* x      = (const float*)d_in[0];
  const float* qkv_w  = (const float*)d_in[1];
  const float* qkv_b  = (const float*)d_in[2];
  const float* proj_w = (const float*)d_in[3];
  const float* proj_b = (const float*)d_in[4];
  const float* plg    = (const float*)d_in[5];
  const float* plb    = (const float*)d_in[6];
  const float* rpb    = (const float*)d_in[7];
  const float* n1g    = (const float*)d_in[8];
  const float* n1b    = (const float*)d_in[9];
  const float* n2g    = (const float*)d_in[10];
  const float* n2b    = (const float*)d_in[11];
  const float* w1     = (const float*)d_in[12];
  const float* b1     = (const float*)d_in[13];
  const float* w2     = (const float*)d_in[14];
  const float* b2     = (const float*)d_in[15];
  float* out = (float*)d_out;

  // ws layout (ushort units), ~233 MB
  ushort* wp   = (ushort*)d_ws;                         // 100352*128
  ushort* qkvb = wp + (size_t)100352 * 128;             // 100352*384
  ushort* obb  = qkvb + (size_t)100352 * 384;           // 100352*128
  ushort* hb   = obb + (size_t)100352 * 128;            // 100352*512
  ushort* qkvT = hb + (size_t)100352 * 512;             // 384*128
  ushort* w1T  = qkvT + 384 * 128;                      // 512*128
  ushort* w2T  = w1T + 512 * 128;                       // 128*512
  ushort* pT   = w2T + 128 * 512;                       // 128*128
  float*  TB   = (float*)(pT + 128 * 128);              // 4*4*64*64 f32
  ushort* yb   = qkvb;  // alias: qkvb dead after k_attn

  k_prep<<<768, 256, 0, stream>>>(qkv_w, w1, w2, proj_w, qkvT, w1T, w2T, pT);
  k_prep2<<<256, 256, 0, stream>>>(rpb, TB);
  k_ln1_part<<<12544, 256, 0, stream>>>(x, n1g, n1b, wp);
  k_gemm2<128, 384, 0><<<dim3(3, 784), 256, 0, stream>>>(wp, qkvT, qkv_b, qkvb);
  k_attn<<<2048, 256, 0, stream>>>(qkvb, TB, obb);
  k_pgemm<<<784, 256, 0, stream>>>(obb, pT, proj_b, plg, plb, yb);
  k_unshift<<<12544, 256, 0, stream>>>(x, yb, n2g, n2b, out, wp);
  k_gemm2<128, 512, 1><<<dim3(4, 784), 256, 0, stream>>>(wp, w1T, b1, hb);
  k_mlp2<<<784, 256, 0, stream>>>(hb, w2T, b2, out);
}

// Round 10
// 234.303 us; speedup vs baseline: 6.1564x; 1.0740x over previous
//
#include <hip/hip_runtime.h>
#include <cstdint>
#include <cstddef>

typedef __attribute__((ext_vector_type(8))) short bf16x8;
typedef __attribute__((ext_vector_type(4))) float f32x4;

namespace {
constexpr float kScale = 0.17677669529663689f; // 32^-0.5
constexpr float kEps = 1e-6f;
constexpr float kInvC = 1.0f / 128.0f;

// tanh-form GELU, rewritten as v*sigmoid(2u) (identical math, fewer VALU ops).
__device__ __forceinline__ float gelu_fast(float v) {
  float t1 = fmaf(0.044715f * v, v, 1.0f);     // 1 + 0.044715 v^2
  float x = v * t1 * -1.5957691216057308f;     // -2*0.7978845608*v*t1
  float e = __expf(x);
  return v * __builtin_amdgcn_rcpf(1.0f + e);
}
__device__ __forceinline__ ushort f2bf(float f) {
  uint32_t u = __builtin_bit_cast(uint32_t, f);
  u += 0x7FFFu + ((u >> 16) & 1u);
  return (ushort)(u >> 16);
}
__device__ __forceinline__ float bf2f(ushort u) {
  return __builtin_bit_cast(float, (uint32_t)u << 16);
}
// async global->LDS, 16B per lane. LDS dest is wave-uniform base + lane*16.
__device__ __forceinline__ void gl16(const ushort* g, ushort* l) {
  __builtin_amdgcn_global_load_lds(
      (const __attribute__((address_space(1))) void*)g,
      (__attribute__((address_space(3))) void*)l, 16, 0, 0);
}
} // namespace

// ---------------------------------------------------------------------------
// K0: convert+transpose weights to bf16 [N][K] layout.
// ---------------------------------------------------------------------------
__global__ __launch_bounds__(256) void k_prep(
    const float* __restrict__ qkv_w, const float* __restrict__ w1,
    const float* __restrict__ w2, const float* __restrict__ pw,
    ushort* __restrict__ qkvT, ushort* __restrict__ w1T,
    ushort* __restrict__ w2T, ushort* __restrict__ projT) {
  int i = blockIdx.x * 256 + threadIdx.x;
  if (i < 49152) {
    int n = i >> 7, k = i & 127;
    qkvT[i] = f2bf(qkv_w[k * 384 + n]);
  } else if (i < 114688) {
    int j = i - 49152;
    int n = j >> 7, k = j & 127;
    w1T[j] = f2bf(w1[k * 512 + n]);
  } else if (i < 180224) {
    int j = i - 114688;
    int n = j >> 9, k = j & 511;
    w2T[j] = f2bf(w2[k * 128 + n]);
  } else if (i < 196608) {
    int j = i - 180224;
    int n = j >> 7, k = j & 127;
    projT[j] = f2bf(pw[k * 128 + n]);
  }
}

// ---------------------------------------------------------------------------
// K0b: precompute bias+mask table TB[type(4)][head(4)][j(64)][i(64)] f32.
// ---------------------------------------------------------------------------
__global__ __launch_bounds__(256) void k_prep2(
    const float* __restrict__ rpb, float* __restrict__ TB) {
  int e = blockIdx.x * 256 + threadIdx.x;  // < 65536
  int i = e & 63, j = (e >> 6) & 63, h = (e >> 12) & 3, type = e >> 14;
  float v = 0.f;
  if (i < 49 && j < 49) {
    int ri = i / 7, ci = i - ri * 7, rj = j / 7, cj = j - rj * 7;
    int ridx = (ri - rj + 6) * 13 + (ci - cj + 6);
    float bias = rpb[ridx * 4 + h];
    int th = type >> 1, tw = type & 1;
    int labi = (th ? ((ri < 4) ? 1 : 2) : 0) * 3 + (tw ? ((ci < 4) ? 1 : 2) : 0);
    int labj = (th ? ((rj < 4) ? 1 : 2) : 0) * 3 + (tw ? ((cj < 4) ? 1 : 2) : 0);
    v = bias + ((labi != labj) ? -100.f : 0.f);
  }
  TB[e] = v;
}

// ---------------------------------------------------------------------------
// K1: LN(norm1) + cyclic shift(-3,-3) + window partition -> bf16
// ---------------------------------------------------------------------------
__global__ __launch_bounds__(256) void k_ln1_part(
    const float* __restrict__ x, const float* __restrict__ g,
    const float* __restrict__ b, ushort* __restrict__ wp) {
  int lane = threadIdx.x & 63, wv = threadIdx.x >> 6;
  int half = lane >> 5, l32 = lane & 31;
  int tok = blockIdx.x * 8 + wv * 2 + half;    // 0..100351
  int win = tok / 49, n = tok - win * 49;
  int bb = win >> 6, wi = win & 63;
  int whi = wi >> 3, wwi = wi & 7;
  int r = n / 7, c = n - r * 7;
  int hs = whi * 7 + r + 3; if (hs >= 56) hs -= 56;
  int ws = wwi * 7 + c + 3; if (ws >= 56) ws -= 56;
  size_t src = ((size_t)bb * 3136 + hs * 56 + ws) * 128;
  float4 v = *(const float4*)(x + src + l32 * 4);
  float s = v.x + v.y + v.z + v.w;
  float sq = v.x * v.x + v.y * v.y + v.z * v.z + v.w * v.w;
#pragma unroll
  for (int off = 1; off < 32; off <<= 1) {
    s += __shfl_xor(s, off);
    sq += __shfl_xor(sq, off);
  }
  float mu = s * kInvC;
  float var = sq * kInvC - mu * mu;
  float rs = rsqrtf(var + kEps);
  float4 gg = *(const float4*)(g + l32 * 4);
  float4 bv = *(const float4*)(b + l32 * 4);
  float o0 = (v.x - mu) * rs * gg.x + bv.x;
  float o1 = (v.y - mu) * rs * gg.y + bv.y;
  float o2 = (v.z - mu) * rs * gg.z + bv.z;
  float o3 = (v.w - mu) * rs * gg.w + bv.w;
  uint2 p;
  p.x = (uint)f2bf(o0) | ((uint)f2bf(o1) << 16);
  p.y = (uint)f2bf(o2) | ((uint)f2bf(o3) << 16);
  ((uint2*)wp)[(size_t)tok * 32 + l32] = p;
}

// ---------------------------------------------------------------------------
// K-UNSHIFT: reverse window partition + reverse shift + residual + LN2.
// ---------------------------------------------------------------------------
__global__ __launch_bounds__(256) void k_unshift(
    const float* __restrict__ x, const ushort* __restrict__ yb,
    const float* __restrict__ g, const float* __restrict__ b,
    float* __restrict__ out, ushort* __restrict__ wp) {
  int lane = threadIdx.x & 63, wv = threadIdx.x >> 6;
  int half = lane >> 5, l32 = lane & 31;
  int tok = blockIdx.x * 8 + wv * 2 + half;    // natural order
  int bb = tok / 3136, rem = tok - bb * 3136;
  int ph = rem / 56, pw = rem - ph * 56;
  int sh = ph + 53; if (sh >= 56) sh -= 56;    // (ph-3) mod 56
  int sw = pw + 53; if (sw >= 56) sw -= 56;
  int whi = sh / 7, r7 = sh - whi * 7;
  int wwi = sw / 7, c7 = sw - wwi * 7;
  int win = bb * 64 + whi * 8 + wwi, nn = r7 * 7 + c7;
  size_t row = (size_t)tok * 128;
  float4 xv = *(const float4*)(x + row + l32 * 4);
  uint2 yv = ((const uint2*)yb)[((size_t)win * 49 + nn) * 32 + l32];
  float o0 = xv.x + bf2f((ushort)(yv.x & 0xffff));
  float o1 = xv.y + bf2f((ushort)(yv.x >> 16));
  float o2 = xv.z + bf2f((ushort)(yv.y & 0xffff));
  float o3 = xv.w + bf2f((ushort)(yv.y >> 16));
  float4 ov; ov.x = o0; ov.y = o1; ov.z = o2; ov.w = o3;
  *(float4*)(out + row + l32 * 4) = ov;
  float s = o0 + o1 + o2 + o3;
  float sq = o0 * o0 + o1 * o1 + o2 * o2 + o3 * o3;
#pragma unroll
  for (int off = 1; off < 32; off <<= 1) {
    s += __shfl_xor(s, off);
    sq += __shfl_xor(sq, off);
  }
  float mu = s * kInvC;
  float var = sq * kInvC - mu * mu;
  float rs = rsqrtf(var + kEps);
  float4 gg = *(const float4*)(g + l32 * 4);
  float4 bv = *(const float4*)(b + l32 * 4);
  float m0 = (o0 - mu) * rs * gg.x + bv.x;
  float m1 = (o1 - mu) * rs * gg.y + bv.y;
  float m2 = (o2 - mu) * rs * gg.z + bv.z;
  float m3 = (o3 - mu) * rs * gg.w + bv.w;
  uint2 p;
  p.x = (uint)f2bf(m0) | ((uint)f2bf(m1) << 16);
  p.y = (uint)f2bf(m2) | ((uint)f2bf(m3) << 16);
  ((uint2*)wp)[(size_t)tok * 32 + l32] = p;
}

// ---------------------------------------------------------------------------
// K-GEMM2: C[M,LDC chunk] = A[M,K] @ BT[N,K]^T + bias. 128x128 tile, BK=64,
// gload_lds staging, XOR-swizzled (pre-swizzled global src + swizzled read):
// LDS[row][j] holds global[row][j ^ (row&7)] (j = 8-ushort chunk index).
// ---------------------------------------------------------------------------
template <int K, int LDC, int EPI>
__global__ __launch_bounds__(256) void k_gemm2(
    const ushort* __restrict__ A, const ushort* __restrict__ BT,
    const float* __restrict__ bias, ushort* __restrict__ C) {
  __shared__ ushort sbuf[128 * 128];  // 32 KB: As|Bs, overlaid by Cs
  ushort (*As)[64] = (ushort(*)[64])sbuf;
  ushort (*Bs)[64] = (ushort(*)[64])(sbuf + 128 * 64);
  int tid = threadIdx.x;
  int nBase = blockIdx.x << 7;
  int mBase = blockIdx.y << 7;
  int lane = tid & 63, wid = tid >> 6;
  int li = lane & 15, g = lane >> 4;
  int wr = (wid >> 1) << 6, wc = (wid & 1) << 6;
  int swz = (li & 7) << 3;            // read-side XOR (ushort units)
  f32x4 acc[4][4] = {};
  for (int ks = 0; ks < K; ks += 64) {
#pragma unroll
    for (int l = 0; l < 4; ++l) {
      int c = l * 256 + tid;
      int row = c >> 3;
      int k8 = ((c & 7) ^ (row & 7)) << 3;   // pre-swizzled source chunk
      int lo = (l * 256 + wid * 64) * 8;     // linear wave-uniform LDS dest
      gl16(A + (size_t)(mBase + row) * K + ks + k8, sbuf + lo);
      gl16(BT + (size_t)(nBase + row) * K + ks + k8, sbuf + 128 * 64 + lo);
    }
    __syncthreads();
#pragma unroll
    for (int ksub = 0; ksub < 64; ksub += 32) {
      int kloc = ksub + g * 8;
      bf16x8 af[4], bfr[4];
#pragma unroll
      for (int m = 0; m < 4; ++m)
        af[m] = *(const bf16x8*)&As[wr + m * 16 + li][kloc ^ swz];
#pragma unroll
      for (int n = 0; n < 4; ++n)
        bfr[n] = *(const bf16x8*)&Bs[wc + n * 16 + li][kloc ^ swz];
#pragma unroll
      for (int m = 0; m < 4; ++m)
#pragma unroll
        for (int n = 0; n < 4; ++n)
          acc[m][n] = __builtin_amdgcn_mfma_f32_16x16x32_bf16(
              af[m], bfr[n], acc[m][n], 0, 0, 0);
    }
    __syncthreads();
  }
  ushort (*Cs)[128] = (ushort(*)[128])sbuf;
#pragma unroll
  for (int n = 0; n < 4; ++n) {
    float bv = bias[nBase + wc + n * 16 + li];
#pragma unroll
    for (int m = 0; m < 4; ++m) {
      int rb = wr + m * 16 + (g << 2);
#pragma unroll
      for (int r = 0; r < 4; ++r) {
        float v = acc[m][n][r] + bv;
        if (EPI == 1) v = gelu_fast(v);
        Cs[rb + r][wc + n * 16 + li] = f2bf(v);
      }
    }
  }
  __syncthreads();
#pragma unroll
  for (int it = 0; it < 8; ++it) {
    int ch = tid + it * 256;
    int row = ch >> 4, c8 = (ch & 15) << 3;
    *(bf16x8*)(C + (size_t)(mBase + row) * LDC + nBase + c8) =
        *(const bf16x8*)&Cs[row][c8];
  }
}

// ---------------------------------------------------------------------------
// K-MLP2: out[M,128] += hb[M,512] @ w2T^T + b2. Swizzled gload_lds, K=512.
// ---------------------------------------------------------------------------
__global__ __launch_bounds__(256) void k_mlp2(
    const ushort* __restrict__ A, const ushort* __restrict__ BT,
    const float* __restrict__ bias, float* __restrict__ out) {
  __shared__ ushort sbuf[128 * 128];
  ushort (*As)[64] = (ushort(*)[64])sbuf;
  ushort (*Bs)[64] = (ushort(*)[64])(sbuf + 128 * 64);
  int tid = threadIdx.x;
  int mBase = blockIdx.x << 7;
  int lane = tid & 63, wid = tid >> 6;
  int li = lane & 15, g = lane >> 4;
  int wr = (wid >> 1) << 6, wc = (wid & 1) << 6;
  int swz = (li & 7) << 3;
  f32x4 acc[4][4] = {};
  for (int ks = 0; ks < 512; ks += 64) {
#pragma unroll
    for (int l = 0; l < 4; ++l) {
      int c = l * 256 + tid;
      int row = c >> 3;
      int k8 = ((c & 7) ^ (row & 7)) << 3;
      int lo = (l * 256 + wid * 64) * 8;
      gl16(A + (size_t)(mBase + row) * 512 + ks + k8, sbuf + lo);
      gl16(BT + (size_t)row * 512 + ks + k8, sbuf + 128 * 64 + lo);
    }
    __syncthreads();
#pragma unroll
    for (int ksub = 0; ksub < 64; ksub += 32) {
      int kloc = ksub + g * 8;
      bf16x8 af[4], bfr[4];
#pragma unroll
      for (int m = 0; m < 4; ++m)
        af[m] = *(const bf16x8*)&As[wr + m * 16 + li][kloc ^ swz];
#pragma unroll
      for (int n = 0; n < 4; ++n)
        bfr[n] = *(const bf16x8*)&Bs[wc + n * 16 + li][kloc ^ swz];
#pragma unroll
      for (int m = 0; m < 4; ++m)
#pragma unroll
        for (int n = 0; n < 4; ++n)
          acc[m][n] = __builtin_amdgcn_mfma_f32_16x16x32_bf16(
              af[m], bfr[n], acc[m][n], 0, 0, 0);
    }
    __syncthreads();
  }
#pragma unroll
  for (int n = 0; n < 4; ++n) {
    int cg = wc + n * 16 + li;
    float bv = bias[cg];
#pragma unroll
    for (int m = 0; m < 4; ++m) {
      int rbase = mBase + wr + m * 16 + (g << 2);
#pragma unroll
      for (int r = 0; r < 4; ++r) {
        size_t off = (size_t)(rbase + r) * 128 + cg;
        out[off] += acc[m][n][r] + bv;
      }
    }
  }
}

// ---------------------------------------------------------------------------
// K-PGEMM: proj GEMM + bias + row-LN(proj_ln) + GELU -> bf16 yb (contiguous).
// Swizzled gload_lds staging; LDS-staged wide stores.
// ---------------------------------------------------------------------------
__global__ __launch_bounds__(256) void k_pgemm(
    const ushort* __restrict__ A, const ushort* __restrict__ BT,
    const float* __restrict__ pb, const float* __restrict__ lg,
    const float* __restrict__ lb, ushort* __restrict__ yb) {
  __shared__ ushort sbuf[128 * 128];
  __shared__ float red[4][64][2];
  ushort (*As)[64] = (ushort(*)[64])sbuf;
  ushort (*Bs)[64] = (ushort(*)[64])(sbuf + 128 * 64);
  int tid = threadIdx.x;
  int mBase = blockIdx.x << 7;
  int lane = tid & 63, wid = tid >> 6;
  int li = lane & 15, g = lane >> 4;
  int wr = (wid >> 1) << 6, wc = (wid & 1) << 6;
  int swz = (li & 7) << 3;
  f32x4 acc[4][4] = {};
  for (int ks = 0; ks < 128; ks += 64) {
#pragma unroll
    for (int l = 0; l < 4; ++l) {
      int c = l * 256 + tid;
      int row = c >> 3;
      int k8 = ((c & 7) ^ (row & 7)) << 3;
      int lo = (l * 256 + wid * 64) * 8;
      gl16(A + (size_t)(mBase + row) * 128 + ks + k8, sbuf + lo);
      gl16(BT + (size_t)row * 128 + ks + k8, sbuf + 128 * 64 + lo);
    }
    __syncthreads();
#pragma unroll
    for (int ksub = 0; ksub < 64; ksub += 32) {
      int kloc = ksub + g * 8;
      bf16x8 af[4], bfr[4];
#pragma unroll
      for (int m = 0; m < 4; ++m)
        af[m] = *(const bf16x8*)&As[wr + m * 16 + li][kloc ^ swz];
#pragma unroll
      for (int n = 0; n < 4; ++n)
        bfr[n] = *(const bf16x8*)&Bs[wc + n * 16 + li][kloc ^ swz];
#pragma unroll
      for (int m = 0; m < 4; ++m)
#pragma unroll
        for (int n = 0; n < 4; ++n)
          acc[m][n] = __builtin_amdgcn_mfma_f32_16x16x32_bf16(
              af[m], bfr[n], acc[m][n], 0, 0, 0);
    }
    __syncthreads();
  }
  float pbv[4], lgv[4], lbv[4];
#pragma unroll
  for (int n = 0; n < 4; ++n) {
    int cg = wc + n * 16 + li;
    pbv[n] = pb[cg]; lgv[n] = lg[cg]; lbv[n] = lb[cg];
  }
  float ps[4][4], psq[4][4];
#pragma unroll
  for (int m = 0; m < 4; ++m)
#pragma unroll
    for (int r = 0; r < 4; ++r) {
      float s = 0.f, q = 0.f;
#pragma unroll
      for (int n = 0; n < 4; ++n) {
        float v = acc[m][n][r] + pbv[n];
        s += v; q += v * v;
      }
#pragma unroll
      for (int off = 1; off < 16; off <<= 1) {
        s += __shfl_xor(s, off);
        q += __shfl_xor(q, off);
      }
      ps[m][r] = s; psq[m][r] = q;
    }
  if (li == 0) {
#pragma unroll
    for (int m = 0; m < 4; ++m)
#pragma unroll
      for (int r = 0; r < 4; ++r) {
        int rl = m * 16 + (g << 2) + r;
        red[wid][rl][0] = ps[m][r];
        red[wid][rl][1] = psq[m][r];
      }
  }
  __syncthreads();
  ushort (*Cs)[128] = (ushort(*)[128])sbuf;
#pragma unroll
  for (int m = 0; m < 4; ++m) {
#pragma unroll
    for (int r = 0; r < 4; ++r) {
      int rl = m * 16 + (g << 2) + r;
      float s = ps[m][r] + red[wid ^ 1][rl][0];
      float q = psq[m][r] + red[wid ^ 1][rl][1];
      float mu = s * kInvC, var = q * kInvC - mu * mu;
      float rs = rsqrtf(var + kEps);
#pragma unroll
      for (int n = 0; n < 4; ++n) {
        float y = (acc[m][n][r] + pbv[n] - mu) * rs * lgv[n] + lbv[n];
        Cs[wr + rl][wc + n * 16 + li] = f2bf(gelu_fast(y));
      }
    }
  }
  __syncthreads();
#pragma unroll
  for (int it = 0; it < 8; ++it) {
    int ch = tid + it * 256;
    int row = ch >> 4, c8 = (ch & 15) << 3;
    *(bf16x8*)(yb + (size_t)(mBase + row) * 128 + c8) =
        *(const bf16x8*)&Cs[row][c8];
  }
}

// ---------------------------------------------------------------------------
// K3: MFMA attention. 1 block = 1 window, 1 wave = 1 head. LDS-staged O store.
// ---------------------------------------------------------------------------
__global__ __launch_bounds__(256) void k_attn(
    const ushort* __restrict__ qkv, const float* __restrict__ TB,
    ushort* __restrict__ ob) {
  __shared__ ushort Pl[4][64][72];
  __shared__ ushort Vt[4][32][72];
  int tid = threadIdx.x;
  int lane = tid & 63, h = tid >> 6;
  int li = lane & 15, g = lane >> 4;
  int win = blockIdx.x;
  int wi = win & 63;
  int type = (((wi >> 3) == 7) ? 2 : 0) | (((wi & 7) == 7) ? 1 : 0);

  const ushort* qbase = qkv + (size_t)win * 49 * 384 + h * 32 + g * 8;
  bf16x8 kf[4], qf[4];
#pragma unroll
  for (int m = 0; m < 4; ++m) {
    kf[m] = *(const bf16x8*)(qbase + (size_t)(m * 16 + li) * 384 + 128);
    qf[m] = *(const bf16x8*)(qbase + (size_t)(m * 16 + li) * 384);
  }
  f32x4 zero = {0.f, 0.f, 0.f, 0.f};
  f32x4 st[4][4];
#pragma unroll
  for (int m = 0; m < 4; ++m)
#pragma unroll
    for (int n = 0; n < 4; ++n)
      st[m][n] = __builtin_amdgcn_mfma_f32_16x16x32_bf16(kf[m], qf[n], zero, 0, 0, 0);

  if (lane < 49) {
#pragma unroll
    for (int dc = 0; dc < 4; ++dc) {
      bf16x8 vv = *(const bf16x8*)(qkv + ((size_t)win * 49 + lane) * 384 + 256 +
                                   h * 32 + dc * 8);
#pragma unroll
      for (int t = 0; t < 8; ++t) Vt[h][dc * 8 + t][lane] = (ushort)vv[t];
    }
  } else {
#pragma unroll
    for (int d = 0; d < 32; ++d) Vt[h][d][lane] = 0;
  }

  const float* tb = TB + ((size_t)(type * 4 + h) << 12);
#pragma unroll
  for (int n = 0; n < 4; ++n) {
    int icol = n * 16 + li;
    float sv[3][4];
#pragma unroll
    for (int m = 0; m < 3; ++m)
#pragma unroll
      for (int r = 0; r < 4; ++r)
        sv[m][r] = st[m][n][r] * kScale + tb[(m * 16 + g * 4 + r) * 64 + icol];
    float sv3 = (g == 0) ? (st[3][n][0] * kScale + tb[48 * 64 + icol]) : -1e30f;
    float mx = sv3;
#pragma unroll
    for (int m = 0; m < 3; ++m)
#pragma unroll
      for (int r = 0; r < 4; ++r) mx = fmaxf(mx, sv[m][r]);
    mx = fmaxf(mx, __shfl_xor(mx, 16));
    mx = fmaxf(mx, __shfl_xor(mx, 32));
    float e[3][4], e3 = __expf(sv3 - mx);
    float sum = e3;
#pragma unroll
    for (int m = 0; m < 3; ++m)
#pragma unroll
      for (int r = 0; r < 4; ++r) { e[m][r] = __expf(sv[m][r] - mx); sum += e[m][r]; }
    sum += __shfl_xor(sum, 16);
    sum += __shfl_xor(sum, 32);
    float inv = 1.f / sum;
    float p3 = e3 * inv;
    float v3 = (g == 0) ? p3 : -1e30f;
    float mx2 = v3;
#pragma unroll
    for (int m = 0; m < 3; ++m)
#pragma unroll
      for (int r = 0; r < 4; ++r) mx2 = fmaxf(mx2, e[m][r] * inv);
    mx2 = fmaxf(mx2, __shfl_xor(mx2, 16));
    mx2 = fmaxf(mx2, __shfl_xor(mx2, 32));
    float e2[3][4], e23 = __expf(v3 - mx2);
    float sum2 = e23;
#pragma unroll
    for (int m = 0; m < 3; ++m)
#pragma unroll
      for (int r = 0; r < 4; ++r) { e2[m][r] = __expf(e[m][r] * inv - mx2); sum2 += e2[m][r]; }
    sum2 += __shfl_xor(sum2, 16);
    sum2 += __shfl_xor(sum2, 32);
    float inv2 = 1.f / sum2;
#pragma unroll
    for (int m = 0; m < 3; ++m) {
      uint u0 = (uint)f2bf(e2[m][0] * inv2) | ((uint)f2bf(e2[m][1] * inv2) << 16);
      uint u1 = (uint)f2bf(e2[m][2] * inv2) | ((uint)f2bf(e2[m][3] * inv2) << 16);
      *(uint*)&Pl[h][icol][m * 16 + g * 4]     = u0;
      *(uint*)&Pl[h][icol][m * 16 + g * 4 + 2] = u1;
    }
    uint u3 = (uint)f2bf(e23 * inv2);
    *(uint*)&Pl[h][icol][48 + g * 4]     = u3;
    *(uint*)&Pl[h][icol][48 + g * 4 + 2] = 0u;
  }
  __syncthreads();

  f32x4 oacc[4][2] = {};
#pragma unroll
  for (int ks = 0; ks < 2; ++ks) {
    int kloc = ks * 32 + g * 8;
    bf16x8 bf0 = *(const bf16x8*)&Vt[h][li][kloc];
    bf16x8 bf1 = *(const bf16x8*)&Vt[h][16 + li][kloc];
#pragma unroll
    for (int mi = 0; mi < 4; ++mi) {
      bf16x8 af = *(const bf16x8*)&Pl[h][mi * 16 + li][kloc];
      oacc[mi][0] = __builtin_amdgcn_mfma_f32_16x16x32_bf16(af, bf0, oacc[mi][0], 0, 0, 0);
      oacc[mi][1] = __builtin_amdgcn_mfma_f32_16x16x32_bf16(af, bf1, oacc[mi][1], 0, 0, 0);
    }
  }
  // stage O (49 x 32 per head) into Pl[h] (stride 40), then wide stores
  ushort* OlH = &Pl[h][0][0];
#pragma unroll
  for (int mi = 0; mi < 4; ++mi)
#pragma unroll
    for (int r = 0; r < 4; ++r) {
      int i = mi * 16 + g * 4 + r;
      if (mi < 3 || (g == 0 && r == 0)) {
        OlH[i * 40 + li]      = f2bf(oacc[mi][0][r]);
        OlH[i * 40 + 16 + li] = f2bf(oacc[mi][1][r]);
      }
    }
  __syncthreads();
  ushort* obase = ob + (size_t)win * 49 * 128;
#pragma unroll
  for (int it = 0; it < 4; ++it) {
    int chunk = tid + it * 256;  // 784 chunks of 8 ushorts
    if (chunk < 784) {
      int row = chunk >> 4, c8 = (chunk & 15) << 3;
      int h2 = c8 >> 5, d8 = c8 & 31;
      bf16x8 v = *(const bf16x8*)(&Pl[h2][0][0] + row * 40 + d8);
      *(bf16x8*)(obase + (size_t)row * 128 + c8) = v;
    }
  }
}

extern "C" void kernel_launch(void* const* d_in, const int* in_sizes, int n_in,
                              void* d_out, int out_size, void* d_ws,
                              size_t ws_size, hipStream_t stream) {
  (void)in_sizes; (void)n_in; (void)out_size; (void)ws_size;
  const float* x      = (const float*)d_in[0];
  const float* qkv_w  = (const float*)d_in[1];
  const float* qkv_b  = (const float*)d_in[2];
  const float* proj_w = (const float*)d_in[3];
  const float* proj_b = (const float*)d_in[4];
  const float* plg    = (const float*)d_in[5];
  const float* plb    = (const float*)d_in[6];
  const float* rpb    = (const float*)d_in[7];
  const float* n1g    = (const float*)d_in[8];
  const float* n1b    = (const float*)d_in[9];
  const float* n2g    = (const float*)d_in[10];
  const float* n2b    = (const float*)d_in[11];
  const float* w1     = (const float*)d_in[12];
  const float* b1     = (const float*)d_in[13];
  const float* w2     = (const float*)d_in[14];
  const float* b2     = (const float*)d_in[15];
  float* out = (float*)d_out;

  // ws layout (ushort units), ~233 MB
  ushort* wp   = (ushort*)d_ws;                         // 100352*128
  ushort* qkvb = wp + (size_t)100352 * 128;             // 100352*384
  ushort* obb  = qkvb + (size_t)100352 * 384;           // 100352*128
  ushort* hb   = obb + (size_t)100352 * 128;            // 100352*512
  ushort* qkvT = hb + (size_t)100352 * 512;             // 384*128
  ushort* w1T  = qkvT + 384 * 128;                      // 512*128
  ushort* w2T  = w1T + 512 * 128;                       // 128*512
  ushort* pT   = w2T + 128 * 512;                       // 128*128
  float*  TB   = (float*)(pT + 128 * 128);              // 4*4*64*64 f32
  ushort* yb   = qkvb;  // alias: qkvb dead after k_attn

  k_prep<<<768, 256, 0, stream>>>(qkv_w, w1, w2, proj_w, qkvT, w1T, w2T, pT);
  k_prep2<<<256, 256, 0, stream>>>(rpb, TB);
  k_ln1_part<<<12544, 256, 0, stream>>>(x, n1g, n1b, wp);
  k_gemm2<128, 384, 0><<<dim3(3, 784), 256, 0, stream>>>(wp, qkvT, qkv_b, qkvb);
  k_attn<<<2048, 256, 0, stream>>>(qkvb, TB, obb);
  k_pgemm<<<784, 256, 0, stream>>>(obb, pT, proj_b, plg, plb, yb);
  k_unshift<<<12544, 256, 0, stream>>>(x, yb, n2g, n2b, out, wp);
  k_gemm2<128, 512, 1><<<dim3(4, 784), 256, 0, stream>>>(wp, w1T, b1, hb);
  k_mlp2<<<784, 256, 0, stream>>>(hb, w2T, b2, out);
}

// Round 11
// 231.964 us; speedup vs baseline: 6.2185x; 1.0101x over previous
//
#include <hip/hip_runtime.h>
#include <cstdint>
#include <cstddef>

typedef __attribute__((ext_vector_type(8))) short bf16x8;
typedef __attribute__((ext_vector_type(4))) float f32x4;

namespace {
constexpr float kScale = 0.17677669529663689f; // 32^-0.5
constexpr float kEps = 1e-6f;
constexpr float kInvC = 1.0f / 128.0f;

// tanh-form GELU as v*sigmoid(2u).
__device__ __forceinline__ float gelu_fast(float v) {
  float t1 = fmaf(0.044715f * v, v, 1.0f);
  float x = v * t1 * -1.5957691216057308f;
  float e = __expf(x);
  return v * __builtin_amdgcn_rcpf(1.0f + e);
}
__device__ __forceinline__ ushort f2bf(float f) {
  uint32_t u = __builtin_bit_cast(uint32_t, f);
  u += 0x7FFFu + ((u >> 16) & 1u);
  return (ushort)(u >> 16);
}
__device__ __forceinline__ float bf2f(ushort u) {
  return __builtin_bit_cast(float, (uint32_t)u << 16);
}
// async global->LDS, 16B per lane. LDS dest is wave-uniform base + lane*16.
__device__ __forceinline__ void gl16(const ushort* g, ushort* l) {
  __builtin_amdgcn_global_load_lds(
      (const __attribute__((address_space(1))) void*)g,
      (__attribute__((address_space(3))) void*)l, 16, 0, 0);
}
// stage one 128x64 A-tile + 128x64 B-tile (XOR-pre-swizzled source) into
// double-buffer slot `buf` of sbuf (each slot: As 8192 + Bs 8192 ushorts).
template <int K>
__device__ __forceinline__ void stage2(const ushort* a, const ushort* b,
                                       ushort* sbuf, int buf, int tid,
                                       int wid) {
#pragma unroll
  for (int l = 0; l < 4; ++l) {
    int c = l * 256 + tid;
    int row = c >> 3;
    int k8 = ((c & 7) ^ (row & 7)) << 3;   // pre-swizzled source chunk
    int lo = buf * 16384 + (l * 256 + wid * 64) * 8;  // wave-uniform dest
    gl16(a + (size_t)row * K + k8, sbuf + lo);
    gl16(b + (size_t)row * K + k8, sbuf + 8192 + lo);
  }
}
} // namespace

// ---------------------------------------------------------------------------
// K0: convert+transpose weights to bf16 [N][K] layout.
// ---------------------------------------------------------------------------
__global__ __launch_bounds__(256) void k_prep(
    const float* __restrict__ qkv_w, const float* __restrict__ w1,
    const float* __restrict__ w2, const float* __restrict__ pw,
    ushort* __restrict__ qkvT, ushort* __restrict__ w1T,
    ushort* __restrict__ w2T, ushort* __restrict__ projT) {
  int i = blockIdx.x * 256 + threadIdx.x;
  if (i < 49152) {
    int n = i >> 7, k = i & 127;
    qkvT[i] = f2bf(qkv_w[k * 384 + n]);
  } else if (i < 114688) {
    int j = i - 49152;
    int n = j >> 7, k = j & 127;
    w1T[j] = f2bf(w1[k * 512 + n]);
  } else if (i < 180224) {
    int j = i - 114688;
    int n = j >> 9, k = j & 511;
    w2T[j] = f2bf(w2[k * 128 + n]);
  } else if (i < 196608) {
    int j = i - 180224;
    int n = j >> 7, k = j & 127;
    projT[j] = f2bf(pw[k * 128 + n]);
  }
}

// ---------------------------------------------------------------------------
// K0b: precompute bias+mask table TB[type(4)][head(4)][j(64)][i(64)] f32.
// ---------------------------------------------------------------------------
__global__ __launch_bounds__(256) void k_prep2(
    const float* __restrict__ rpb, float* __restrict__ TB) {
  int e = blockIdx.x * 256 + threadIdx.x;  // < 65536
  int i = e & 63, j = (e >> 6) & 63, h = (e >> 12) & 3, type = e >> 14;
  float v = 0.f;
  if (i < 49 && j < 49) {
    int ri = i / 7, ci = i - ri * 7, rj = j / 7, cj = j - rj * 7;
    int ridx = (ri - rj + 6) * 13 + (ci - cj + 6);
    float bias = rpb[ridx * 4 + h];
    int th = type >> 1, tw = type & 1;
    int labi = (th ? ((ri < 4) ? 1 : 2) : 0) * 3 + (tw ? ((ci < 4) ? 1 : 2) : 0);
    int labj = (th ? ((rj < 4) ? 1 : 2) : 0) * 3 + (tw ? ((cj < 4) ? 1 : 2) : 0);
    v = bias + ((labi != labj) ? -100.f : 0.f);
  }
  TB[e] = v;
}

// ---------------------------------------------------------------------------
// K1: LN(norm1) + cyclic shift(-3,-3) + window partition -> bf16
// ---------------------------------------------------------------------------
__global__ __launch_bounds__(256) void k_ln1_part(
    const float* __restrict__ x, const float* __restrict__ g,
    const float* __restrict__ b, ushort* __restrict__ wp) {
  int lane = threadIdx.x & 63, wv = threadIdx.x >> 6;
  int half = lane >> 5, l32 = lane & 31;
  int tok = blockIdx.x * 8 + wv * 2 + half;    // 0..100351
  int win = tok / 49, n = tok - win * 49;
  int bb = win >> 6, wi = win & 63;
  int whi = wi >> 3, wwi = wi & 7;
  int r = n / 7, c = n - r * 7;
  int hs = whi * 7 + r + 3; if (hs >= 56) hs -= 56;
  int ws = wwi * 7 + c + 3; if (ws >= 56) ws -= 56;
  size_t src = ((size_t)bb * 3136 + hs * 56 + ws) * 128;
  float4 v = *(const float4*)(x + src + l32 * 4);
  float s = v.x + v.y + v.z + v.w;
  float sq = v.x * v.x + v.y * v.y + v.z * v.z + v.w * v.w;
#pragma unroll
  for (int off = 1; off < 32; off <<= 1) {
    s += __shfl_xor(s, off);
    sq += __shfl_xor(sq, off);
  }
  float mu = s * kInvC;
  float var = sq * kInvC - mu * mu;
  float rs = rsqrtf(var + kEps);
  float4 gg = *(const float4*)(g + l32 * 4);
  float4 bv = *(const float4*)(b + l32 * 4);
  float o0 = (v.x - mu) * rs * gg.x + bv.x;
  float o1 = (v.y - mu) * rs * gg.y + bv.y;
  float o2 = (v.z - mu) * rs * gg.z + bv.z;
  float o3 = (v.w - mu) * rs * gg.w + bv.w;
  uint2 p;
  p.x = (uint)f2bf(o0) | ((uint)f2bf(o1) << 16);
  p.y = (uint)f2bf(o2) | ((uint)f2bf(o3) << 16);
  ((uint2*)wp)[(size_t)tok * 32 + l32] = p;
}

// ---------------------------------------------------------------------------
// K-UNSHIFT: reverse window partition + reverse shift + residual + LN2.
// ---------------------------------------------------------------------------
__global__ __launch_bounds__(256) void k_unshift(
    const float* __restrict__ x, const ushort* __restrict__ yb,
    const float* __restrict__ g, const float* __restrict__ b,
    float* __restrict__ out, ushort* __restrict__ wp) {
  int lane = threadIdx.x & 63, wv = threadIdx.x >> 6;
  int half = lane >> 5, l32 = lane & 31;
  int tok = blockIdx.x * 8 + wv * 2 + half;    // natural order
  int bb = tok / 3136, rem = tok - bb * 3136;
  int ph = rem / 56, pw = rem - ph * 56;
  int sh = ph + 53; if (sh >= 56) sh -= 56;    // (ph-3) mod 56
  int sw = pw + 53; if (sw >= 56) sw -= 56;
  int whi = sh / 7, r7 = sh - whi * 7;
  int wwi = sw / 7, c7 = sw - wwi * 7;
  int win = bb * 64 + whi * 8 + wwi, nn = r7 * 7 + c7;
  size_t row = (size_t)tok * 128;
  float4 xv = *(const float4*)(x + row + l32 * 4);
  uint2 yv = ((const uint2*)yb)[((size_t)win * 49 + nn) * 32 + l32];
  float o0 = xv.x + bf2f((ushort)(yv.x & 0xffff));
  float o1 = xv.y + bf2f((ushort)(yv.x >> 16));
  float o2 = xv.z + bf2f((ushort)(yv.y & 0xffff));
  float o3 = xv.w + bf2f((ushort)(yv.y >> 16));
  float4 ov; ov.x = o0; ov.y = o1; ov.z = o2; ov.w = o3;
  *(float4*)(out + row + l32 * 4) = ov;
  float s = o0 + o1 + o2 + o3;
  float sq = o0 * o0 + o1 * o1 + o2 * o2 + o3 * o3;
#pragma unroll
  for (int off = 1; off < 32; off <<= 1) {
    s += __shfl_xor(s, off);
    sq += __shfl_xor(sq, off);
  }
  float mu = s * kInvC;
  float var = sq * kInvC - mu * mu;
  float rs = rsqrtf(var + kEps);
  float4 gg = *(const float4*)(g + l32 * 4);
  float4 bv = *(const float4*)(b + l32 * 4);
  float m0 = (o0 - mu) * rs * gg.x + bv.x;
  float m1 = (o1 - mu) * rs * gg.y + bv.y;
  float m2 = (o2 - mu) * rs * gg.z + bv.z;
  float m3 = (o3 - mu) * rs * gg.w + bv.w;
  uint2 p;
  p.x = (uint)f2bf(m0) | ((uint)f2bf(m1) << 16);
  p.y = (uint)f2bf(m2) | ((uint)f2bf(m3) << 16);
  ((uint2*)wp)[(size_t)tok * 32 + l32] = p;
}

// ---------------------------------------------------------------------------
// K-GEMM2: C[M,LDC chunk] = A[M,K] @ BT[N,K]^T + bias. 128x128 tile, BK=64,
// DOUBLE-BUFFERED gload_lds pipeline: stage(t+1) issued before compute(t);
// the __syncthreads vmcnt(0) drain completes the prefetch.
// ---------------------------------------------------------------------------
template <int K, int LDC, int EPI>
__global__ __launch_bounds__(256) void k_gemm2(
    const ushort* __restrict__ A, const ushort* __restrict__ BT,
    const float* __restrict__ bias, ushort* __restrict__ C) {
  __shared__ ushort sbuf[2 * 16384];  // 64 KB double buffer
  int tid = threadIdx.x;
  int nBase = blockIdx.x << 7;
  int mBase = blockIdx.y << 7;
  int lane = tid & 63, wid = tid >> 6;
  int li = lane & 15, g = lane >> 4;
  int wr = (wid >> 1) << 6, wc = (wid & 1) << 6;
  int swz = (li & 7) << 3;
  const ushort* Ab = A + (size_t)mBase * K;
  const ushort* Bb = BT + (size_t)nBase * K;
  f32x4 acc[4][4] = {};
  stage2<K>(Ab, Bb, sbuf, 0, tid, wid);
  __syncthreads();
  int cur = 0;
#pragma unroll
  for (int ks = 0; ks < K; ks += 64) {
    if (ks + 64 < K)
      stage2<K>(Ab + ks + 64, Bb + ks + 64, sbuf, cur ^ 1, tid, wid);
    const ushort(*As)[64] = (const ushort(*)[64])(sbuf + cur * 16384);
    const ushort(*Bs)[64] = (const ushort(*)[64])(sbuf + cur * 16384 + 8192);
#pragma unroll
    for (int ksub = 0; ksub < 64; ksub += 32) {
      int kloc = ksub + g * 8;
      bf16x8 af[4], bfr[4];
#pragma unroll
      for (int m = 0; m < 4; ++m)
        af[m] = *(const bf16x8*)&As[wr + m * 16 + li][kloc ^ swz];
#pragma unroll
      for (int n = 0; n < 4; ++n)
        bfr[n] = *(const bf16x8*)&Bs[wc + n * 16 + li][kloc ^ swz];
#pragma unroll
      for (int m = 0; m < 4; ++m)
#pragma unroll
        for (int n = 0; n < 4; ++n)
          acc[m][n] = __builtin_amdgcn_mfma_f32_16x16x32_bf16(
              af[m], bfr[n], acc[m][n], 0, 0, 0);
    }
    __syncthreads();  // prefetch landed; buffer-swap safe
    cur ^= 1;
  }
  ushort (*Cs)[128] = (ushort(*)[128])sbuf;  // overlays buffer 0
#pragma unroll
  for (int n = 0; n < 4; ++n) {
    float bv = bias[nBase + wc + n * 16 + li];
#pragma unroll
    for (int m = 0; m < 4; ++m) {
      int rb = wr + m * 16 + (g << 2);
#pragma unroll
      for (int r = 0; r < 4; ++r) {
        float v = acc[m][n][r] + bv;
        if (EPI == 1) v = gelu_fast(v);
        Cs[rb + r][wc + n * 16 + li] = f2bf(v);
      }
    }
  }
  __syncthreads();
#pragma unroll
  for (int it = 0; it < 8; ++it) {
    int ch = tid + it * 256;
    int row = ch >> 4, c8 = (ch & 15) << 3;
    *(bf16x8*)(C + (size_t)(mBase + row) * LDC + nBase + c8) =
        *(const bf16x8*)&Cs[row][c8];
  }
}

// ---------------------------------------------------------------------------
// K-MLP2: out[M,128] += hb[M,512] @ w2T^T + b2. Double-buffered pipeline,
// 8 K-steps -> the main beneficiary of prefetch.
// ---------------------------------------------------------------------------
__global__ __launch_bounds__(256) void k_mlp2(
    const ushort* __restrict__ A, const ushort* __restrict__ BT,
    const float* __restrict__ bias, float* __restrict__ out) {
  __shared__ ushort sbuf[2 * 16384];
  int tid = threadIdx.x;
  int mBase = blockIdx.x << 7;
  int lane = tid & 63, wid = tid >> 6;
  int li = lane & 15, g = lane >> 4;
  int wr = (wid >> 1) << 6, wc = (wid & 1) << 6;
  int swz = (li & 7) << 3;
  const ushort* Ab = A + (size_t)mBase * 512;
  f32x4 acc[4][4] = {};
  stage2<512>(Ab, BT, sbuf, 0, tid, wid);
  __syncthreads();
  int cur = 0;
#pragma unroll
  for (int ks = 0; ks < 512; ks += 64) {
    if (ks + 64 < 512)
      stage2<512>(Ab + ks + 64, BT + ks + 64, sbuf, cur ^ 1, tid, wid);
    const ushort(*As)[64] = (const ushort(*)[64])(sbuf + cur * 16384);
    const ushort(*Bs)[64] = (const ushort(*)[64])(sbuf + cur * 16384 + 8192);
#pragma unroll
    for (int ksub = 0; ksub < 64; ksub += 32) {
      int kloc = ksub + g * 8;
      bf16x8 af[4], bfr[4];
#pragma unroll
      for (int m = 0; m < 4; ++m)
        af[m] = *(const bf16x8*)&As[wr + m * 16 + li][kloc ^ swz];
#pragma unroll
      for (int n = 0; n < 4; ++n)
        bfr[n] = *(const bf16x8*)&Bs[wc + n * 16 + li][kloc ^ swz];
#pragma unroll
      for (int m = 0; m < 4; ++m)
#pragma unroll
        for (int n = 0; n < 4; ++n)
          acc[m][n] = __builtin_amdgcn_mfma_f32_16x16x32_bf16(
              af[m], bfr[n], acc[m][n], 0, 0, 0);
    }
    __syncthreads();
    cur ^= 1;
  }
#pragma unroll
  for (int n = 0; n < 4; ++n) {
    int cg = wc + n * 16 + li;
    float bv = bias[cg];
#pragma unroll
    for (int m = 0; m < 4; ++m) {
      int rbase = mBase + wr + m * 16 + (g << 2);
#pragma unroll
      for (int r = 0; r < 4; ++r) {
        size_t off = (size_t)(rbase + r) * 128 + cg;
        out[off] += acc[m][n][r] + bv;
      }
    }
  }
}

// ---------------------------------------------------------------------------
// K-PGEMM: proj GEMM + bias + row-LN(proj_ln) + GELU -> bf16 yb (contiguous).
// Double-buffered gload_lds pipeline; LDS-staged wide stores.
// ---------------------------------------------------------------------------
__global__ __launch_bounds__(256) void k_pgemm(
    const ushort* __restrict__ A, const ushort* __restrict__ BT,
    const float* __restrict__ pb, const float* __restrict__ lg,
    const float* __restrict__ lb, ushort* __restrict__ yb) {
  __shared__ ushort sbuf[2 * 16384];
  __shared__ float red[4][64][2];
  int tid = threadIdx.x;
  int mBase = blockIdx.x << 7;
  int lane = tid & 63, wid = tid >> 6;
  int li = lane & 15, g = lane >> 4;
  int wr = (wid >> 1) << 6, wc = (wid & 1) << 6;
  int swz = (li & 7) << 3;
  const ushort* Ab = A + (size_t)mBase * 128;
  f32x4 acc[4][4] = {};
  stage2<128>(Ab, BT, sbuf, 0, tid, wid);
  __syncthreads();
  int cur = 0;
#pragma unroll
  for (int ks = 0; ks < 128; ks += 64) {
    if (ks + 64 < 128)
      stage2<128>(Ab + ks + 64, BT + ks + 64, sbuf, cur ^ 1, tid, wid);
    const ushort(*As)[64] = (const ushort(*)[64])(sbuf + cur * 16384);
    const ushort(*Bs)[64] = (const ushort(*)[64])(sbuf + cur * 16384 + 8192);
#pragma unroll
    for (int ksub = 0; ksub < 64; ksub += 32) {
      int kloc = ksub + g * 8;
      bf16x8 af[4], bfr[4];
#pragma unroll
      for (int m = 0; m < 4; ++m)
        af[m] = *(const bf16x8*)&As[wr + m * 16 + li][kloc ^ swz];
#pragma unroll
      for (int n = 0; n < 4; ++n)
        bfr[n] = *(const bf16x8*)&Bs[wc + n * 16 + li][kloc ^ swz];
#pragma unroll
      for (int m = 0; m < 4; ++m)
#pragma unroll
        for (int n = 0; n < 4; ++n)
          acc[m][n] = __builtin_amdgcn_mfma_f32_16x16x32_bf16(
              af[m], bfr[n], acc[m][n], 0, 0, 0);
    }
    __syncthreads();
    cur ^= 1;
  }
  float pbv[4], lgv[4], lbv[4];
#pragma unroll
  for (int n = 0; n < 4; ++n) {
    int cg = wc + n * 16 + li;
    pbv[n] = pb[cg]; lgv[n] = lg[cg]; lbv[n] = lb[cg];
  }
  float ps[4][4], psq[4][4];
#pragma unroll
  for (int m = 0; m < 4; ++m)
#pragma unroll
    for (int r = 0; r < 4; ++r) {
      float s = 0.f, q = 0.f;
#pragma unroll
      for (int n = 0; n < 4; ++n) {
        float v = acc[m][n][r] + pbv[n];
        s += v; q += v * v;
      }
#pragma unroll
      for (int off = 1; off < 16; off <<= 1) {
        s += __shfl_xor(s, off);
        q += __shfl_xor(q, off);
      }
      ps[m][r] = s; psq[m][r] = q;
    }
  if (li == 0) {
#pragma unroll
    for (int m = 0; m < 4; ++m)
#pragma unroll
      for (int r = 0; r < 4; ++r) {
        int rl = m * 16 + (g << 2) + r;
        red[wid][rl][0] = ps[m][r];
        red[wid][rl][1] = psq[m][r];
      }
  }
  __syncthreads();
  ushort (*Cs)[128] = (ushort(*)[128])sbuf;
#pragma unroll
  for (int m = 0; m < 4; ++m) {
#pragma unroll
    for (int r = 0; r < 4; ++r) {
      int rl = m * 16 + (g << 2) + r;
      float s = ps[m][r] + red[wid ^ 1][rl][0];
      float q = psq[m][r] + red[wid ^ 1][rl][1];
      float mu = s * kInvC, var = q * kInvC - mu * mu;
      float rs = rsqrtf(var + kEps);
#pragma unroll
      for (int n = 0; n < 4; ++n) {
        float y = (acc[m][n][r] + pbv[n] - mu) * rs * lgv[n] + lbv[n];
        Cs[wr + rl][wc + n * 16 + li] = f2bf(gelu_fast(y));
      }
    }
  }
  __syncthreads();
#pragma unroll
  for (int it = 0; it < 8; ++it) {
    int ch = tid + it * 256;
    int row = ch >> 4, c8 = (ch & 15) << 3;
    *(bf16x8*)(yb + (size_t)(mBase + row) * 128 + c8) =
        *(const bf16x8*)&Cs[row][c8];
  }
}

// ---------------------------------------------------------------------------
// K3: MFMA attention. 1 block = 1 window, 1 wave = 1 head. LDS-staged O store.
// ---------------------------------------------------------------------------
__global__ __launch_bounds__(256) void k_attn(
    const ushort* __restrict__ qkv, const float* __restrict__ TB,
    ushort* __restrict__ ob) {
  __shared__ ushort Pl[4][64][72];
  __shared__ ushort Vt[4][32][72];
  int tid = threadIdx.x;
  int lane = tid & 63, h = tid >> 6;
  int li = lane & 15, g = lane >> 4;
  int win = blockIdx.x;
  int wi = win & 63;
  int type = (((wi >> 3) == 7) ? 2 : 0) | (((wi & 7) == 7) ? 1 : 0);

  const ushort* qbase = qkv + (size_t)win * 49 * 384 + h * 32 + g * 8;
  bf16x8 kf[4], qf[4];
#pragma unroll
  for (int m = 0; m < 4; ++m) {
    kf[m] = *(const bf16x8*)(qbase + (size_t)(m * 16 + li) * 384 + 128);
    qf[m] = *(const bf16x8*)(qbase + (size_t)(m * 16 + li) * 384);
  }
  f32x4 zero = {0.f, 0.f, 0.f, 0.f};
  f32x4 st[4][4];
#pragma unroll
  for (int m = 0; m < 4; ++m)
#pragma unroll
    for (int n = 0; n < 4; ++n)
      st[m][n] = __builtin_amdgcn_mfma_f32_16x16x32_bf16(kf[m], qf[n], zero, 0, 0, 0);

  if (lane < 49) {
#pragma unroll
    for (int dc = 0; dc < 4; ++dc) {
      bf16x8 vv = *(const bf16x8*)(qkv + ((size_t)win * 49 + lane) * 384 + 256 +
                                   h * 32 + dc * 8);
#pragma unroll
      for (int t = 0; t < 8; ++t) Vt[h][dc * 8 + t][lane] = (ushort)vv[t];
    }
  } else {
#pragma unroll
    for (int d = 0; d < 32; ++d) Vt[h][d][lane] = 0;
  }

  const float* tb = TB + ((size_t)(type * 4 + h) << 12);
#pragma unroll
  for (int n = 0; n < 4; ++n) {
    int icol = n * 16 + li;
    float sv[3][4];
#pragma unroll
    for (int m = 0; m < 3; ++m)
#pragma unroll
      for (int r = 0; r < 4; ++r)
        sv[m][r] = st[m][n][r] * kScale + tb[(m * 16 + g * 4 + r) * 64 + icol];
    float sv3 = (g == 0) ? (st[3][n][0] * kScale + tb[48 * 64 + icol]) : -1e30f;
    float mx = sv3;
#pragma unroll
    for (int m = 0; m < 3; ++m)
#pragma unroll
      for (int r = 0; r < 4; ++r) mx = fmaxf(mx, sv[m][r]);
    mx = fmaxf(mx, __shfl_xor(mx, 16));
    mx = fmaxf(mx, __shfl_xor(mx, 32));
    float e[3][4], e3 = __expf(sv3 - mx);
    float sum = e3;
#pragma unroll
    for (int m = 0; m < 3; ++m)
#pragma unroll
      for (int r = 0; r < 4; ++r) { e[m][r] = __expf(sv[m][r] - mx); sum += e[m][r]; }
    sum += __shfl_xor(sum, 16);
    sum += __shfl_xor(sum, 32);
    float inv = 1.f / sum;
    float p3 = e3 * inv;
    float v3 = (g == 0) ? p3 : -1e30f;
    float mx2 = v3;
#pragma unroll
    for (int m = 0; m < 3; ++m)
#pragma unroll
      for (int r = 0; r < 4; ++r) mx2 = fmaxf(mx2, e[m][r] * inv);
    mx2 = fmaxf(mx2, __shfl_xor(mx2, 16));
    mx2 = fmaxf(mx2, __shfl_xor(mx2, 32));
    float e2[3][4], e23 = __expf(v3 - mx2);
    float sum2 = e23;
#pragma unroll
    for (int m = 0; m < 3; ++m)
#pragma unroll
      for (int r = 0; r < 4; ++r) { e2[m][r] = __expf(e[m][r] * inv - mx2); sum2 += e2[m][r]; }
    sum2 += __shfl_xor(sum2, 16);
    sum2 += __shfl_xor(sum2, 32);
    float inv2 = 1.f / sum2;
#pragma unroll
    for (int m = 0; m < 3; ++m) {
      uint u0 = (uint)f2bf(e2[m][0] * inv2) | ((uint)f2bf(e2[m][1] * inv2) << 16);
      uint u1 = (uint)f2bf(e2[m][2] * inv2) | ((uint)f2bf(e2[m][3] * inv2) << 16);
      *(uint*)&Pl[h][icol][m * 16 + g * 4]     = u0;
      *(uint*)&Pl[h][icol][m * 16 + g * 4 + 2] = u1;
    }
    uint u3 = (uint)f2bf(e23 * inv2);
    *(uint*)&Pl[h][icol][48 + g * 4]     = u3;
    *(uint*)&Pl[h][icol][48 + g * 4 + 2] = 0u;
  }
  __syncthreads();

  f32x4 oacc[4][2] = {};
#pragma unroll
  for (int ks = 0; ks < 2; ++ks) {
    int kloc = ks * 32 + g * 8;
    bf16x8 bf0 = *(const bf16x8*)&Vt[h][li][kloc];
    bf16x8 bf1 = *(const bf16x8*)&Vt[h][16 + li][kloc];
#pragma unroll
    for (int mi = 0; mi < 4; ++mi) {
      bf16x8 af = *(const bf16x8*)&Pl[h][mi * 16 + li][kloc];
      oacc[mi][0] = __builtin_amdgcn_mfma_f32_16x16x32_bf16(af, bf0, oacc[mi][0], 0, 0, 0);
      oacc[mi][1] = __builtin_amdgcn_mfma_f32_16x16x32_bf16(af, bf1, oacc[mi][1], 0, 0, 0);
    }
  }
  // stage O (49 x 32 per head) into Pl[h] (stride 40), then wide stores
  ushort* OlH = &Pl[h][0][0];
#pragma unroll
  for (int mi = 0; mi < 4; ++mi)
#pragma unroll
    for (int r = 0; r < 4; ++r) {
      int i = mi * 16 + g * 4 + r;
      if (mi < 3 || (g == 0 && r == 0)) {
        OlH[i * 40 + li]      = f2bf(oacc[mi][0][r]);
        OlH[i * 40 + 16 + li] = f2bf(oacc[mi][1][r]);
      }
    }
  __syncthreads();
  ushort* obase = ob + (size_t)win * 49 * 128;
#pragma unroll
  for (int it = 0; it < 4; ++it) {
    int chunk = tid + it * 256;  // 784 chunks of 8 ushorts
    if (chunk < 784) {
      int row = chunk >> 4, c8 = (chunk & 15) << 3;
      int h2 = c8 >> 5, d8 = c8 & 31;
      bf16x8 v = *(const bf16x8*)(&Pl[h2][0][0] + row * 40 + d8);
      *(bf16x8*)(obase + (size_t)row * 128 + c8) = v;
    }
  }
}

extern "C" void kernel_launch(void* const* d_in, const int* in_sizes, int n_in,
                              void* d_out, int out_size, void* d_ws,
                              size_t ws_size, hipStream_t stream) {
  (void)in_sizes; (void)n_in; (void)out_size; (void)ws_size;
  const float* x      = (const float*)d_in[0];
  const float* qkv_w  = (const float*)d_in[1];
  const float* qkv_b  = (const float*)d_in[2];
  const float* proj_w = (const float*)d_in[3];
  const float* proj_b = (const float*)d_in[4];
  const float* plg    = (const float*)d_in[5];
  const float* plb    = (const float*)d_in[6];
  const float* rpb    = (const float*)d_in[7];
  const float* n1g    = (const float*)d_in[8];
  const float* n1b    = (const float*)d_in[9];
  const float* n2g    = (const float*)d_in[10];
  const float* n2b    = (const float*)d_in[11];
  const float* w1     = (const float*)d_in[12];
  const float* b1     = (const float*)d_in[13];
  const float* w2     = (const float*)d_in[14];
  const float* b2     = (const float*)d_in[15];
  float* out = (float*)d_out;

  // ws layout (ushort units), ~233 MB
  ushort* wp   = (ushort*)d_ws;                         // 100352*128
  ushort* qkvb = wp + (size_t)100352 * 128;             // 100352*384
  ushort* obb  = qkvb + (size_t)100352 * 384;           // 100352*128
  ushort* hb   = obb + (size_t)100352 * 128;            // 100352*512
  ushort* qkvT = hb + (size_t)100352 * 512;             // 384*128
  ushort* w1T  = qkvT + 384 * 128;                      // 512*128
  ushort* w2T  = w1T + 512 * 128;                       // 128*512
  ushort* pT   = w2T + 128 * 512;                       // 128*128
  float*  TB   = (float*)(pT + 128 * 128);              // 4*4*64*64 f32
  ushort* yb   = qkvb;  // alias: qkvb dead after k_attn

  k_prep<<<768, 256, 0, stream>>>(qkv_w, w1, w2, proj_w, qkvT, w1T, w2T, pT);
  k_prep2<<<256, 256, 0, stream>>>(rpb, TB);
  k_ln1_part<<<12544, 256, 0, stream>>>(x, n1g, n1b, wp);
  k_gemm2<128, 384, 0><<<dim3(3, 784), 256, 0, stream>>>(wp, qkvT, qkv_b, qkvb);
  k_attn<<<2048, 256, 0, stream>>>(qkvb, TB, obb);
  k_pgemm<<<784, 256, 0, stream>>>(obb, pT, proj_b, plg, plb, yb);
  k_unshift<<<12544, 256, 0, stream>>>(x, yb, n2g, n2b, out, wp);
  k_gemm2<128, 512, 1><<<dim3(4, 784), 256, 0, stream>>>(wp, w1T, b1, hb);
  k_mlp2<<<784, 256, 0, stream>>>(hb, w2T, b2, out);
}

// Round 12
// 230.704 us; speedup vs baseline: 6.2524x; 1.0055x over previous
//
#include <hip/hip_runtime.h>
#include <cstdint>
#include <cstddef>

typedef __attribute__((ext_vector_type(8))) short bf16x8;
typedef __attribute__((ext_vector_type(4))) float f32x4;

namespace {
constexpr float kScale = 0.17677669529663689f; // 32^-0.5
constexpr float kEps = 1e-6f;
constexpr float kInvC = 1.0f / 128.0f;

// tanh-form GELU as v*sigmoid(2u).
__device__ __forceinline__ float gelu_fast(float v) {
  float t1 = fmaf(0.044715f * v, v, 1.0f);
  float x = v * t1 * -1.5957691216057308f;
  float e = __expf(x);
  return v * __builtin_amdgcn_rcpf(1.0f + e);
}
__device__ __forceinline__ ushort f2bf(float f) {
  uint32_t u = __builtin_bit_cast(uint32_t, f);
  u += 0x7FFFu + ((u >> 16) & 1u);
  return (ushort)(u >> 16);
}
__device__ __forceinline__ float bf2f(ushort u) {
  return __builtin_bit_cast(float, (uint32_t)u << 16);
}
// async global->LDS, 16B per lane. LDS dest is wave-uniform base + lane*16.
__device__ __forceinline__ void gl16(const ushort* g, ushort* l) {
  __builtin_amdgcn_global_load_lds(
      (const __attribute__((address_space(1))) void*)g,
      (__attribute__((address_space(3))) void*)l, 16, 0, 0);
}
// stage one 128x64 A-tile + 128x64 B-tile (XOR-pre-swizzled source) into
// double-buffer slot `buf` of sbuf (each slot: As 8192 + Bs 8192 ushorts).
template <int K>
__device__ __forceinline__ void stage2(const ushort* a, const ushort* b,
                                       ushort* sbuf, int buf, int tid,
                                       int wid) {
#pragma unroll
  for (int l = 0; l < 4; ++l) {
    int c = l * 256 + tid;
    int row = c >> 3;
    int k8 = ((c & 7) ^ (row & 7)) << 3;   // pre-swizzled source chunk
    int lo = buf * 16384 + (l * 256 + wid * 64) * 8;  // wave-uniform dest
    gl16(a + (size_t)row * K + k8, sbuf + lo);
    gl16(b + (size_t)row * K + k8, sbuf + 8192 + lo);
  }
}
} // namespace

// ---------------------------------------------------------------------------
// K0: convert+transpose weights to bf16 [N][K] layout.
// ---------------------------------------------------------------------------
__global__ __launch_bounds__(256) void k_prep(
    const float* __restrict__ qkv_w, const float* __restrict__ w1,
    const float* __restrict__ w2, const float* __restrict__ pw,
    ushort* __restrict__ qkvT, ushort* __restrict__ w1T,
    ushort* __restrict__ w2T, ushort* __restrict__ projT) {
  int i = blockIdx.x * 256 + threadIdx.x;
  if (i < 49152) {
    int n = i >> 7, k = i & 127;
    qkvT[i] = f2bf(qkv_w[k * 384 + n]);
  } else if (i < 114688) {
    int j = i - 49152;
    int n = j >> 7, k = j & 127;
    w1T[j] = f2bf(w1[k * 512 + n]);
  } else if (i < 180224) {
    int j = i - 114688;
    int n = j >> 9, k = j & 511;
    w2T[j] = f2bf(w2[k * 128 + n]);
  } else if (i < 196608) {
    int j = i - 180224;
    int n = j >> 7, k = j & 127;
    projT[j] = f2bf(pw[k * 128 + n]);
  }
}

// ---------------------------------------------------------------------------
// K0b: precompute bias+mask table TB[type(4)][head(4)][j(64)][i(64)] f32.
// ---------------------------------------------------------------------------
__global__ __launch_bounds__(256) void k_prep2(
    const float* __restrict__ rpb, float* __restrict__ TB) {
  int e = blockIdx.x * 256 + threadIdx.x;  // < 65536
  int i = e & 63, j = (e >> 6) & 63, h = (e >> 12) & 3, type = e >> 14;
  float v = 0.f;
  if (i < 49 && j < 49) {
    int ri = i / 7, ci = i - ri * 7, rj = j / 7, cj = j - rj * 7;
    int ridx = (ri - rj + 6) * 13 + (ci - cj + 6);
    float bias = rpb[ridx * 4 + h];
    int th = type >> 1, tw = type & 1;
    int labi = (th ? ((ri < 4) ? 1 : 2) : 0) * 3 + (tw ? ((ci < 4) ? 1 : 2) : 0);
    int labj = (th ? ((rj < 4) ? 1 : 2) : 0) * 3 + (tw ? ((cj < 4) ? 1 : 2) : 0);
    v = bias + ((labi != labj) ? -100.f : 0.f);
  }
  TB[e] = v;
}

// ---------------------------------------------------------------------------
// K1: LN(norm1) + cyclic shift(-3,-3) + window partition -> bf16
// ---------------------------------------------------------------------------
__global__ __launch_bounds__(256) void k_ln1_part(
    const float* __restrict__ x, const float* __restrict__ g,
    const float* __restrict__ b, ushort* __restrict__ wp) {
  int lane = threadIdx.x & 63, wv = threadIdx.x >> 6;
  int half = lane >> 5, l32 = lane & 31;
  int tok = blockIdx.x * 8 + wv * 2 + half;    // 0..100351
  int win = tok / 49, n = tok - win * 49;
  int bb = win >> 6, wi = win & 63;
  int whi = wi >> 3, wwi = wi & 7;
  int r = n / 7, c = n - r * 7;
  int hs = whi * 7 + r + 3; if (hs >= 56) hs -= 56;
  int ws = wwi * 7 + c + 3; if (ws >= 56) ws -= 56;
  size_t src = ((size_t)bb * 3136 + hs * 56 + ws) * 128;
  float4 v = *(const float4*)(x + src + l32 * 4);
  float s = v.x + v.y + v.z + v.w;
  float sq = v.x * v.x + v.y * v.y + v.z * v.z + v.w * v.w;
#pragma unroll
  for (int off = 1; off < 32; off <<= 1) {
    s += __shfl_xor(s, off);
    sq += __shfl_xor(sq, off);
  }
  float mu = s * kInvC;
  float var = sq * kInvC - mu * mu;
  float rs = rsqrtf(var + kEps);
  float4 gg = *(const float4*)(g + l32 * 4);
  float4 bv = *(const float4*)(b + l32 * 4);
  float o0 = (v.x - mu) * rs * gg.x + bv.x;
  float o1 = (v.y - mu) * rs * gg.y + bv.y;
  float o2 = (v.z - mu) * rs * gg.z + bv.z;
  float o3 = (v.w - mu) * rs * gg.w + bv.w;
  uint2 p;
  p.x = (uint)f2bf(o0) | ((uint)f2bf(o1) << 16);
  p.y = (uint)f2bf(o2) | ((uint)f2bf(o3) << 16);
  ((uint2*)wp)[(size_t)tok * 32 + l32] = p;
}

// ---------------------------------------------------------------------------
// K-UNSHIFT: reverse window partition + reverse shift + residual + LN2.
// ---------------------------------------------------------------------------
__global__ __launch_bounds__(256) void k_unshift(
    const float* __restrict__ x, const ushort* __restrict__ yb,
    const float* __restrict__ g, const float* __restrict__ b,
    float* __restrict__ out, ushort* __restrict__ wp) {
  int lane = threadIdx.x & 63, wv = threadIdx.x >> 6;
  int half = lane >> 5, l32 = lane & 31;
  int tok = blockIdx.x * 8 + wv * 2 + half;    // natural order
  int bb = tok / 3136, rem = tok - bb * 3136;
  int ph = rem / 56, pw = rem - ph * 56;
  int sh = ph + 53; if (sh >= 56) sh -= 56;    // (ph-3) mod 56
  int sw = pw + 53; if (sw >= 56) sw -= 56;
  int whi = sh / 7, r7 = sh - whi * 7;
  int wwi = sw / 7, c7 = sw - wwi * 7;
  int win = bb * 64 + whi * 8 + wwi, nn = r7 * 7 + c7;
  size_t row = (size_t)tok * 128;
  float4 xv = *(const float4*)(x + row + l32 * 4);
  uint2 yv = ((const uint2*)yb)[((size_t)win * 49 + nn) * 32 + l32];
  float o0 = xv.x + bf2f((ushort)(yv.x & 0xffff));
  float o1 = xv.y + bf2f((ushort)(yv.x >> 16));
  float o2 = xv.z + bf2f((ushort)(yv.y & 0xffff));
  float o3 = xv.w + bf2f((ushort)(yv.y >> 16));
  float4 ov; ov.x = o0; ov.y = o1; ov.z = o2; ov.w = o3;
  *(float4*)(out + row + l32 * 4) = ov;
  float s = o0 + o1 + o2 + o3;
  float sq = o0 * o0 + o1 * o1 + o2 * o2 + o3 * o3;
#pragma unroll
  for (int off = 1; off < 32; off <<= 1) {
    s += __shfl_xor(s, off);
    sq += __shfl_xor(sq, off);
  }
  float mu = s * kInvC;
  float var = sq * kInvC - mu * mu;
  float rs = rsqrtf(var + kEps);
  float4 gg = *(const float4*)(g + l32 * 4);
  float4 bv = *(const float4*)(b + l32 * 4);
  float m0 = (o0 - mu) * rs * gg.x + bv.x;
  float m1 = (o1 - mu) * rs * gg.y + bv.y;
  float m2 = (o2 - mu) * rs * gg.z + bv.z;
  float m3 = (o3 - mu) * rs * gg.w + bv.w;
  uint2 p;
  p.x = (uint)f2bf(m0) | ((uint)f2bf(m1) << 16);
  p.y = (uint)f2bf(m2) | ((uint)f2bf(m3) << 16);
  ((uint2*)wp)[(size_t)tok * 32 + l32] = p;
}

// ---------------------------------------------------------------------------
// K-GEMM2: C[M,LDC chunk] = A[M,K] @ BT[N,K]^T + bias. 128x128 tile, BK=64,
// double-buffered gload_lds pipeline (used for QKV).
// ---------------------------------------------------------------------------
template <int K, int LDC, int EPI>
__global__ __launch_bounds__(256) void k_gemm2(
    const ushort* __restrict__ A, const ushort* __restrict__ BT,
    const float* __restrict__ bias, ushort* __restrict__ C) {
  __shared__ ushort sbuf[2 * 16384];  // 64 KB double buffer
  int tid = threadIdx.x;
  int nBase = blockIdx.x << 7;
  int mBase = blockIdx.y << 7;
  int lane = tid & 63, wid = tid >> 6;
  int li = lane & 15, g = lane >> 4;
  int wr = (wid >> 1) << 6, wc = (wid & 1) << 6;
  int swz = (li & 7) << 3;
  const ushort* Ab = A + (size_t)mBase * K;
  const ushort* Bb = BT + (size_t)nBase * K;
  f32x4 acc[4][4] = {};
  stage2<K>(Ab, Bb, sbuf, 0, tid, wid);
  __syncthreads();
  int cur = 0;
#pragma unroll
  for (int ks = 0; ks < K; ks += 64) {
    if (ks + 64 < K)
      stage2<K>(Ab + ks + 64, Bb + ks + 64, sbuf, cur ^ 1, tid, wid);
    const ushort(*As)[64] = (const ushort(*)[64])(sbuf + cur * 16384);
    const ushort(*Bs)[64] = (const ushort(*)[64])(sbuf + cur * 16384 + 8192);
#pragma unroll
    for (int ksub = 0; ksub < 64; ksub += 32) {
      int kloc = ksub + g * 8;
      bf16x8 af[4], bfr[4];
#pragma unroll
      for (int m = 0; m < 4; ++m)
        af[m] = *(const bf16x8*)&As[wr + m * 16 + li][kloc ^ swz];
#pragma unroll
      for (int n = 0; n < 4; ++n)
        bfr[n] = *(const bf16x8*)&Bs[wc + n * 16 + li][kloc ^ swz];
#pragma unroll
      for (int m = 0; m < 4; ++m)
#pragma unroll
        for (int n = 0; n < 4; ++n)
          acc[m][n] = __builtin_amdgcn_mfma_f32_16x16x32_bf16(
              af[m], bfr[n], acc[m][n], 0, 0, 0);
    }
    __syncthreads();  // prefetch landed; buffer-swap safe
    cur ^= 1;
  }
  ushort (*Cs)[128] = (ushort(*)[128])sbuf;  // overlays buffer 0
#pragma unroll
  for (int n = 0; n < 4; ++n) {
    float bv = bias[nBase + wc + n * 16 + li];
#pragma unroll
    for (int m = 0; m < 4; ++m) {
      int rb = wr + m * 16 + (g << 2);
#pragma unroll
      for (int r = 0; r < 4; ++r) {
        float v = acc[m][n][r] + bv;
        if (EPI == 1) v = gelu_fast(v);
        Cs[rb + r][wc + n * 16 + li] = f2bf(v);
      }
    }
  }
  __syncthreads();
#pragma unroll
  for (int it = 0; it < 8; ++it) {
    int ch = tid + it * 256;
    int row = ch >> 4, c8 = (ch & 15) << 3;
    *(bf16x8*)(C + (size_t)(mBase + row) * LDC + nBase + c8) =
        *(const bf16x8*)&Cs[row][c8];
  }
}

// ---------------------------------------------------------------------------
// K-MLPF: fused MLP. out[M,128] += gelu(wp[M,128]@W1+b1) @ W2 + b2.
// Per block: 128 rows. A-fragments hoisted to registers; per hidden-chunk
// (8 x 64): phase A produces h chunk into LDS, phase B accumulates out.
// W1/W2 chunks staged via swizzled gload_lds, cross-phase prefetched.
// LDS: [Wbuf0 16K][Wbuf1 16K][h_s 18K] = 50KB -> 3 blocks/CU.
// ---------------------------------------------------------------------------
__global__ __launch_bounds__(256) void k_mlpf(
    const ushort* __restrict__ wp, const ushort* __restrict__ w1T,
    const float* __restrict__ b1, const ushort* __restrict__ w2T,
    const float* __restrict__ b2, float* __restrict__ out) {
  __shared__ ushort sbuf[25600];
  ushort* Wbuf0 = sbuf;            // [64][128] W1 chunk
  ushort* Wbuf1 = sbuf + 8192;     // [128][64] W2 chunk
  ushort* h_s   = sbuf + 16384;    // [128][72] bf16 h chunk
  ushort* A_s   = sbuf + 8192;     // transient: 2 slots of [128][64]
  int tid = threadIdx.x;
  int mBase = blockIdx.x << 7;
  int lane = tid & 63, wid = tid >> 6;
  int li = lane & 15, g = lane >> 4;
  int swz = (li & 7) << 3;
  const ushort* Ab = wp + (size_t)mBase * 128;

  // prologue: stage A (2 slots) + W1 chunk 0
#pragma unroll
  for (int s = 0; s < 2; ++s)
#pragma unroll
    for (int l = 0; l < 4; ++l) {
      int c = l * 256 + tid;
      int row = c >> 3;
      int k8 = ((c & 7) ^ (row & 7)) << 3;
      gl16(Ab + (size_t)row * 128 + s * 64 + k8,
           A_s + s * 8192 + (l * 256 + wid * 64) * 8);
    }
#pragma unroll
  for (int l = 0; l < 4; ++l) {
    int c = l * 256 + tid;
    int row = c >> 4;                     // 0..63 (hidden col)
    int ch = (c & 15) ^ (row & 7);        // bijective low-3-bit XOR
    gl16(w1T + (size_t)row * 128 + ch * 8, Wbuf0 + (l * 256 + wid * 64) * 8);
  }
  __syncthreads();
  // hoist A-fragments to registers: rows wid*32 + m*16 + li, all K=128
  bf16x8 afr[4][2];
#pragma unroll
  for (int kstep = 0; kstep < 4; ++kstep) {
    int slot = kstep >> 1, kloc = (kstep & 1) * 32 + g * 8;
#pragma unroll
    for (int m = 0; m < 2; ++m) {
      int row = wid * 32 + m * 16 + li;
      afr[kstep][m] =
          *(const bf16x8*)(A_s + slot * 8192 + row * 64 + (kloc ^ swz));
    }
  }
  __syncthreads();  // all waves done reading A_s -> safe to overwrite

  int wr = (wid >> 1) << 6, wc = (wid & 1) << 6;
  f32x4 oacc[4][4] = {};
  for (int nc = 0; nc < 8; ++nc) {
    // issue W2 chunk nc -> Wbuf1 (rows = out col, k = nc*64..)
#pragma unroll
    for (int l = 0; l < 4; ++l) {
      int c = l * 256 + tid;
      int row = c >> 3;
      int k8 = ((c & 7) ^ (row & 7)) << 3;
      gl16(w2T + (size_t)row * 512 + nc * 64 + k8,
           Wbuf1 + (l * 256 + wid * 64) * 8);
    }
    // phase A: h = gelu(A @ W1chunk + b1); wave wid -> rows wid*32..+31
    f32x4 hacc[2][4] = {};
#pragma unroll
    for (int kstep = 0; kstep < 4; ++kstep) {
      int chix = kstep * 4 + g;          // kloc>>3
      bf16x8 bfr[4];
#pragma unroll
      for (int n = 0; n < 4; ++n) {
        int row = n * 16 + li;
        bfr[n] =
            *(const bf16x8*)(Wbuf0 + row * 128 + ((chix ^ (row & 7)) << 3));
      }
#pragma unroll
      for (int m = 0; m < 2; ++m)
#pragma unroll
        for (int n = 0; n < 4; ++n)
          hacc[m][n] = __builtin_amdgcn_mfma_f32_16x16x32_bf16(
              afr[kstep][m], bfr[n], hacc[m][n], 0, 0, 0);
    }
#pragma unroll
    for (int n = 0; n < 4; ++n) {
      float bb = b1[nc * 64 + n * 16 + li];
#pragma unroll
      for (int m = 0; m < 2; ++m) {
        int rb = wid * 32 + m * 16 + (g << 2);
#pragma unroll
        for (int r = 0; r < 4; ++r)
          h_s[(rb + r) * 72 + n * 16 + li] =
              f2bf(gelu_fast(hacc[m][n][r] + bb));
      }
    }
    __syncthreads();  // W2(nc) landed; h_s visible
    // issue W1 chunk nc+1 -> Wbuf0 (safe: all waves past phase A)
    if (nc < 7) {
#pragma unroll
      for (int l = 0; l < 4; ++l) {
        int c = l * 256 + tid;
        int row = c >> 4;
        int ch = (c & 15) ^ (row & 7);
        gl16(w1T + (size_t)((nc + 1) * 64 + row) * 128 + ch * 8,
             Wbuf0 + (l * 256 + wid * 64) * 8);
      }
    }
    // phase B: oacc += h[128 x 64k] @ W2chunk^T
#pragma unroll
    for (int ksub = 0; ksub < 64; ksub += 32) {
      int kloc = ksub + g * 8;
      bf16x8 af[4], bfr[4];
#pragma unroll
      for (int m = 0; m < 4; ++m)
        af[m] = *(const bf16x8*)(h_s + (wr + m * 16 + li) * 72 + kloc);
#pragma unroll
      for (int n = 0; n < 4; ++n)
        bfr[n] =
            *(const bf16x8*)(Wbuf1 + (wc + n * 16 + li) * 64 + (kloc ^ swz));
#pragma unroll
      for (int m = 0; m < 4; ++m)
#pragma unroll
        for (int n = 0; n < 4; ++n)
          oacc[m][n] = __builtin_amdgcn_mfma_f32_16x16x32_bf16(
              af[m], bfr[n], oacc[m][n], 0, 0, 0);
    }
    __syncthreads();  // W1(nc+1) landed; h_s reads done
  }
  // epilogue: out RMW
#pragma unroll
  for (int n = 0; n < 4; ++n) {
    int cg = wc + n * 16 + li;
    float bv = b2[cg];
#pragma unroll
    for (int m = 0; m < 4; ++m) {
      int rbase = mBase + wr + m * 16 + (g << 2);
#pragma unroll
      for (int r = 0; r < 4; ++r) {
        size_t off = (size_t)(rbase + r) * 128 + cg;
        out[off] += oacc[m][n][r] + bv;
      }
    }
  }
}

// ---------------------------------------------------------------------------
// K-PGEMM: proj GEMM + bias + row-LN(proj_ln) + GELU -> bf16 yb (contiguous).
// Double-buffered gload_lds pipeline; LDS-staged wide stores.
// ---------------------------------------------------------------------------
__global__ __launch_bounds__(256) void k_pgemm(
    const ushort* __restrict__ A, const ushort* __restrict__ BT,
    const float* __restrict__ pb, const float* __restrict__ lg,
    const float* __restrict__ lb, ushort* __restrict__ yb) {
  __shared__ ushort sbuf[2 * 16384];
  __shared__ float red[4][64][2];
  int tid = threadIdx.x;
  int mBase = blockIdx.x << 7;
  int lane = tid & 63, wid = tid >> 6;
  int li = lane & 15, g = lane >> 4;
  int wr = (wid >> 1) << 6, wc = (wid & 1) << 6;
  int swz = (li & 7) << 3;
  const ushort* Ab = A + (size_t)mBase * 128;
  f32x4 acc[4][4] = {};
  stage2<128>(Ab, BT, sbuf, 0, tid, wid);
  __syncthreads();
  int cur = 0;
#pragma unroll
  for (int ks = 0; ks < 128; ks += 64) {
    if (ks + 64 < 128)
      stage2<128>(Ab + ks + 64, BT + ks + 64, sbuf, cur ^ 1, tid, wid);
    const ushort(*As)[64] = (const ushort(*)[64])(sbuf + cur * 16384);
    const ushort(*Bs)[64] = (const ushort(*)[64])(sbuf + cur * 16384 + 8192);
#pragma unroll
    for (int ksub = 0; ksub < 64; ksub += 32) {
      int kloc = ksub + g * 8;
      bf16x8 af[4], bfr[4];
#pragma unroll
      for (int m = 0; m < 4; ++m)
        af[m] = *(const bf16x8*)&As[wr + m * 16 + li][kloc ^ swz];
#pragma unroll
      for (int n = 0; n < 4; ++n)
        bfr[n] = *(const bf16x8*)&Bs[wc + n * 16 + li][kloc ^ swz];
#pragma unroll
      for (int m = 0; m < 4; ++m)
#pragma unroll
        for (int n = 0; n < 4; ++n)
          acc[m][n] = __builtin_amdgcn_mfma_f32_16x16x32_bf16(
              af[m], bfr[n], acc[m][n], 0, 0, 0);
    }
    __syncthreads();
    cur ^= 1;
  }
  float pbv[4], lgv[4], lbv[4];
#pragma unroll
  for (int n = 0; n < 4; ++n) {
    int cg = wc + n * 16 + li;
    pbv[n] = pb[cg]; lgv[n] = lg[cg]; lbv[n] = lb[cg];
  }
  float ps[4][4], psq[4][4];
#pragma unroll
  for (int m = 0; m < 4; ++m)
#pragma unroll
    for (int r = 0; r < 4; ++r) {
      float s = 0.f, q = 0.f;
#pragma unroll
      for (int n = 0; n < 4; ++n) {
        float v = acc[m][n][r] + pbv[n];
        s += v; q += v * v;
      }
#pragma unroll
      for (int off = 1; off < 16; off <<= 1) {
        s += __shfl_xor(s, off);
        q += __shfl_xor(q, off);
      }
      ps[m][r] = s; psq[m][r] = q;
    }
  if (li == 0) {
#pragma unroll
    for (int m = 0; m < 4; ++m)
#pragma unroll
      for (int r = 0; r < 4; ++r) {
        int rl = m * 16 + (g << 2) + r;
        red[wid][rl][0] = ps[m][r];
        red[wid][rl][1] = psq[m][r];
      }
  }
  __syncthreads();
  ushort (*Cs)[128] = (ushort(*)[128])sbuf;
#pragma unroll
  for (int m = 0; m < 4; ++m) {
#pragma unroll
    for (int r = 0; r < 4; ++r) {
      int rl = m * 16 + (g << 2) + r;
      float s = ps[m][r] + red[wid ^ 1][rl][0];
      float q = psq[m][r] + red[wid ^ 1][rl][1];
      float mu = s * kInvC, var = q * kInvC - mu * mu;
      float rs = rsqrtf(var + kEps);
#pragma unroll
      for (int n = 0; n < 4; ++n) {
        float y = (acc[m][n][r] + pbv[n] - mu) * rs * lgv[n] + lbv[n];
        Cs[wr + rl][wc + n * 16 + li] = f2bf(gelu_fast(y));
      }
    }
  }
  __syncthreads();
#pragma unroll
  for (int it = 0; it < 8; ++it) {
    int ch = tid + it * 256;
    int row = ch >> 4, c8 = (ch & 15) << 3;
    *(bf16x8*)(yb + (size_t)(mBase + row) * 128 + c8) =
        *(const bf16x8*)&Cs[row][c8];
  }
}

// ---------------------------------------------------------------------------
// K3: MFMA attention. 1 block = 1 window, 1 wave = 1 head. LDS-staged O store.
// ---------------------------------------------------------------------------
__global__ __launch_bounds__(256) void k_attn(
    const ushort* __restrict__ qkv, const float* __restrict__ TB,
    ushort* __restrict__ ob) {
  __shared__ ushort Pl[4][64][72];
  __shared__ ushort Vt[4][32][72];
  int tid = threadIdx.x;
  int lane = tid & 63, h = tid >> 6;
  int li = lane & 15, g = lane >> 4;
  int win = blockIdx.x;
  int wi = win & 63;
  int type = (((wi >> 3) == 7) ? 2 : 0) | (((wi & 7) == 7) ? 1 : 0);

  const ushort* qbase = qkv + (size_t)win * 49 * 384 + h * 32 + g * 8;
  bf16x8 kf[4], qf[4];
#pragma unroll
  for (int m = 0; m < 4; ++m) {
    kf[m] = *(const bf16x8*)(qbase + (size_t)(m * 16 + li) * 384 + 128);
    qf[m] = *(const bf16x8*)(qbase + (size_t)(m * 16 + li) * 384);
  }
  f32x4 zero = {0.f, 0.f, 0.f, 0.f};
  f32x4 st[4][4];
#pragma unroll
  for (int m = 0; m < 4; ++m)
#pragma unroll
    for (int n = 0; n < 4; ++n)
      st[m][n] = __builtin_amdgcn_mfma_f32_16x16x32_bf16(kf[m], qf[n], zero, 0, 0, 0);

  if (lane < 49) {
#pragma unroll
    for (int dc = 0; dc < 4; ++dc) {
      bf16x8 vv = *(const bf16x8*)(qkv + ((size_t)win * 49 + lane) * 384 + 256 +
                                   h * 32 + dc * 8);
#pragma unroll
      for (int t = 0; t < 8; ++t) Vt[h][dc * 8 + t][lane] = (ushort)vv[t];
    }
  } else {
#pragma unroll
    for (int d = 0; d < 32; ++d) Vt[h][d][lane] = 0;
  }

  const float* tb = TB + ((size_t)(type * 4 + h) << 12);
#pragma unroll
  for (int n = 0; n < 4; ++n) {
    int icol = n * 16 + li;
    float sv[3][4];
#pragma unroll
    for (int m = 0; m < 3; ++m)
#pragma unroll
      for (int r = 0; r < 4; ++r)
        sv[m][r] = st[m][n][r] * kScale + tb[(m * 16 + g * 4 + r) * 64 + icol];
    float sv3 = (g == 0) ? (st[3][n][0] * kScale + tb[48 * 64 + icol]) : -1e30f;
    float mx = sv3;
#pragma unroll
    for (int m = 0; m < 3; ++m)
#pragma unroll
      for (int r = 0; r < 4; ++r) mx = fmaxf(mx, sv[m][r]);
    mx = fmaxf(mx, __shfl_xor(mx, 16));
    mx = fmaxf(mx, __shfl_xor(mx, 32));
    float e[3][4], e3 = __expf(sv3 - mx);
    float sum = e3;
#pragma unroll
    for (int m = 0; m < 3; ++m)
#pragma unroll
      for (int r = 0; r < 4; ++r) { e[m][r] = __expf(sv[m][r] - mx); sum += e[m][r]; }
    sum += __shfl_xor(sum, 16);
    sum += __shfl_xor(sum, 32);
    float inv = 1.f / sum;
    float p3 = e3 * inv;
    float v3 = (g == 0) ? p3 : -1e30f;
    float mx2 = v3;
#pragma unroll
    for (int m = 0; m < 3; ++m)
#pragma unroll
      for (int r = 0; r < 4; ++r) mx2 = fmaxf(mx2, e[m][r] * inv);
    mx2 = fmaxf(mx2, __shfl_xor(mx2, 16));
    mx2 = fmaxf(mx2, __shfl_xor(mx2, 32));
    float e2[3][4], e23 = __expf(v3 - mx2);
    float sum2 = e23;
#pragma unroll
    for (int m = 0; m < 3; ++m)
#pragma unroll
      for (int r = 0; r < 4; ++r) { e2[m][r] = __expf(e[m][r] * inv - mx2); sum2 += e2[m][r]; }
    sum2 += __shfl_xor(sum2, 16);
    sum2 += __shfl_xor(sum2, 32);
    float inv2 = 1.f / sum2;
#pragma unroll
    for (int m = 0; m < 3; ++m) {
      uint u0 = (uint)f2bf(e2[m][0] * inv2) | ((uint)f2bf(e2[m][1] * inv2) << 16);
      uint u1 = (uint)f2bf(e2[m][2] * inv2) | ((uint)f2bf(e2[m][3] * inv2) << 16);
      *(uint*)&Pl[h][icol][m * 16 + g * 4]     = u0;
      *(uint*)&Pl[h][icol][m * 16 + g * 4 + 2] = u1;
    }
    uint u3 = (uint)f2bf(e23 * inv2);
    *(uint*)&Pl[h][icol][48 + g * 4]     = u3;
    *(uint*)&Pl[h][icol][48 + g * 4 + 2] = 0u;
  }
  __syncthreads();

  f32x4 oacc[4][2] = {};
#pragma unroll
  for (int ks = 0; ks < 2; ++ks) {
    int kloc = ks * 32 + g * 8;
    bf16x8 bf0 = *(const bf16x8*)&Vt[h][li][kloc];
    bf16x8 bf1 = *(const bf16x8*)&Vt[h][16 + li][kloc];
#pragma unroll
    for (int mi = 0; mi < 4; ++mi) {
      bf16x8 af = *(const bf16x8*)&Pl[h][mi * 16 + li][kloc];
      oacc[mi][0] = __builtin_amdgcn_mfma_f32_16x16x32_bf16(af, bf0, oacc[mi][0], 0, 0, 0);
      oacc[mi][1] = __builtin_amdgcn_mfma_f32_16x16x32_bf16(af, bf1, oacc[mi][1], 0, 0, 0);
    }
  }
  // stage O (49 x 32 per head) into Pl[h] (stride 40), then wide stores
  ushort* OlH = &Pl[h][0][0];
#pragma unroll
  for (int mi = 0; mi < 4; ++mi)
#pragma unroll
    for (int r = 0; r < 4; ++r) {
      int i = mi * 16 + g * 4 + r;
      if (mi < 3 || (g == 0 && r == 0)) {
        OlH[i * 40 + li]      = f2bf(oacc[mi][0][r]);
        OlH[i * 40 + 16 + li] = f2bf(oacc[mi][1][r]);
      }
    }
  __syncthreads();
  ushort* obase = ob + (size_t)win * 49 * 128;
#pragma unroll
  for (int it = 0; it < 4; ++it) {
    int chunk = tid + it * 256;  // 784 chunks of 8 ushorts
    if (chunk < 784) {
      int row = chunk >> 4, c8 = (chunk & 15) << 3;
      int h2 = c8 >> 5, d8 = c8 & 31;
      bf16x8 v = *(const bf16x8*)(&Pl[h2][0][0] + row * 40 + d8);
      *(bf16x8*)(obase + (size_t)row * 128 + c8) = v;
    }
  }
}

extern "C" void kernel_launch(void* const* d_in, const int* in_sizes, int n_in,
                              void* d_out, int out_size, void* d_ws,
                              size_t ws_size, hipStream_t stream) {
  (void)in_sizes; (void)n_in; (void)out_size; (void)ws_size;
  const float* x      = (const float*)d_in[0];
  const float* qkv_w  = (const float*)d_in[1];
  const float* qkv_b  = (const float*)d_in[2];
  const float* proj_w = (const float*)d_in[3];
  const float* proj_b = (const float*)d_in[4];
  const float* plg    = (const float*)d_in[5];
  const float* plb    = (const float*)d_in[6];
  const float* rpb    = (const float*)d_in[7];
  const float* n1g    = (const float*)d_in[8];
  const float* n1b    = (const float*)d_in[9];
  const float* n2g    = (const float*)d_in[10];
  const float* n2b    = (const float*)d_in[11];
  const float* w1     = (const float*)d_in[12];
  const float* b1     = (const float*)d_in[13];
  const float* w2     = (const float*)d_in[14];
  const float* b2     = (const float*)d_in[15];
  float* out = (float*)d_out;

  // ws layout (ushort units)
  ushort* wp   = (ushort*)d_ws;                         // 100352*128
  ushort* qkvb = wp + (size_t)100352 * 128;             // 100352*384
  ushort* obb  = qkvb + (size_t)100352 * 384;           // 100352*128
  ushort* qkvT = obb + (size_t)100352 * 128;            // 384*128
  ushort* w1T  = qkvT + 384 * 128;                      // 512*128
  ushort* w2T  = w1T + 512 * 128;                       // 128*512
  ushort* pT   = w2T + 128 * 512;                       // 128*128
  float*  TB   = (float*)(pT + 128 * 128);              // 4*4*64*64 f32
  ushort* yb   = qkvb;  // alias: qkvb dead after k_attn

  k_prep<<<768, 256, 0, stream>>>(qkv_w, w1, w2, proj_w, qkvT, w1T, w2T, pT);
  k_prep2<<<256, 256, 0, stream>>>(rpb, TB);
  k_ln1_part<<<12544, 256, 0, stream>>>(x, n1g, n1b, wp);
  k_gemm2<128, 384, 0><<<dim3(3, 784), 256, 0, stream>>>(wp, qkvT, qkv_b, qkvb);
  k_attn<<<2048, 256, 0, stream>>>(qkvb, TB, obb);
  k_pgemm<<<784, 256, 0, stream>>>(obb, pT, proj_b, plg, plb, yb);
  k_unshift<<<12544, 256, 0, stream>>>(x, yb, n2g, n2b, out, wp);
  k_mlpf<<<784, 256, 0, stream>>>(wp, w1T, b1, w2T, b2, out);
}

// Round 13
// 224.652 us; speedup vs baseline: 6.4209x; 1.0269x over previous
//
#include <hip/hip_runtime.h>
#include <cstdint>
#include <cstddef>

typedef __attribute__((ext_vector_type(8))) short bf16x8;
typedef __attribute__((ext_vector_type(4))) float f32x4;

namespace {
constexpr float kScale = 0.17677669529663689f; // 32^-0.5
constexpr float kEps = 1e-6f;
constexpr float kInvC = 1.0f / 128.0f;

// tanh-form GELU as v*sigmoid(2u).
__device__ __forceinline__ float gelu_fast(float v) {
  float t1 = fmaf(0.044715f * v, v, 1.0f);
  float x = v * t1 * -1.5957691216057308f;
  float e = __expf(x);
  return v * __builtin_amdgcn_rcpf(1.0f + e);
}
__device__ __forceinline__ ushort f2bf(float f) {
  uint32_t u = __builtin_bit_cast(uint32_t, f);
  u += 0x7FFFu + ((u >> 16) & 1u);
  return (ushort)(u >> 16);
}
__device__ __forceinline__ float bf2f(ushort u) {
  return __builtin_bit_cast(float, (uint32_t)u << 16);
}
// async global->LDS, 16B per lane. LDS dest is wave-uniform base + lane*16.
__device__ __forceinline__ void gl16(const ushort* g, ushort* l) {
  __builtin_amdgcn_global_load_lds(
      (const __attribute__((address_space(1))) void*)g,
      (__attribute__((address_space(3))) void*)l, 16, 0, 0);
}
// stage one 128x64 A-tile + 128x64 B-tile (XOR-pre-swizzled source) into
// double-buffer slot `buf` of sbuf (each slot: As 8192 + Bs 8192 ushorts).
template <int K>
__device__ __forceinline__ void stage2(const ushort* a, const ushort* b,
                                       ushort* sbuf, int buf, int tid,
                                       int wid) {
#pragma unroll
  for (int l = 0; l < 4; ++l) {
    int c = l * 256 + tid;
    int row = c >> 3;
    int k8 = ((c & 7) ^ (row & 7)) << 3;   // pre-swizzled source chunk
    int lo = buf * 16384 + (l * 256 + wid * 64) * 8;  // wave-uniform dest
    gl16(a + (size_t)row * K + k8, sbuf + lo);
    gl16(b + (size_t)row * K + k8, sbuf + 8192 + lo);
  }
}
} // namespace

// ---------------------------------------------------------------------------
// K0: convert+transpose weights to bf16 [N][K] layout.
// ---------------------------------------------------------------------------
__global__ __launch_bounds__(256) void k_prep(
    const float* __restrict__ qkv_w, const float* __restrict__ w1,
    const float* __restrict__ w2, const float* __restrict__ pw,
    ushort* __restrict__ qkvT, ushort* __restrict__ w1T,
    ushort* __restrict__ w2T, ushort* __restrict__ projT) {
  int i = blockIdx.x * 256 + threadIdx.x;
  if (i < 49152) {
    int n = i >> 7, k = i & 127;
    qkvT[i] = f2bf(qkv_w[k * 384 + n]);
  } else if (i < 114688) {
    int j = i - 49152;
    int n = j >> 7, k = j & 127;
    w1T[j] = f2bf(w1[k * 512 + n]);
  } else if (i < 180224) {
    int j = i - 114688;
    int n = j >> 9, k = j & 511;
    w2T[j] = f2bf(w2[k * 128 + n]);
  } else if (i < 196608) {
    int j = i - 180224;
    int n = j >> 7, k = j & 127;
    projT[j] = f2bf(pw[k * 128 + n]);
  }
}

// ---------------------------------------------------------------------------
// K0b: precompute bias+mask table TB[type(4)][head(4)][j(64)][i(64)] f32.
// ---------------------------------------------------------------------------
__global__ __launch_bounds__(256) void k_prep2(
    const float* __restrict__ rpb, float* __restrict__ TB) {
  int e = blockIdx.x * 256 + threadIdx.x;  // < 65536
  int i = e & 63, j = (e >> 6) & 63, h = (e >> 12) & 3, type = e >> 14;
  float v = 0.f;
  if (i < 49 && j < 49) {
    int ri = i / 7, ci = i - ri * 7, rj = j / 7, cj = j - rj * 7;
    int ridx = (ri - rj + 6) * 13 + (ci - cj + 6);
    float bias = rpb[ridx * 4 + h];
    int th = type >> 1, tw = type & 1;
    int labi = (th ? ((ri < 4) ? 1 : 2) : 0) * 3 + (tw ? ((ci < 4) ? 1 : 2) : 0);
    int labj = (th ? ((rj < 4) ? 1 : 2) : 0) * 3 + (tw ? ((cj < 4) ? 1 : 2) : 0);
    v = bias + ((labi != labj) ? -100.f : 0.f);
  }
  TB[e] = v;
}

// ---------------------------------------------------------------------------
// K1: LN(norm1) + cyclic shift(-3,-3) + window partition -> bf16
// ---------------------------------------------------------------------------
__global__ __launch_bounds__(256) void k_ln1_part(
    const float* __restrict__ x, const float* __restrict__ g,
    const float* __restrict__ b, ushort* __restrict__ wp) {
  int lane = threadIdx.x & 63, wv = threadIdx.x >> 6;
  int half = lane >> 5, l32 = lane & 31;
  int tok = blockIdx.x * 8 + wv * 2 + half;    // 0..100351
  int win = tok / 49, n = tok - win * 49;
  int bb = win >> 6, wi = win & 63;
  int whi = wi >> 3, wwi = wi & 7;
  int r = n / 7, c = n - r * 7;
  int hs = whi * 7 + r + 3; if (hs >= 56) hs -= 56;
  int ws = wwi * 7 + c + 3; if (ws >= 56) ws -= 56;
  size_t src = ((size_t)bb * 3136 + hs * 56 + ws) * 128;
  float4 v = *(const float4*)(x + src + l32 * 4);
  float s = v.x + v.y + v.z + v.w;
  float sq = v.x * v.x + v.y * v.y + v.z * v.z + v.w * v.w;
#pragma unroll
  for (int off = 1; off < 32; off <<= 1) {
    s += __shfl_xor(s, off);
    sq += __shfl_xor(sq, off);
  }
  float mu = s * kInvC;
  float var = sq * kInvC - mu * mu;
  float rs = rsqrtf(var + kEps);
  float4 gg = *(const float4*)(g + l32 * 4);
  float4 bv = *(const float4*)(b + l32 * 4);
  float o0 = (v.x - mu) * rs * gg.x + bv.x;
  float o1 = (v.y - mu) * rs * gg.y + bv.y;
  float o2 = (v.z - mu) * rs * gg.z + bv.z;
  float o3 = (v.w - mu) * rs * gg.w + bv.w;
  uint2 p;
  p.x = (uint)f2bf(o0) | ((uint)f2bf(o1) << 16);
  p.y = (uint)f2bf(o2) | ((uint)f2bf(o3) << 16);
  ((uint2*)wp)[(size_t)tok * 32 + l32] = p;
}

// ---------------------------------------------------------------------------
// K-UNSHIFT: reverse window partition + reverse shift + residual + LN2.
// ---------------------------------------------------------------------------
__global__ __launch_bounds__(256) void k_unshift(
    const float* __restrict__ x, const ushort* __restrict__ yb,
    const float* __restrict__ g, const float* __restrict__ b,
    float* __restrict__ out, ushort* __restrict__ wp) {
  int lane = threadIdx.x & 63, wv = threadIdx.x >> 6;
  int half = lane >> 5, l32 = lane & 31;
  int tok = blockIdx.x * 8 + wv * 2 + half;    // natural order
  int bb = tok / 3136, rem = tok - bb * 3136;
  int ph = rem / 56, pw = rem - ph * 56;
  int sh = ph + 53; if (sh >= 56) sh -= 56;    // (ph-3) mod 56
  int sw = pw + 53; if (sw >= 56) sw -= 56;
  int whi = sh / 7, r7 = sh - whi * 7;
  int wwi = sw / 7, c7 = sw - wwi * 7;
  int win = bb * 64 + whi * 8 + wwi, nn = r7 * 7 + c7;
  size_t row = (size_t)tok * 128;
  float4 xv = *(const float4*)(x + row + l32 * 4);
  uint2 yv = ((const uint2*)yb)[((size_t)win * 49 + nn) * 32 + l32];
  float o0 = xv.x + bf2f((ushort)(yv.x & 0xffff));
  float o1 = xv.y + bf2f((ushort)(yv.x >> 16));
  float o2 = xv.z + bf2f((ushort)(yv.y & 0xffff));
  float o3 = xv.w + bf2f((ushort)(yv.y >> 16));
  float4 ov; ov.x = o0; ov.y = o1; ov.z = o2; ov.w = o3;
  *(float4*)(out + row + l32 * 4) = ov;
  float s = o0 + o1 + o2 + o3;
  float sq = o0 * o0 + o1 * o1 + o2 * o2 + o3 * o3;
#pragma unroll
  for (int off = 1; off < 32; off <<= 1) {
    s += __shfl_xor(s, off);
    sq += __shfl_xor(sq, off);
  }
  float mu = s * kInvC;
  float var = sq * kInvC - mu * mu;
  float rs = rsqrtf(var + kEps);
  float4 gg = *(const float4*)(g + l32 * 4);
  float4 bv = *(const float4*)(b + l32 * 4);
  float m0 = (o0 - mu) * rs * gg.x + bv.x;
  float m1 = (o1 - mu) * rs * gg.y + bv.y;
  float m2 = (o2 - mu) * rs * gg.z + bv.z;
  float m3 = (o3 - mu) * rs * gg.w + bv.w;
  uint2 p;
  p.x = (uint)f2bf(m0) | ((uint)f2bf(m1) << 16);
  p.y = (uint)f2bf(m2) | ((uint)f2bf(m3) << 16);
  ((uint2*)wp)[(size_t)tok * 32 + l32] = p;
}

// ---------------------------------------------------------------------------
// K-GEMM2 (M=64 tile): C[64, 128-chunk] = A[64,K] @ BT[N,K]^T + bias.
// Single-buffer 24KB LDS (A[64][64] + B[128][64]) -> ~6 blocks/CU for TLP
// latency hiding. Swizzled gload_lds staging; LDS-staged contiguous stores.
// EPI 0: bias -> bf16. EPI 1: bias+gelu -> bf16.
// ---------------------------------------------------------------------------
template <int K, int LDC, int EPI>
__global__ __launch_bounds__(256) void k_gemm2(
    const ushort* __restrict__ A, const ushort* __restrict__ BT,
    const float* __restrict__ bias, ushort* __restrict__ C) {
  __shared__ ushort sbuf[12288];  // A 4096 | B 8192 (ushorts)
  int tid = threadIdx.x;
  int nBase = blockIdx.x << 7;
  int mBase = blockIdx.y << 6;
  int lane = tid & 63, wid = tid >> 6;
  int li = lane & 15, g = lane >> 4;
  int wr = (wid >> 1) << 5, wc = (wid & 1) << 6;
  int swz = (li & 7) << 3;
  f32x4 acc[2][4] = {};
  for (int ks = 0; ks < K; ks += 64) {
#pragma unroll
    for (int l = 0; l < 2; ++l) {
      int c = l * 256 + tid;
      int row = c >> 3;
      int k8 = ((c & 7) ^ (row & 7)) << 3;
      gl16(A + (size_t)(mBase + row) * K + ks + k8,
           sbuf + (l * 256 + wid * 64) * 8);
    }
#pragma unroll
    for (int l = 0; l < 4; ++l) {
      int c = l * 256 + tid;
      int row = c >> 3;
      int k8 = ((c & 7) ^ (row & 7)) << 3;
      gl16(BT + (size_t)(nBase + row) * K + ks + k8,
           sbuf + 4096 + (l * 256 + wid * 64) * 8);
    }
    __syncthreads();
#pragma unroll
    for (int ksub = 0; ksub < 64; ksub += 32) {
      int kloc = ksub + g * 8;
      bf16x8 af[2], bfr[4];
#pragma unroll
      for (int m = 0; m < 2; ++m)
        af[m] = *(const bf16x8*)(sbuf + (wr + m * 16 + li) * 64 + (kloc ^ swz));
#pragma unroll
      for (int n = 0; n < 4; ++n)
        bfr[n] = *(const bf16x8*)(sbuf + 4096 + (wc + n * 16 + li) * 64 +
                                  (kloc ^ swz));
#pragma unroll
      for (int m = 0; m < 2; ++m)
#pragma unroll
        for (int n = 0; n < 4; ++n)
          acc[m][n] = __builtin_amdgcn_mfma_f32_16x16x32_bf16(
              af[m], bfr[n], acc[m][n], 0, 0, 0);
    }
    __syncthreads();
  }
  ushort (*Cs)[128] = (ushort(*)[128])sbuf;  // 64x128 overlay (16KB)
#pragma unroll
  for (int n = 0; n < 4; ++n) {
    float bv = bias[nBase + wc + n * 16 + li];
#pragma unroll
    for (int m = 0; m < 2; ++m) {
      int rb = wr + m * 16 + (g << 2);
#pragma unroll
      for (int r = 0; r < 4; ++r) {
        float v = acc[m][n][r] + bv;
        if (EPI == 1) v = gelu_fast(v);
        Cs[rb + r][wc + n * 16 + li] = f2bf(v);
      }
    }
  }
  __syncthreads();
#pragma unroll
  for (int it = 0; it < 4; ++it) {
    int ch = tid + it * 256;  // 1024 chunks of 8
    int row = ch >> 4, c8 = (ch & 15) << 3;
    *(bf16x8*)(C + (size_t)(mBase + row) * LDC + nBase + c8) =
        *(const bf16x8*)&Cs[row][c8];
  }
}

// ---------------------------------------------------------------------------
// K-MLP2 (M=64 tile): out[64,128] += hb[64,512] @ w2T^T + b2. Single-buffer.
// ---------------------------------------------------------------------------
__global__ __launch_bounds__(256) void k_mlp2(
    const ushort* __restrict__ A, const ushort* __restrict__ BT,
    const float* __restrict__ bias, float* __restrict__ out) {
  __shared__ ushort sbuf[12288];
  int tid = threadIdx.x;
  int mBase = blockIdx.x << 6;
  int lane = tid & 63, wid = tid >> 6;
  int li = lane & 15, g = lane >> 4;
  int wr = (wid >> 1) << 5, wc = (wid & 1) << 6;
  int swz = (li & 7) << 3;
  f32x4 acc[2][4] = {};
  for (int ks = 0; ks < 512; ks += 64) {
#pragma unroll
    for (int l = 0; l < 2; ++l) {
      int c = l * 256 + tid;
      int row = c >> 3;
      int k8 = ((c & 7) ^ (row & 7)) << 3;
      gl16(A + (size_t)(mBase + row) * 512 + ks + k8,
           sbuf + (l * 256 + wid * 64) * 8);
    }
#pragma unroll
    for (int l = 0; l < 4; ++l) {
      int c = l * 256 + tid;
      int row = c >> 3;
      int k8 = ((c & 7) ^ (row & 7)) << 3;
      gl16(BT + (size_t)row * 512 + ks + k8,
           sbuf + 4096 + (l * 256 + wid * 64) * 8);
    }
    __syncthreads();
#pragma unroll
    for (int ksub = 0; ksub < 64; ksub += 32) {
      int kloc = ksub + g * 8;
      bf16x8 af[2], bfr[4];
#pragma unroll
      for (int m = 0; m < 2; ++m)
        af[m] = *(const bf16x8*)(sbuf + (wr + m * 16 + li) * 64 + (kloc ^ swz));
#pragma unroll
      for (int n = 0; n < 4; ++n)
        bfr[n] = *(const bf16x8*)(sbuf + 4096 + (wc + n * 16 + li) * 64 +
                                  (kloc ^ swz));
#pragma unroll
      for (int m = 0; m < 2; ++m)
#pragma unroll
        for (int n = 0; n < 4; ++n)
          acc[m][n] = __builtin_amdgcn_mfma_f32_16x16x32_bf16(
              af[m], bfr[n], acc[m][n], 0, 0, 0);
    }
    __syncthreads();
  }
#pragma unroll
  for (int n = 0; n < 4; ++n) {
    int cg = wc + n * 16 + li;
    float bv = bias[cg];
#pragma unroll
    for (int m = 0; m < 2; ++m) {
      int rbase = mBase + wr + m * 16 + (g << 2);
#pragma unroll
      for (int r = 0; r < 4; ++r) {
        size_t off = (size_t)(rbase + r) * 128 + cg;
        out[off] += acc[m][n][r] + bv;
      }
    }
  }
}

// ---------------------------------------------------------------------------
// K-PGEMM: proj GEMM + bias + row-LN(proj_ln) + GELU -> bf16 yb (contiguous).
// Double-buffered gload_lds pipeline; LDS-staged wide stores. M=128.
// ---------------------------------------------------------------------------
__global__ __launch_bounds__(256) void k_pgemm(
    const ushort* __restrict__ A, const ushort* __restrict__ BT,
    const float* __restrict__ pb, const float* __restrict__ lg,
    const float* __restrict__ lb, ushort* __restrict__ yb) {
  __shared__ ushort sbuf[2 * 16384];
  __shared__ float red[4][64][2];
  int tid = threadIdx.x;
  int mBase = blockIdx.x << 7;
  int lane = tid & 63, wid = tid >> 6;
  int li = lane & 15, g = lane >> 4;
  int wr = (wid >> 1) << 6, wc = (wid & 1) << 6;
  int swz = (li & 7) << 3;
  const ushort* Ab = A + (size_t)mBase * 128;
  f32x4 acc[4][4] = {};
  stage2<128>(Ab, BT, sbuf, 0, tid, wid);
  __syncthreads();
  int cur = 0;
#pragma unroll
  for (int ks = 0; ks < 128; ks += 64) {
    if (ks + 64 < 128)
      stage2<128>(Ab + ks + 64, BT + ks + 64, sbuf, cur ^ 1, tid, wid);
    const ushort(*As)[64] = (const ushort(*)[64])(sbuf + cur * 16384);
    const ushort(*Bs)[64] = (const ushort(*)[64])(sbuf + cur * 16384 + 8192);
#pragma unroll
    for (int ksub = 0; ksub < 64; ksub += 32) {
      int kloc = ksub + g * 8;
      bf16x8 af[4], bfr[4];
#pragma unroll
      for (int m = 0; m < 4; ++m)
        af[m] = *(const bf16x8*)&As[wr + m * 16 + li][kloc ^ swz];
#pragma unroll
      for (int n = 0; n < 4; ++n)
        bfr[n] = *(const bf16x8*)&Bs[wc + n * 16 + li][kloc ^ swz];
#pragma unroll
      for (int m = 0; m < 4; ++m)
#pragma unroll
        for (int n = 0; n < 4; ++n)
          acc[m][n] = __builtin_amdgcn_mfma_f32_16x16x32_bf16(
              af[m], bfr[n], acc[m][n], 0, 0, 0);
    }
    __syncthreads();
    cur ^= 1;
  }
  float pbv[4], lgv[4], lbv[4];
#pragma unroll
  for (int n = 0; n < 4; ++n) {
    int cg = wc + n * 16 + li;
    pbv[n] = pb[cg]; lgv[n] = lg[cg]; lbv[n] = lb[cg];
  }
  float ps[4][4], psq[4][4];
#pragma unroll
  for (int m = 0; m < 4; ++m)
#pragma unroll
    for (int r = 0; r < 4; ++r) {
      float s = 0.f, q = 0.f;
#pragma unroll
      for (int n = 0; n < 4; ++n) {
        float v = acc[m][n][r] + pbv[n];
        s += v; q += v * v;
      }
#pragma unroll
      for (int off = 1; off < 16; off <<= 1) {
        s += __shfl_xor(s, off);
        q += __shfl_xor(q, off);
      }
      ps[m][r] = s; psq[m][r] = q;
    }
  if (li == 0) {
#pragma unroll
    for (int m = 0; m < 4; ++m)
#pragma unroll
      for (int r = 0; r < 4; ++r) {
        int rl = m * 16 + (g << 2) + r;
        red[wid][rl][0] = ps[m][r];
        red[wid][rl][1] = psq[m][r];
      }
  }
  __syncthreads();
  ushort (*Cs)[128] = (ushort(*)[128])sbuf;
#pragma unroll
  for (int m = 0; m < 4; ++m) {
#pragma unroll
    for (int r = 0; r < 4; ++r) {
      int rl = m * 16 + (g << 2) + r;
      float s = ps[m][r] + red[wid ^ 1][rl][0];
      float q = psq[m][r] + red[wid ^ 1][rl][1];
      float mu = s * kInvC, var = q * kInvC - mu * mu;
      float rs = rsqrtf(var + kEps);
#pragma unroll
      for (int n = 0; n < 4; ++n) {
        float y = (acc[m][n][r] + pbv[n] - mu) * rs * lgv[n] + lbv[n];
        Cs[wr + rl][wc + n * 16 + li] = f2bf(gelu_fast(y));
      }
    }
  }
  __syncthreads();
#pragma unroll
  for (int it = 0; it < 8; ++it) {
    int ch = tid + it * 256;
    int row = ch >> 4, c8 = (ch & 15) << 3;
    *(bf16x8*)(yb + (size_t)(mBase + row) * 128 + c8) =
        *(const bf16x8*)&Cs[row][c8];
  }
}

// ---------------------------------------------------------------------------
// K3: MFMA attention. 1 block = 1 window, 1 wave = 1 head. LDS-staged O store.
// ---------------------------------------------------------------------------
__global__ __launch_bounds__(256) void k_attn(
    const ushort* __restrict__ qkv, const float* __restrict__ TB,
    ushort* __restrict__ ob) {
  __shared__ ushort Pl[4][64][72];
  __shared__ ushort Vt[4][32][72];
  int tid = threadIdx.x;
  int lane = tid & 63, h = tid >> 6;
  int li = lane & 15, g = lane >> 4;
  int win = blockIdx.x;
  int wi = win & 63;
  int type = (((wi >> 3) == 7) ? 2 : 0) | (((wi & 7) == 7) ? 1 : 0);

  const ushort* qbase = qkv + (size_t)win * 49 * 384 + h * 32 + g * 8;
  bf16x8 kf[4], qf[4];
#pragma unroll
  for (int m = 0; m < 4; ++m) {
    kf[m] = *(const bf16x8*)(qbase + (size_t)(m * 16 + li) * 384 + 128);
    qf[m] = *(const bf16x8*)(qbase + (size_t)(m * 16 + li) * 384);
  }
  f32x4 zero = {0.f, 0.f, 0.f, 0.f};
  f32x4 st[4][4];
#pragma unroll
  for (int m = 0; m < 4; ++m)
#pragma unroll
    for (int n = 0; n < 4; ++n)
      st[m][n] = __builtin_amdgcn_mfma_f32_16x16x32_bf16(kf[m], qf[n], zero, 0, 0, 0);

  if (lane < 49) {
#pragma unroll
    for (int dc = 0; dc < 4; ++dc) {
      bf16x8 vv = *(const bf16x8*)(qkv + ((size_t)win * 49 + lane) * 384 + 256 +
                                   h * 32 + dc * 8);
#pragma unroll
      for (int t = 0; t < 8; ++t) Vt[h][dc * 8 + t][lane] = (ushort)vv[t];
    }
  } else {
#pragma unroll
    for (int d = 0; d < 32; ++d) Vt[h][d][lane] = 0;
  }

  const float* tb = TB + ((size_t)(type * 4 + h) << 12);
#pragma unroll
  for (int n = 0; n < 4; ++n) {
    int icol = n * 16 + li;
    float sv[3][4];
#pragma unroll
    for (int m = 0; m < 3; ++m)
#pragma unroll
      for (int r = 0; r < 4; ++r)
        sv[m][r] = st[m][n][r] * kScale + tb[(m * 16 + g * 4 + r) * 64 + icol];
    float sv3 = (g == 0) ? (st[3][n][0] * kScale + tb[48 * 64 + icol]) : -1e30f;
    float mx = sv3;
#pragma unroll
    for (int m = 0; m < 3; ++m)
#pragma unroll
      for (int r = 0; r < 4; ++r) mx = fmaxf(mx, sv[m][r]);
    mx = fmaxf(mx, __shfl_xor(mx, 16));
    mx = fmaxf(mx, __shfl_xor(mx, 32));
    float e[3][4], e3 = __expf(sv3 - mx);
    float sum = e3;
#pragma unroll
    for (int m = 0; m < 3; ++m)
#pragma unroll
      for (int r = 0; r < 4; ++r) { e[m][r] = __expf(sv[m][r] - mx); sum += e[m][r]; }
    sum += __shfl_xor(sum, 16);
    sum += __shfl_xor(sum, 32);
    float inv = 1.f / sum;
    float p3 = e3 * inv;
    float v3 = (g == 0) ? p3 : -1e30f;
    float mx2 = v3;
#pragma unroll
    for (int m = 0; m < 3; ++m)
#pragma unroll
      for (int r = 0; r < 4; ++r) mx2 = fmaxf(mx2, e[m][r] * inv);
    mx2 = fmaxf(mx2, __shfl_xor(mx2, 16));
    mx2 = fmaxf(mx2, __shfl_xor(mx2, 32));
    float e2[3][4], e23 = __expf(v3 - mx2);
    float sum2 = e23;
#pragma unroll
    for (int m = 0; m < 3; ++m)
#pragma unroll
      for (int r = 0; r < 4; ++r) { e2[m][r] = __expf(e[m][r] * inv - mx2); sum2 += e2[m][r]; }
    sum2 += __shfl_xor(sum2, 16);
    sum2 += __shfl_xor(sum2, 32);
    float inv2 = 1.f / sum2;
#pragma unroll
    for (int m = 0; m < 3; ++m) {
      uint u0 = (uint)f2bf(e2[m][0] * inv2) | ((uint)f2bf(e2[m][1] * inv2) << 16);
      uint u1 = (uint)f2bf(e2[m][2] * inv2) | ((uint)f2bf(e2[m][3] * inv2) << 16);
      *(uint*)&Pl[h][icol][m * 16 + g * 4]     = u0;
      *(uint*)&Pl[h][icol][m * 16 + g * 4 + 2] = u1;
    }
    uint u3 = (uint)f2bf(e23 * inv2);
    *(uint*)&Pl[h][icol][48 + g * 4]     = u3;
    *(uint*)&Pl[h][icol][48 + g * 4 + 2] = 0u;
  }
  __syncthreads();

  f32x4 oacc[4][2] = {};
#pragma unroll
  for (int ks = 0; ks < 2; ++ks) {
    int kloc = ks * 32 + g * 8;
    bf16x8 bf0 = *(const bf16x8*)&Vt[h][li][kloc];
    bf16x8 bf1 = *(const bf16x8*)&Vt[h][16 + li][kloc];
#pragma unroll
    for (int mi = 0; mi < 4; ++mi) {
      bf16x8 af = *(const bf16x8*)&Pl[h][mi * 16 + li][kloc];
      oacc[mi][0] = __builtin_amdgcn_mfma_f32_16x16x32_bf16(af, bf0, oacc[mi][0], 0, 0, 0);
      oacc[mi][1] = __builtin_amdgcn_mfma_f32_16x16x32_bf16(af, bf1, oacc[mi][1], 0, 0, 0);
    }
  }
  // stage O (49 x 32 per head) into Pl[h] (stride 40), then wide stores
  ushort* OlH = &Pl[h][0][0];
#pragma unroll
  for (int mi = 0; mi < 4; ++mi)
#pragma unroll
    for (int r = 0; r < 4; ++r) {
      int i = mi * 16 + g * 4 + r;
      if (mi < 3 || (g == 0 && r == 0)) {
        OlH[i * 40 + li]      = f2bf(oacc[mi][0][r]);
        OlH[i * 40 + 16 + li] = f2bf(oacc[mi][1][r]);
      }
    }
  __syncthreads();
  ushort* obase = ob + (size_t)win * 49 * 128;
#pragma unroll
  for (int it = 0; it < 4; ++it) {
    int chunk = tid + it * 256;  // 784 chunks of 8 ushorts
    if (chunk < 784) {
      int row = chunk >> 4, c8 = (chunk & 15) << 3;
      int h2 = c8 >> 5, d8 = c8 & 31;
      bf16x8 v = *(const bf16x8*)(&Pl[h2][0][0] + row * 40 + d8);
      *(bf16x8*)(obase + (size_t)row * 128 + c8) = v;
    }
  }
}

extern "C" void kernel_launch(void* const* d_in, const int* in_sizes, int n_in,
                              void* d_out, int out_size, void* d_ws,
                              size_t ws_size, hipStream_t stream) {
  (void)in_sizes; (void)n_in; (void)out_size; (void)ws_size;
  const float* x      = (const float*)d_in[0];
  const float* qkv_w  = (const float*)d_in[1];
  const float* qkv_b  = (const float*)d_in[2];
  const float* proj_w = (const float*)d_in[3];
  const float* proj_b = (const float*)d_in[4];
  const float* plg    = (const float*)d_in[5];
  const float* plb    = (const float*)d_in[6];
  const float* rpb    = (const float*)d_in[7];
  const float* n1g    = (const float*)d_in[8];
  const float* n1b    = (const float*)d_in[9];
  const float* n2g    = (const float*)d_in[10];
  const float* n2b    = (const float*)d_in[11];
  const float* w1     = (const float*)d_in[12];
  const float* b1     = (const float*)d_in[13];
  const float* w2     = (const float*)d_in[14];
  const float* b2     = (const float*)d_in[15];
  float* out = (float*)d_out;

  // ws layout (ushort units), ~233 MB
  ushort* wp   = (ushort*)d_ws;                         // 100352*128
  ushort* qkvb = wp + (size_t)100352 * 128;             // 100352*384
  ushort* obb  = qkvb + (size_t)100352 * 384;           // 100352*128
  ushort* hb   = obb + (size_t)100352 * 128;            // 100352*512
  ushort* qkvT = hb + (size_t)100352 * 512;             // 384*128
  ushort* w1T  = qkvT + 384 * 128;                      // 512*128
  ushort* w2T  = w1T + 512 * 128;                       // 128*512
  ushort* pT   = w2T + 128 * 512;                       // 128*128
  float*  TB   = (float*)(pT + 128 * 128);              // 4*4*64*64 f32
  ushort* yb   = qkvb;  // alias: qkvb dead after k_attn

  k_prep<<<768, 256, 0, stream>>>(qkv_w, w1, w2, proj_w, qkvT, w1T, w2T, pT);
  k_prep2<<<256, 256, 0, stream>>>(rpb, TB);
  k_ln1_part<<<12544, 256, 0, stream>>>(x, n1g, n1b, wp);
  k_gemm2<128, 384, 0><<<dim3(3, 1568), 256, 0, stream>>>(wp, qkvT, qkv_b, qkvb);
  k_attn<<<2048, 256, 0, stream>>>(qkvb, TB, obb);
  k_pgemm<<<784, 256, 0, stream>>>(obb, pT, proj_b, plg, plb, yb);
  k_unshift<<<12544, 256, 0, stream>>>(x, yb, n2g, n2b, out, wp);
  k_gemm2<128, 512, 1><<<dim3(4, 1568), 256, 0, stream>>>(wp, w1T, b1, hb);
  k_mlp2<<<1568, 256, 0, stream>>>(hb, w2T, b2, out);
}